// Round 2
// baseline (2742.586 us; speedup 1.0000x reference)
//
#include <hip/hip_runtime.h>
#include <math.h>

#define Bb 4
#define Hh 8
#define NP 4096
#define PTOT 8192
#define NTOT 12288
#define DIM 512
#define DH 64
#define SCALE 0.125f

// ---------------- workspace layout (float offsets) ----------------
// mq lives in d_out (same size as the final output; k_out overwrites last).
#define SZ_K    (4ull*8*12288*64)      // 25,165,824
#define SZ_L    (32ull*64*64)          // 131,072
#define OFF_K    0ull
#define OFF_V    (OFF_K + SZ_K)
#define OFF_QL   (OFF_V + SZ_K)
#define OFF_KL   (OFF_QL + SZ_L)
#define OFF_A2   (OFF_KL + SZ_L)
#define OFF_T3   (OFF_A2 + SZ_L)
#define OFF_T2   (OFF_T3 + SZ_L)
#define OFF_MAX  (OFF_T2 + SZ_L)
#define OFF_OPRE (OFF_MAX + 16ull)     // 64B-aligned
// total = 59,375,648 floats ≈ 226.5 MiB  (< 256 MiB d_ws)

// ---------------- K1: qkv = concat(x, ps) @ w_qkv, scatter to heads ----------------
__global__ __launch_bounds__(256) void k_qkv(const float* __restrict__ x,
    const float* __restrict__ ps, const float* __restrict__ wq,
    float* __restrict__ mq, float* __restrict__ kb, float* __restrict__ vb)
{
    __shared__ float As[16][64];
    __shared__ float Bs[16][64];
    const int tid = threadIdx.x;
    const int n0 = blockIdx.x * 64;   // 24 blocks over 1536 cols
    const int m0 = blockIdx.y * 64;   // 768 blocks over 49152 rows
    const int ty = tid >> 4, tx = tid & 15;
    const int arow = tid >> 2, ak = (tid & 3) << 2;
    const int brow = tid >> 4, bcol = (tid & 15) << 2;

    int grow = m0 + arow;
    int bidx = grow / NTOT;
    int pos  = grow - bidx * NTOT;
    const float* aptr = (pos < NP)
        ? (x  + ((size_t)bidx * NP   + pos) * DIM)
        : (ps + ((size_t)bidx * PTOT + (pos - NP)) * DIM);
    const float* bptr = wq + (size_t)brow * 1536 + n0 + bcol;

    float acc[4][4] = {};
    for (int k0 = 0; k0 < DIM; k0 += 16) {
        float4 av = *(const float4*)(aptr + k0 + ak);
        float4 bv = *(const float4*)(bptr + (size_t)k0 * 1536);
        __syncthreads();
        As[ak+0][arow] = av.x; As[ak+1][arow] = av.y;
        As[ak+2][arow] = av.z; As[ak+3][arow] = av.w;
        *(float4*)&Bs[brow][bcol] = bv;
        __syncthreads();
        #pragma unroll
        for (int kk = 0; kk < 16; ++kk) {
            float a[4], b[4];
            *(float4*)a = *(const float4*)&As[kk][ty << 2];
            *(float4*)b = *(const float4*)&Bs[kk][tx << 2];
            #pragma unroll
            for (int i = 0; i < 4; ++i)
                #pragma unroll
                for (int j = 0; j < 4; ++j)
                    acc[i][j] = fmaf(a[i], b[j], acc[i][j]);
        }
    }
    const int which = n0 >> 9;          // 0=q 1=k 2=v (tile never straddles)
    const int h = (n0 >> 6) & 7;
    #pragma unroll
    for (int i = 0; i < 4; ++i) {
        int row = m0 + (ty << 2) + i;
        int bi = row / NTOT;
        int p  = row - bi * NTOT;
        #pragma unroll
        for (int j = 0; j < 4; ++j) {
            int d = (tx << 2) + j;
            float v = acc[i][j];
            if (which == 0) {
                if (p < NP)
                    mq[(((size_t)bi*Hh + h)*NP + p)*DH + d] = v * SCALE;
            } else if (which == 1) {
                kb[(((size_t)bi*Hh + h)*NTOT + p)*DH + d] = v;
            } else {
                vb[(((size_t)bi*Hh + h)*NTOT + p)*DH + d] = v;
            }
        }
    }
}

// ---------------- K2: landmark means ----------------
__global__ __launch_bounds__(64) void k_land(const float* __restrict__ mq,
    const float* __restrict__ kb, float* __restrict__ ql, float* __restrict__ kl)
{
    const int d = threadIdx.x;
    int idx = blockIdx.x;
    if (idx < 2048) {               // q_l: mean over 64 contiguous rows of mq
        int bh = idx >> 6, i = idx & 63;
        const float* src = mq + ((size_t)bh * NP + i * 64) * DH + d;
        float s = 0.f;
        for (int j = 0; j < 64; ++j) s += src[(size_t)j * DH];
        ql[((size_t)bh * 64 + i) * 64 + d] = s * (1.f / 64.f);
    } else {                        // k_l: mean over 192 contiguous rows of k
        idx -= 2048;
        int bh = idx >> 6, i = idx & 63;
        const float* src = kb + ((size_t)bh * NTOT + i * 192) * DH + d;
        float s = 0.f;
        for (int j = 0; j < 192; ++j) s += src[(size_t)j * DH];
        kl[((size_t)bh * 64 + i) * 64 + d] = s * (1.f / 192.f);
    }
}

// ---------------- K3: attn2 = softmax(q_l @ k_l^T) ----------------
__global__ __launch_bounds__(256) void k_sim2(const float* __restrict__ ql,
    const float* __restrict__ kl, float* __restrict__ a2)
{
    __shared__ float qs[64][64];
    __shared__ float ks[64][65];
    __shared__ float S[64][65];
    const int tid = threadIdx.x;
    const int bh = blockIdx.x;
    for (int e = tid; e < 4096; e += 256) {
        qs[e >> 6][e & 63] = ql[(size_t)bh * 4096 + e];
        ks[e >> 6][e & 63] = kl[(size_t)bh * 4096 + e];
    }
    __syncthreads();
    for (int sI = 0; sI < 16; ++sI) {
        int e = (sI << 8) + tid;
        int i = e >> 6, j = e & 63;
        float acc = 0.f;
        #pragma unroll 16
        for (int d = 0; d < 64; ++d) acc = fmaf(qs[i][d], ks[j][d], acc);
        S[i][j] = acc;
    }
    __syncthreads();
    const int wv = tid >> 6, lane = tid & 63;
    for (int i = wv; i < 64; i += 4) {
        float v = S[i][lane];
        float mxv = v;
        #pragma unroll
        for (int off = 32; off; off >>= 1) mxv = fmaxf(mxv, __shfl_xor(mxv, off));
        float p = expf(v - mxv);
        float sm = p;
        #pragma unroll
        for (int off = 32; off; off >>= 1) sm += __shfl_xor(sm, off);
        a2[((size_t)bh * 64 + i) * 64 + lane] = p / sm;
    }
}

// ---------------- K4: global max of row/col abs-sums of attn2 ----------------
__global__ __launch_bounds__(256) void k_maxes(const float* __restrict__ a2,
    float* __restrict__ mx)
{
    __shared__ float red[256];
    const int tid = threadIdx.x;
    float mc = 0.f, mr = 0.f;
    for (int idx = tid; idx < 32 * 64; idx += 256) {
        int bh = idx >> 6, i = idx & 63;
        const float* base = a2 + (size_t)bh * 4096;
        float cs = 0.f, rs = 0.f;
        for (int j = 0; j < 64; ++j) {
            cs += fabsf(base[i * 64 + j]);   // sum over last axis
            rs += fabsf(base[j * 64 + i]);   // sum over axis -2
        }
        mc = fmaxf(mc, cs); mr = fmaxf(mr, rs);
    }
    red[tid] = mc; __syncthreads();
    for (int s = 128; s; s >>= 1) { if (tid < s) red[tid] = fmaxf(red[tid], red[tid + s]); __syncthreads(); }
    if (tid == 0) mx[0] = red[0];
    __syncthreads();
    red[tid] = mr; __syncthreads();
    for (int s = 128; s; s >>= 1) { if (tid < s) red[tid] = fmaxf(red[tid], red[tid + s]); __syncthreads(); }
    if (tid == 0) mx[1] = red[0];
}

// ---------------- K5: fused t3 = softmax(q_l @ k^T) @ v (flash-style) ----------------
__global__ __launch_bounds__(512) void k_sim3pv(const float* __restrict__ ql,
    const float* __restrict__ kb, const float* __restrict__ vb, float* __restrict__ t3)
{
    __shared__ float ks[64][65];
    __shared__ float vs[64][65];
    const int bh = blockIdx.x;
    const int rg = blockIdx.y;
    const int wv = threadIdx.x >> 6, lane = threadIdx.x & 63;
    const int row = (rg << 3) + wv;
    const float qv = ql[((size_t)bh * 64 + row) * 64 + lane];
    const float* kbase = kb + (size_t)bh * NTOT * DH;
    const float* vbase = vb + (size_t)bh * NTOT * DH;
    float m_run = -INFINITY, l_run = 0.f, acc = 0.f;
    for (int t = 0; t < NTOT / 64; ++t) {
        __syncthreads();
        for (int e = threadIdx.x << 2; e < 4096; e += 2048) {
            int r = e >> 6, c = e & 63;
            float4 k4 = *(const float4*)(kbase + ((size_t)(t * 64 + r)) * 64 + c);
            ks[r][c] = k4.x; ks[r][c+1] = k4.y; ks[r][c+2] = k4.z; ks[r][c+3] = k4.w;
            float4 v4 = *(const float4*)(vbase + ((size_t)(t * 64 + r)) * 64 + c);
            vs[r][c] = v4.x; vs[r][c+1] = v4.y; vs[r][c+2] = v4.z; vs[r][c+3] = v4.w;
        }
        __syncthreads();
        float s = 0.f;
        #pragma unroll 16
        for (int d = 0; d < 64; ++d) s = fmaf(__shfl(qv, d), ks[lane][d], s);
        float mxv = s;
        #pragma unroll
        for (int off = 32; off; off >>= 1) mxv = fmaxf(mxv, __shfl_xor(mxv, off));
        float m_new = fmaxf(m_run, mxv);
        float p = expf(s - m_new);
        float corr = expf(m_run - m_new);     // first iter: exp(-inf)=0
        float psum = p;
        #pragma unroll
        for (int off = 32; off; off >>= 1) psum += __shfl_xor(psum, off);
        l_run = l_run * corr + psum;
        float pv = 0.f;
        #pragma unroll 16
        for (int j = 0; j < 64; ++j) pv = fmaf(__shfl(p, j), vs[j][lane], pv);
        acc = acc * corr + pv;
        m_run = m_new;
    }
    t3[((size_t)bh * 64 + row) * 64 + lane] = acc / l_run;
}

// ---------------- K6: pinv iterations (LDS-resident, 48KB) + t2 = z @ t3 ----------------
// Register-buffered writes make in-place (C aliasing A/B/S) safe.
__device__ __forceinline__ void mm64r(float* __restrict__ C, const float* A,
    const float* Bm, const float* S, float sa, float sm, int tid)
{
    float r[16];
    __syncthreads();
    #pragma unroll
    for (int s = 0; s < 16; ++s) {
        int e = (s << 8) + tid;
        int i = e >> 6, j = e & 63;
        float acc = 0.f;
        #pragma unroll 16
        for (int k = 0; k < 64; ++k)
            acc = fmaf(A[(i << 6) + k], Bm[(k << 6) + j], acc);
        float v = sm * acc;
        if (S) v = fmaf(sa, S[e], v);
        r[s] = v;
    }
    __syncthreads();
    #pragma unroll
    for (int s = 0; s < 16; ++s) C[(s << 8) + tid] = r[s];
    __syncthreads();
}

// A-operand from global (wave-uniform broadcast reads, L2-resident)
__device__ __forceinline__ void mm64g(float* __restrict__ C, const float* __restrict__ Ag,
    const float* __restrict__ Bm, int tid)
{
    float r[16];
    __syncthreads();
    #pragma unroll
    for (int s = 0; s < 16; ++s) {
        int e = (s << 8) + tid;
        int i = e >> 6, j = e & 63;
        float acc = 0.f;
        #pragma unroll 16
        for (int k = 0; k < 64; ++k)
            acc = fmaf(Ag[(i << 6) + k], Bm[(k << 6) + j], acc);
        r[s] = acc;
    }
    __syncthreads();
    #pragma unroll
    for (int s = 0; s < 16; ++s) C[(s << 8) + tid] = r[s];
    __syncthreads();
}

__global__ __launch_bounds__(256) void k_pinv(const float* __restrict__ attn2,
    const float* __restrict__ mx, const float* __restrict__ t3g, float* __restrict__ t2g)
{
    __shared__ float Zs[4096], Ab[4096], Db[4096];
    const int tid = threadIdx.x;
    const int bh = blockIdx.x;
    const float inv = 1.0f / (mx[0] * mx[1]);
    const float* a2 = attn2 + (size_t)bh * 4096;
    for (int e = tid; e < 4096; e += 256) {
        int i = e >> 6, j = e & 63;
        Zs[e] = a2[(j << 6) + i] * inv;          // z = x^T / (mc*mr)
    }
    for (int it = 0; it < 6; ++it) {
        // z' = 0.25 z (13I - A(15I - A(7I - A))),  A = x@z
        //    = 3.25 z - 0.25 (z@A) @ (15I - 7A + A@A)
        mm64g(Ab, a2, Zs, tid);                     // A = X@Z
        mm64r(Db, Ab, Ab, Ab, 7.f, -1.f, tid);      // D' = 7A - A@A
        for (int e = tid; e < 4096; e += 256) {
            int i = e >> 6, j = e & 63;
            Db[e] = ((i == j) ? 15.f : 0.f) - Db[e];  // D = 15I - 7A + A@A
        }
        mm64r(Ab, Zs, Ab, nullptr, 0.f, 1.f, tid);  // A <- P = Z@A (in-place B)
        mm64r(Zs, Ab, Db, Zs, 3.25f, -0.25f, tid);  // Z <- 3.25Z - 0.25 P@D (in-place S/C)
    }
    for (int e = tid; e < 4096; e += 256) Ab[e] = t3g[(size_t)bh * 4096 + e];
    mm64r(Db, Zs, Ab, nullptr, 0.f, 1.f, tid);      // t2 = Z @ t3
    for (int e = tid; e < 4096; e += 256) t2g[(size_t)bh * 4096 + e] = Db[e];
}

// ---------------- K7: out1 = softmax(mq@k_l^T) @ t2 + depthwise conv(v) ----------------
__global__ __launch_bounds__(256) void k_attn1(const float* __restrict__ mq,
    const float* __restrict__ kl, const float* __restrict__ t2,
    const float* __restrict__ vb, const float* __restrict__ cwg,
    float* __restrict__ opre)
{
    __shared__ float kls[64][65];
    __shared__ float t2s[64][65];
    __shared__ float cw[33];
    const int bh = blockIdx.x;
    const int b = bh >> 3, h = bh & 7;
    const int rg = blockIdx.y;
    const int tid = threadIdx.x;
    const int wv = tid >> 6, lane = tid & 63;
    for (int e = tid; e < 4096; e += 256) {
        kls[e >> 6][e & 63] = kl[(size_t)bh * 4096 + e];
        t2s[e >> 6][e & 63] = t2[(size_t)bh * 4096 + e];
    }
    if (tid < 33) cw[tid] = cwg[h * 33 + tid];
    __syncthreads();
    const float* mqb = mq + (size_t)bh * NP * DH;
    const float* vp = vb + (size_t)bh * NTOT * DH + lane;
    for (int rr = 0; rr < 16; ++rr) {
        int row = (rg << 6) + (wv << 4) + rr;
        float qv = mqb[(size_t)row * DH + lane];
        float s = 0.f;
        #pragma unroll 16
        for (int d = 0; d < 64; ++d) s = fmaf(__shfl(qv, d), kls[lane][d], s);
        float mxv = s;
        #pragma unroll
        for (int off = 32; off; off >>= 1) mxv = fmaxf(mxv, __shfl_xor(mxv, off));
        float p = expf(s - mxv);
        float psum = p;
        #pragma unroll
        for (int off = 32; off; off >>= 1) psum += __shfl_xor(psum, off);
        p /= psum;
        float o = 0.f;
        #pragma unroll 16
        for (int j = 0; j < 64; ++j) o = fmaf(__shfl(p, j), t2s[j][lane], o);
        float c = 0.f;
        int kk0 = (row >= 16) ? 0 : (16 - row);
        for (int k = kk0; k < 33; ++k)
            c = fmaf(cw[k], vp[(size_t)(row - 16 + k) * DH], c);
        opre[((size_t)b * NP + row) * DIM + h * DH + lane] = o + c;
    }
}

// ---------------- K8: out = out_pre @ w_out ----------------
__global__ __launch_bounds__(256) void k_out(const float* __restrict__ A,
    const float* __restrict__ Bw, float* __restrict__ C)
{
    __shared__ float As[16][64];
    __shared__ float Bs[16][64];
    const int tid = threadIdx.x;
    const int n0 = blockIdx.x * 64;   // 8
    const int m0 = blockIdx.y * 64;   // 256
    const int ty = tid >> 4, tx = tid & 15;
    const int arow = tid >> 2, ak = (tid & 3) << 2;
    const int brow = tid >> 4, bcol = (tid & 15) << 2;
    const float* aptr = A + (size_t)(m0 + arow) * DIM;
    const float* bptr = Bw + (size_t)brow * DIM + n0 + bcol;
    float acc[4][4] = {};
    for (int k0 = 0; k0 < DIM; k0 += 16) {
        float4 av = *(const float4*)(aptr + k0 + ak);
        float4 bv = *(const float4*)(bptr + (size_t)k0 * DIM);
        __syncthreads();
        As[ak+0][arow] = av.x; As[ak+1][arow] = av.y;
        As[ak+2][arow] = av.z; As[ak+3][arow] = av.w;
        *(float4*)&Bs[brow][bcol] = bv;
        __syncthreads();
        #pragma unroll
        for (int kk = 0; kk < 16; ++kk) {
            float a[4], b[4];
            *(float4*)a = *(const float4*)&As[kk][ty << 2];
            *(float4*)b = *(const float4*)&Bs[kk][tx << 2];
            #pragma unroll
            for (int i = 0; i < 4; ++i)
                #pragma unroll
                for (int j = 0; j < 4; ++j)
                    acc[i][j] = fmaf(a[i], b[j], acc[i][j]);
        }
    }
    #pragma unroll
    for (int i = 0; i < 4; ++i) {
        float4 o = make_float4(acc[i][0], acc[i][1], acc[i][2], acc[i][3]);
        *(float4*)(C + (size_t)(m0 + (ty << 2) + i) * DIM + n0 + (tx << 2)) = o;
    }
}

extern "C" void kernel_launch(void* const* d_in, const int* in_sizes, int n_in,
                              void* d_out, int out_size, void* d_ws, size_t ws_size,
                              hipStream_t stream)
{
    const float* x   = (const float*)d_in[0];
    const float* ps  = (const float*)d_in[1];
    const float* wq  = (const float*)d_in[2];
    const float* wo  = (const float*)d_in[3];
    const float* cwg = (const float*)d_in[4];
    float* out = (float*)d_out;
    float* ws  = (float*)d_ws;

    float* mq   = out;               // d_out doubles as mq scratch; k_out overwrites last
    float* kb   = ws + OFF_K;
    float* vb   = ws + OFF_V;
    float* ql   = ws + OFF_QL;
    float* kl   = ws + OFF_KL;
    float* a2   = ws + OFF_A2;
    float* t3   = ws + OFF_T3;
    float* t2   = ws + OFF_T2;
    float* mx   = ws + OFF_MAX;
    float* opre = ws + OFF_OPRE;

    k_qkv  <<<dim3(24, 768), 256, 0, stream>>>(x, ps, wq, mq, kb, vb);
    k_land <<<4096, 64, 0, stream>>>(mq, kb, ql, kl);
    k_sim2 <<<32, 256, 0, stream>>>(ql, kl, a2);
    k_maxes<<<1, 256, 0, stream>>>(a2, mx);
    k_sim3pv<<<dim3(32, 8), 512, 0, stream>>>(ql, kb, vb, t3);
    k_pinv <<<32, 256, 0, stream>>>(a2, mx, t3, t2);
    k_attn1<<<dim3(32, 64), 256, 0, stream>>>(mq, kl, t2, vb, cwg, opre);
    k_out  <<<dim3(8, 256), 256, 0, stream>>>(opre, wo, out);
}

// Round 3
// 1997.606 us; speedup vs baseline: 1.3729x; 1.3729x over previous
//
#include <hip/hip_runtime.h>
#include <math.h>

#define Bb 4
#define Hh 8
#define NP 4096
#define PTOT 8192
#define NTOT 12288
#define DIM 512
#define DH 64
#define SCALE 0.125f
#define NCH 24          // sequence chunks for sim3 split
#define CHUNK 512       // 12288 / 24

// ---------------- workspace layout (float offsets) ----------------
// mq lives in d_out (same size as the final output; k_out overwrites last).
#define SZ_K    (4ull*8*12288*64)      // 25,165,824
#define SZ_L    (32ull*64*64)          // 131,072
#define OFF_K    0ull
#define OFF_V    (OFF_K + SZ_K)
#define OFF_QL   (OFF_V + SZ_K)
#define OFF_KL   (OFF_QL + SZ_L)
#define OFF_A2   (OFF_KL + SZ_L)
#define OFF_T3   (OFF_A2 + SZ_L)
#define OFF_T2   (OFF_T3 + SZ_L)
#define OFF_MAX  (OFF_T2 + SZ_L)
#define OFF_OPRE (OFF_MAX + 16ull)     // 64B-aligned
// sim3 partials alias the opre region (consumed by k_sim3comb before k_attn1 writes opre):
//   pacc: 32*24*64*64 = 3,145,728   pm/pl: 32*24*64 each

// ---------------- K1: qkv = concat(x, ps) @ w_qkv, scatter to heads ----------------
__global__ __launch_bounds__(256) void k_qkv(const float* __restrict__ x,
    const float* __restrict__ ps, const float* __restrict__ wq,
    float* __restrict__ mq, float* __restrict__ kb, float* __restrict__ vb)
{
    __shared__ float As[16][64];
    __shared__ float Bs[16][64];
    const int tid = threadIdx.x;
    const int n0 = blockIdx.x * 64;   // 24 blocks over 1536 cols
    const int m0 = blockIdx.y * 64;   // 768 blocks over 49152 rows
    const int ty = tid >> 4, tx = tid & 15;
    const int arow = tid >> 2, ak = (tid & 3) << 2;
    const int brow = tid >> 4, bcol = (tid & 15) << 2;

    int grow = m0 + arow;
    int bidx = grow / NTOT;
    int pos  = grow - bidx * NTOT;
    const float* aptr = (pos < NP)
        ? (x  + ((size_t)bidx * NP   + pos) * DIM)
        : (ps + ((size_t)bidx * PTOT + (pos - NP)) * DIM);
    const float* bptr = wq + (size_t)brow * 1536 + n0 + bcol;

    float acc[4][4] = {};
    for (int k0 = 0; k0 < DIM; k0 += 16) {
        float4 av = *(const float4*)(aptr + k0 + ak);
        float4 bv = *(const float4*)(bptr + (size_t)k0 * 1536);
        __syncthreads();
        As[ak+0][arow] = av.x; As[ak+1][arow] = av.y;
        As[ak+2][arow] = av.z; As[ak+3][arow] = av.w;
        *(float4*)&Bs[brow][bcol] = bv;
        __syncthreads();
        #pragma unroll
        for (int kk = 0; kk < 16; ++kk) {
            float a[4], b[4];
            *(float4*)a = *(const float4*)&As[kk][ty << 2];
            *(float4*)b = *(const float4*)&Bs[kk][tx << 2];
            #pragma unroll
            for (int i = 0; i < 4; ++i)
                #pragma unroll
                for (int j = 0; j < 4; ++j)
                    acc[i][j] = fmaf(a[i], b[j], acc[i][j]);
        }
    }
    const int which = n0 >> 9;          // 0=q 1=k 2=v (tile never straddles)
    const int h = (n0 >> 6) & 7;
    #pragma unroll
    for (int i = 0; i < 4; ++i) {
        int row = m0 + (ty << 2) + i;
        int bi = row / NTOT;
        int p  = row - bi * NTOT;
        #pragma unroll
        for (int j = 0; j < 4; ++j) {
            int d = (tx << 2) + j;
            float v = acc[i][j];
            if (which == 0) {
                if (p < NP)
                    mq[(((size_t)bi*Hh + h)*NP + p)*DH + d] = v * SCALE;
            } else if (which == 1) {
                kb[(((size_t)bi*Hh + h)*NTOT + p)*DH + d] = v;
            } else {
                vb[(((size_t)bi*Hh + h)*NTOT + p)*DH + d] = v;
            }
        }
    }
}

// ---------------- K2: landmark means ----------------
__global__ __launch_bounds__(64) void k_land(const float* __restrict__ mq,
    const float* __restrict__ kb, float* __restrict__ ql, float* __restrict__ kl)
{
    const int d = threadIdx.x;
    int idx = blockIdx.x;
    if (idx < 2048) {               // q_l: mean over 64 contiguous rows of mq
        int bh = idx >> 6, i = idx & 63;
        const float* src = mq + ((size_t)bh * NP + i * 64) * DH + d;
        float s = 0.f;
        for (int j = 0; j < 64; ++j) s += src[(size_t)j * DH];
        ql[((size_t)bh * 64 + i) * 64 + d] = s * (1.f / 64.f);
    } else {                        // k_l: mean over 192 contiguous rows of k
        idx -= 2048;
        int bh = idx >> 6, i = idx & 63;
        const float* src = kb + ((size_t)bh * NTOT + i * 192) * DH + d;
        float s = 0.f;
        for (int j = 0; j < 192; ++j) s += src[(size_t)j * DH];
        kl[((size_t)bh * 64 + i) * 64 + d] = s * (1.f / 192.f);
    }
}

// ---------------- K3: attn2 = softmax(q_l @ k_l^T) ----------------
__global__ __launch_bounds__(256) void k_sim2(const float* __restrict__ ql,
    const float* __restrict__ kl, float* __restrict__ a2)
{
    __shared__ float qs[64][64];
    __shared__ float ks[64][65];
    __shared__ float S[64][65];
    const int tid = threadIdx.x;
    const int bh = blockIdx.x;
    for (int e = tid; e < 4096; e += 256) {
        qs[e >> 6][e & 63] = ql[(size_t)bh * 4096 + e];
        ks[e >> 6][e & 63] = kl[(size_t)bh * 4096 + e];
    }
    __syncthreads();
    for (int sI = 0; sI < 16; ++sI) {
        int e = (sI << 8) + tid;
        int i = e >> 6, j = e & 63;
        float acc = 0.f;
        #pragma unroll 16
        for (int d = 0; d < 64; ++d) acc = fmaf(qs[i][d], ks[j][d], acc);
        S[i][j] = acc;
    }
    __syncthreads();
    const int wv = tid >> 6, lane = tid & 63;
    for (int i = wv; i < 64; i += 4) {
        float v = S[i][lane];
        float mxv = v;
        #pragma unroll
        for (int off = 32; off; off >>= 1) mxv = fmaxf(mxv, __shfl_xor(mxv, off));
        float p = expf(v - mxv);
        float sm = p;
        #pragma unroll
        for (int off = 32; off; off >>= 1) sm += __shfl_xor(sm, off);
        a2[((size_t)bh * 64 + i) * 64 + lane] = p / sm;
    }
}

// ---------------- K4: global max of row/col abs-sums of attn2 ----------------
__global__ __launch_bounds__(256) void k_maxes(const float* __restrict__ a2,
    float* __restrict__ mx)
{
    __shared__ float red[256];
    const int tid = threadIdx.x;
    float mc = 0.f, mr = 0.f;
    for (int idx = tid; idx < 32 * 64; idx += 256) {
        int bh = idx >> 6, i = idx & 63;
        const float* base = a2 + (size_t)bh * 4096;
        float cs = 0.f, rs = 0.f;
        for (int j = 0; j < 64; ++j) {
            cs += fabsf(base[i * 64 + j]);   // sum over last axis
            rs += fabsf(base[j * 64 + i]);   // sum over axis -2
        }
        mc = fmaxf(mc, cs); mr = fmaxf(mr, rs);
    }
    red[tid] = mc; __syncthreads();
    for (int s = 128; s; s >>= 1) { if (tid < s) red[tid] = fmaxf(red[tid], red[tid + s]); __syncthreads(); }
    if (tid == 0) mx[0] = red[0];
    __syncthreads();
    red[tid] = mr; __syncthreads();
    for (int s = 128; s; s >>= 1) { if (tid < s) red[tid] = fmaxf(red[tid], red[tid + s]); __syncthreads(); }
    if (tid == 0) mx[1] = red[0];
}

// ---------------- K5a: sim3 partials — flash over a 512-row chunk ----------------
// grid (32 bh, 24 chunks), 256 thr. Thread (ty,tx) owns rows ty*4..+3, cols tx*4..+3.
// K/V time-share one LDS tile; float4-slot XOR swizzle kills the 4-row-stride conflict.
__global__ __launch_bounds__(256) void k_sim3part(const float* __restrict__ ql,
    const float* __restrict__ kb, const float* __restrict__ vb,
    float* __restrict__ pacc, float* __restrict__ pm, float* __restrict__ pl)
{
    __shared__ float qs[64][68];
    __shared__ float kv[64][64];   // swizzled: kv[r][ (slot ^ ((r>>2)&15))<<2 .. ]
    __shared__ float pss[64][68];
    const int bh = blockIdx.x, ch = blockIdx.y;
    const int tid = threadIdx.x;
    const int ty = tid >> 4, tx = tid & 15;

    for (int e = tid; e < 4096; e += 256) qs[e >> 6][e & 63] = ql[(size_t)bh * 4096 + e];

    float m_run[4] = {-INFINITY, -INFINITY, -INFINITY, -INFINITY};
    float l_run[4] = {};
    float acc[4][4] = {};

    const float* kc = kb + ((size_t)bh * NTOT + ch * CHUNK) * DH;
    const float* vc = vb + ((size_t)bh * NTOT + ch * CHUNK) * DH;

    for (int t = 0; t < CHUNK / 64; ++t) {
        __syncthreads();   // prev PV done with ps/kv; qs ready on first iter
        // stage K tile (64x64), swizzled
        #pragma unroll
        for (int e = tid; e < 1024; e += 256) {
            int r = e >> 4, slot = e & 15;
            float4 kx = *(const float4*)(kc + ((size_t)(t * 64 + r)) * DH + (slot << 2));
            *(float4*)&kv[r][((slot ^ ((r >> 2) & 15)) << 2)] = kx;
        }
        __syncthreads();
        // S = q @ k^T, 4x4 per thread
        float s[4][4] = {};
        #pragma unroll
        for (int d4 = 0; d4 < 16; ++d4) {
            float4 qv[4], kvv[4];
            #pragma unroll
            for (int ii = 0; ii < 4; ++ii) qv[ii] = *(const float4*)&qs[(ty << 2) + ii][d4 << 2];
            #pragma unroll
            for (int jj = 0; jj < 4; ++jj)
                kvv[jj] = *(const float4*)&kv[(tx << 2) + jj][((d4 ^ tx) & 15) << 2];
            #pragma unroll
            for (int ii = 0; ii < 4; ++ii)
                #pragma unroll
                for (int jj = 0; jj < 4; ++jj) {
                    s[ii][jj] = fmaf(qv[ii].x, kvv[jj].x, s[ii][jj]);
                    s[ii][jj] = fmaf(qv[ii].y, kvv[jj].y, s[ii][jj]);
                    s[ii][jj] = fmaf(qv[ii].z, kvv[jj].z, s[ii][jj]);
                    s[ii][jj] = fmaf(qv[ii].w, kvv[jj].w, s[ii][jj]);
                }
        }
        // online softmax over the 64 cols (16-lane row groups)
        #pragma unroll
        for (int ii = 0; ii < 4; ++ii) {
            float rmax = fmaxf(fmaxf(s[ii][0], s[ii][1]), fmaxf(s[ii][2], s[ii][3]));
            #pragma unroll
            for (int off = 8; off; off >>= 1) rmax = fmaxf(rmax, __shfl_xor(rmax, off));
            float mnew = fmaxf(m_run[ii], rmax);
            float corr = expf(m_run[ii] - mnew);
            float rs = 0.f;
            #pragma unroll
            for (int jj = 0; jj < 4; ++jj) { s[ii][jj] = expf(s[ii][jj] - mnew); rs += s[ii][jj]; }
            #pragma unroll
            for (int off = 8; off; off >>= 1) rs += __shfl_xor(rs, off);
            l_run[ii] = l_run[ii] * corr + rs;
            m_run[ii] = mnew;
            #pragma unroll
            for (int dd = 0; dd < 4; ++dd) acc[ii][dd] *= corr;
            *(float4*)&pss[(ty << 2) + ii][tx << 2] = make_float4(s[ii][0], s[ii][1], s[ii][2], s[ii][3]);
        }
        __syncthreads();   // S-compute done reading kv; P written
        // stage V tile into kv (same swizzle)
        #pragma unroll
        for (int e = tid; e < 1024; e += 256) {
            int r = e >> 4, slot = e & 15;
            float4 vx = *(const float4*)(vc + ((size_t)(t * 64 + r)) * DH + (slot << 2));
            *(float4*)&kv[r][((slot ^ ((r >> 2) & 15)) << 2)] = vx;
        }
        __syncthreads();
        // acc += P @ V
        #pragma unroll
        for (int j4 = 0; j4 < 16; ++j4) {
            float4 pv4[4], vv[4];
            #pragma unroll
            for (int ii = 0; ii < 4; ++ii) pv4[ii] = *(const float4*)&pss[(ty << 2) + ii][j4 << 2];
            #pragma unroll
            for (int jj = 0; jj < 4; ++jj)
                vv[jj] = *(const float4*)&kv[(j4 << 2) + jj][((tx ^ j4) & 15) << 2];
            #pragma unroll
            for (int ii = 0; ii < 4; ++ii) {
                #pragma unroll
                for (int jj = 0; jj < 4; ++jj) {
                    float pj = ((const float*)&pv4[ii])[jj];
                    #pragma unroll
                    for (int dd = 0; dd < 4; ++dd)
                        acc[ii][dd] = fmaf(pj, ((const float*)&vv[jj])[dd], acc[ii][dd]);
                }
            }
        }
    }
    // write partials: pacc[bh][ch][i][d], pm/pl[bh][ch][i]
    const size_t base = ((size_t)bh * NCH + ch) * 64;
    #pragma unroll
    for (int ii = 0; ii < 4; ++ii) {
        int i = (ty << 2) + ii;
        *(float4*)(pacc + (base + i) * 64 + (tx << 2)) =
            make_float4(acc[ii][0], acc[ii][1], acc[ii][2], acc[ii][3]);
        if (tx == 0) { pm[base + i] = m_run[ii]; pl[base + i] = l_run[ii]; }
    }
}

// ---------------- K5b: combine sim3 partials -> t3 ----------------
__global__ __launch_bounds__(256) void k_sim3comb(const float* __restrict__ pacc,
    const float* __restrict__ pm, const float* __restrict__ pl, float* __restrict__ t3)
{
    __shared__ float w[NCH][64];
    __shared__ float Linv[64];
    const int bh = blockIdx.x;
    const int tid = threadIdx.x;
    if (tid < 64) {
        float M = -INFINITY;
        for (int c = 0; c < NCH; ++c)
            M = fmaxf(M, pm[((size_t)bh * NCH + c) * 64 + tid]);
        float L = 0.f;
        for (int c = 0; c < NCH; ++c) {
            float e = expf(pm[((size_t)bh * NCH + c) * 64 + tid] - M);
            w[c][tid] = e;
            L = fmaf(e, pl[((size_t)bh * NCH + c) * 64 + tid], L);
        }
        Linv[tid] = 1.f / L;
    }
    __syncthreads();
    const int wv = tid >> 6, lane = tid & 63;
    for (int p = 0; p < 16; ++p) {
        int i = (p << 2) + wv;
        float o = 0.f;
        for (int c = 0; c < NCH; ++c)
            o = fmaf(w[c][i], pacc[(((size_t)bh * NCH + c) * 64 + i) * 64 + lane], o);
        t3[((size_t)bh * 64 + i) * 64 + lane] = o * Linv[i];
    }
}

// ---------------- K6: pinv iterations (LDS-resident, 48KB) + t2 = z @ t3 ----------------
__device__ __forceinline__ void mm64r(float* __restrict__ C, const float* A,
    const float* Bm, const float* S, float sa, float sm, int tid)
{
    float r[16];
    __syncthreads();
    #pragma unroll
    for (int s = 0; s < 16; ++s) {
        int e = (s << 8) + tid;
        int i = e >> 6, j = e & 63;
        float acc = 0.f;
        #pragma unroll 16
        for (int k = 0; k < 64; ++k)
            acc = fmaf(A[(i << 6) + k], Bm[(k << 6) + j], acc);
        float v = sm * acc;
        if (S) v = fmaf(sa, S[e], v);
        r[s] = v;
    }
    __syncthreads();
    #pragma unroll
    for (int s = 0; s < 16; ++s) C[(s << 8) + tid] = r[s];
    __syncthreads();
}

__device__ __forceinline__ void mm64g(float* __restrict__ C, const float* __restrict__ Ag,
    const float* __restrict__ Bm, int tid)
{
    float r[16];
    __syncthreads();
    #pragma unroll
    for (int s = 0; s < 16; ++s) {
        int e = (s << 8) + tid;
        int i = e >> 6, j = e & 63;
        float acc = 0.f;
        #pragma unroll 16
        for (int k = 0; k < 64; ++k)
            acc = fmaf(Ag[(i << 6) + k], Bm[(k << 6) + j], acc);
        r[s] = acc;
    }
    __syncthreads();
    #pragma unroll
    for (int s = 0; s < 16; ++s) C[(s << 8) + tid] = r[s];
    __syncthreads();
}

__global__ __launch_bounds__(256) void k_pinv(const float* __restrict__ attn2,
    const float* __restrict__ mx, const float* __restrict__ t3g, float* __restrict__ t2g)
{
    __shared__ float Zs[4096], Ab[4096], Db[4096];
    const int tid = threadIdx.x;
    const int bh = blockIdx.x;
    const float inv = 1.0f / (mx[0] * mx[1]);
    const float* a2 = attn2 + (size_t)bh * 4096;
    for (int e = tid; e < 4096; e += 256) {
        int i = e >> 6, j = e & 63;
        Zs[e] = a2[(j << 6) + i] * inv;          // z = x^T / (mc*mr)
    }
    for (int it = 0; it < 6; ++it) {
        mm64g(Ab, a2, Zs, tid);                     // A = X@Z
        mm64r(Db, Ab, Ab, Ab, 7.f, -1.f, tid);      // D' = 7A - A@A
        for (int e = tid; e < 4096; e += 256) {
            int i = e >> 6, j = e & 63;
            Db[e] = ((i == j) ? 15.f : 0.f) - Db[e];  // D = 15I - 7A + A@A
        }
        mm64r(Ab, Zs, Ab, nullptr, 0.f, 1.f, tid);  // A <- P = Z@A (in-place B)
        mm64r(Zs, Ab, Db, Zs, 3.25f, -0.25f, tid);  // Z <- 3.25Z - 0.25 P@D
    }
    for (int e = tid; e < 4096; e += 256) Ab[e] = t3g[(size_t)bh * 4096 + e];
    mm64r(Db, Zs, Ab, nullptr, 0.f, 1.f, tid);      // t2 = Z @ t3
    for (int e = tid; e < 4096; e += 256) t2g[(size_t)bh * 4096 + e] = Db[e];
}

// ---------------- K7: out1 = softmax(mq@k_l^T) @ t2 + depthwise conv(v) ----------------
__global__ __launch_bounds__(256) void k_attn1(const float* __restrict__ mq,
    const float* __restrict__ kl, const float* __restrict__ t2,
    const float* __restrict__ vb, const float* __restrict__ cwg,
    float* __restrict__ opre)
{
    __shared__ float kls[64][65];
    __shared__ float t2s[64][65];
    __shared__ float cw[33];
    const int bh = blockIdx.x;
    const int b = bh >> 3, h = bh & 7;
    const int rg = blockIdx.y;
    const int tid = threadIdx.x;
    const int wv = tid >> 6, lane = tid & 63;
    for (int e = tid; e < 4096; e += 256) {
        kls[e >> 6][e & 63] = kl[(size_t)bh * 4096 + e];
        t2s[e >> 6][e & 63] = t2[(size_t)bh * 4096 + e];
    }
    if (tid < 33) cw[tid] = cwg[h * 33 + tid];
    __syncthreads();
    const float* mqb = mq + (size_t)bh * NP * DH;
    const float* vp = vb + (size_t)bh * NTOT * DH + lane;
    for (int rr = 0; rr < 16; ++rr) {
        int row = (rg << 6) + (wv << 4) + rr;
        float qv = mqb[(size_t)row * DH + lane];
        float s = 0.f;
        #pragma unroll 16
        for (int d = 0; d < 64; ++d) s = fmaf(__shfl(qv, d), kls[lane][d], s);
        float mxv = s;
        #pragma unroll
        for (int off = 32; off; off >>= 1) mxv = fmaxf(mxv, __shfl_xor(mxv, off));
        float p = expf(s - mxv);
        float psum = p;
        #pragma unroll
        for (int off = 32; off; off >>= 1) psum += __shfl_xor(psum, off);
        p /= psum;
        float o = 0.f;
        #pragma unroll 16
        for (int j = 0; j < 64; ++j) o = fmaf(__shfl(p, j), t2s[j][lane], o);
        float c = 0.f;
        int kk0 = (row >= 16) ? 0 : (16 - row);
        for (int k = kk0; k < 33; ++k)
            c = fmaf(cw[k], vp[(size_t)(row - 16 + k) * DH], c);
        opre[((size_t)b * NP + row) * DIM + h * DH + lane] = o + c;
    }
}

// ---------------- K8: out = out_pre @ w_out ----------------
__global__ __launch_bounds__(256) void k_out(const float* __restrict__ A,
    const float* __restrict__ Bw, float* __restrict__ C)
{
    __shared__ float As[16][64];
    __shared__ float Bs[16][64];
    const int tid = threadIdx.x;
    const int n0 = blockIdx.x * 64;
    const int m0 = blockIdx.y * 64;
    const int ty = tid >> 4, tx = tid & 15;
    const int arow = tid >> 2, ak = (tid & 3) << 2;
    const int brow = tid >> 4, bcol = (tid & 15) << 2;
    const float* aptr = A + (size_t)(m0 + arow) * DIM;
    const float* bptr = Bw + (size_t)brow * DIM + n0 + bcol;
    float acc[4][4] = {};
    for (int k0 = 0; k0 < DIM; k0 += 16) {
        float4 av = *(const float4*)(aptr + k0 + ak);
        float4 bv = *(const float4*)(bptr + (size_t)k0 * DIM);
        __syncthreads();
        As[ak+0][arow] = av.x; As[ak+1][arow] = av.y;
        As[ak+2][arow] = av.z; As[ak+3][arow] = av.w;
        *(float4*)&Bs[brow][bcol] = bv;
        __syncthreads();
        #pragma unroll
        for (int kk = 0; kk < 16; ++kk) {
            float a[4], b[4];
            *(float4*)a = *(const float4*)&As[kk][ty << 2];
            *(float4*)b = *(const float4*)&Bs[kk][tx << 2];
            #pragma unroll
            for (int i = 0; i < 4; ++i)
                #pragma unroll
                for (int j = 0; j < 4; ++j)
                    acc[i][j] = fmaf(a[i], b[j], acc[i][j]);
        }
    }
    #pragma unroll
    for (int i = 0; i < 4; ++i) {
        float4 o = make_float4(acc[i][0], acc[i][1], acc[i][2], acc[i][3]);
        *(float4*)(C + (size_t)(m0 + (ty << 2) + i) * DIM + n0 + (tx << 2)) = o;
    }
}

extern "C" void kernel_launch(void* const* d_in, const int* in_sizes, int n_in,
                              void* d_out, int out_size, void* d_ws, size_t ws_size,
                              hipStream_t stream)
{
    const float* x   = (const float*)d_in[0];
    const float* ps  = (const float*)d_in[1];
    const float* wq  = (const float*)d_in[2];
    const float* wo  = (const float*)d_in[3];
    const float* cwg = (const float*)d_in[4];
    float* out = (float*)d_out;
    float* ws  = (float*)d_ws;

    float* mq   = out;               // d_out doubles as mq scratch; k_out overwrites last
    float* kb   = ws + OFF_K;
    float* vb   = ws + OFF_V;
    float* ql   = ws + OFF_QL;
    float* kl   = ws + OFF_KL;
    float* a2   = ws + OFF_A2;
    float* t3   = ws + OFF_T3;
    float* t2   = ws + OFF_T2;
    float* mx   = ws + OFF_MAX;
    float* opre = ws + OFF_OPRE;
    // sim3 partials alias opre (consumed before k_attn1 writes opre)
    float* pacc = opre;
    float* pm   = opre + 3145728ull;
    float* pl   = pm + 49152ull;

    k_qkv     <<<dim3(24, 768), 256, 0, stream>>>(x, ps, wq, mq, kb, vb);
    k_land    <<<4096, 64, 0, stream>>>(mq, kb, ql, kl);
    k_sim2    <<<32, 256, 0, stream>>>(ql, kl, a2);
    k_maxes   <<<1, 256, 0, stream>>>(a2, mx);
    k_sim3part<<<dim3(32, NCH), 256, 0, stream>>>(ql, kb, vb, pacc, pm, pl);
    k_sim3comb<<<32, 256, 0, stream>>>(pacc, pm, pl, t3);
    k_pinv    <<<32, 256, 0, stream>>>(a2, mx, t3, t2);
    k_attn1   <<<dim3(32, 64), 256, 0, stream>>>(mq, kl, t2, vb, cwg, opre);
    k_out     <<<dim3(8, 256), 256, 0, stream>>>(opre, wo, out);
}

// Round 4
// 1122.642 us; speedup vs baseline: 2.4430x; 1.7794x over previous
//
#include <hip/hip_runtime.h>
#include <math.h>

#define Bb 4
#define Hh 8
#define NP 4096
#define PTOT 8192
#define NTOT 12288
#define DIM 512
#define DH 64
#define SCALE 0.125f
#define NCH 24
#define CHUNK 512

typedef __attribute__((ext_vector_type(8))) _Float16 f16x8;
typedef __attribute__((ext_vector_type(4))) float f32x4;

// ---------------- workspace layout (float offsets) ----------------
#define SZ_K    (4ull*8*12288*64)      // 25,165,824
#define SZ_L    (32ull*64*64)          // 131,072
#define OFF_K    0ull
#define OFF_V    (OFF_K + SZ_K)
#define OFF_QL   (OFF_V + SZ_K)
#define OFF_KL   (OFF_QL + SZ_L)
#define OFF_A2   (OFF_KL + SZ_L)
#define OFF_T3   (OFF_A2 + SZ_L)
#define OFF_T2   (OFF_T3 + SZ_L)
#define OFF_MAX  (OFF_T2 + SZ_L)
#define OFF_OPRE (OFF_MAX + 16ull)
// total = 59,375,648 floats (237.5 MB) — proven to fit in round 2.
// BTq (fp16 w_qkv^T hi/lo, 786432 floats) aliases [OFF_QL ...): those regions
// (ql,kl,a2,t3,t2,mx,opre-head) are written only AFTER the qkv GEMM consumes BTq.
// BTo (fp16 w_out^T hi/lo, 524288 floats) aliases kb (dead after k_sim3part);
// its cvt kernel launches after k_sim3comb.

// ---------------- transpose + fp16-split weights: w[K][N] -> BT[N][K] hi/lo ----------------
__global__ __launch_bounds__(256) void k_cvtw(const float* __restrict__ w,
    _Float16* __restrict__ bh, _Float16* __restrict__ bl, int K, int N)
{
    __shared__ float t[64][65];
    const int n0 = blockIdx.x * 64, k0 = blockIdx.y * 64;
    const int tid = threadIdx.x;
    #pragma unroll
    for (int i = 0; i < 4; ++i) {
        int r = (tid >> 4) + i * 16;
        int c = (tid & 15) * 4;
        float4 v = *(const float4*)(w + (size_t)(k0 + r) * N + n0 + c);
        t[r][c] = v.x; t[r][c+1] = v.y; t[r][c+2] = v.z; t[r][c+3] = v.w;
    }
    __syncthreads();
    const int n = tid >> 2, kq = (tid & 3) * 16;
    f16x8 h8[2], l8[2];
    #pragma unroll
    for (int j = 0; j < 16; ++j) {
        float a = t[kq + j][n];
        _Float16 hh = (_Float16)a;
        _Float16 ll = (_Float16)(a - (float)hh);
        h8[j >> 3][j & 7] = hh;
        l8[j >> 3][j & 7] = ll;
    }
    size_t o = (size_t)(n0 + n) * K + k0 + kq;
    *(f16x8*)(bh + o) = h8[0]; *(f16x8*)(bh + o + 8) = h8[1];
    *(f16x8*)(bl + o) = l8[0]; *(f16x8*)(bl + o + 8) = l8[1];
}

// ---------------- fp16-split MFMA GEMM (3 products: hh + hl + lh) ----------------
// MODE 0: A = concat(x,ps) [49152][512] fp32 (converted inline), C scattered to mq/kb/vb
// MODE 1: A = opre [16384][512] fp32, C = out [16384][512]
__device__ __forceinline__ int hoff(int r, int slot) {
    return r * 32 + (((slot ^ (r >> 1)) & 3) << 3);
}

template<int MODE>
__global__ __launch_bounds__(256) void k_gemm_split(
    const float* __restrict__ Asrc0, const float* __restrict__ Asrc1,
    const _Float16* __restrict__ BTh, const _Float16* __restrict__ BTl,
    float* __restrict__ out0, float* __restrict__ out1, float* __restrict__ out2)
{
    __shared__ __align__(16) _Float16 Ah[128 * 32], Al[128 * 32];
    __shared__ __align__(16) _Float16 Bh[128 * 32], Bl[128 * 32];
    const int NCOLS = (MODE == 0) ? 1536 : 512;
    const int tid = threadIdx.x;
    const int n0 = blockIdx.x * 128;
    const int m0 = blockIdx.y * 128;
    const int wv = tid >> 6, lane = tid & 63;
    const int wr = wv >> 1, wc = wv & 1;
    const int kslot = lane >> 4;

    // per-thread staging coordinates (2 A slots, 2 B slot-pairs)
    int ar[2], asl[2];
    const float* aptr[2];
    #pragma unroll
    for (int i = 0; i < 2; ++i) {
        int id = tid + 256 * i;
        ar[i] = id >> 2; asl[i] = id & 3;
        int grow = m0 + ar[i];
        if (MODE == 0) {
            int bi = grow / NTOT;
            int pos = grow - bi * NTOT;
            aptr[i] = (pos < NP) ? (Asrc0 + ((size_t)bi * NP + pos) * DIM)
                                 : (Asrc1 + ((size_t)bi * PTOT + (pos - NP)) * DIM);
        } else {
            aptr[i] = Asrc0 + (size_t)grow * DIM;
        }
    }

    f32x4 acc[4][4] = {};
    for (int k0 = 0; k0 < DIM; k0 += 32) {
        // issue global loads (overlaps previous iteration's compute)
        float4 a0[2], a1[2];
        f16x8 vbh[2], vbl[2];
        #pragma unroll
        for (int i = 0; i < 2; ++i) {
            a0[i] = *(const float4*)(aptr[i] + k0 + asl[i] * 8);
            a1[i] = *(const float4*)(aptr[i] + k0 + asl[i] * 8 + 4);
            size_t bo = (size_t)(n0 + ar[i]) * DIM + k0 + asl[i] * 8;
            vbh[i] = *(const f16x8*)(BTh + bo);
            vbl[i] = *(const f16x8*)(BTl + bo);
        }
        __syncthreads();
        #pragma unroll
        for (int i = 0; i < 2; ++i) {
            f16x8 h, l;
            float vals[8] = {a0[i].x, a0[i].y, a0[i].z, a0[i].w,
                             a1[i].x, a1[i].y, a1[i].z, a1[i].w};
            #pragma unroll
            for (int j = 0; j < 8; ++j) {
                _Float16 hh = (_Float16)vals[j];
                h[j] = hh;
                l[j] = (_Float16)(vals[j] - (float)hh);
            }
            int o = hoff(ar[i], asl[i]);
            *(f16x8*)&Ah[o] = h;
            *(f16x8*)&Al[o] = l;
            *(f16x8*)&Bh[o] = vbh[i];
            *(f16x8*)&Bl[o] = vbl[i];
        }
        __syncthreads();
        // fragments + MFMA
        f16x8 afh[4], afl[4];
        #pragma unroll
        for (int m = 0; m < 4; ++m) {
            int o = hoff(wr * 64 + m * 16 + (lane & 15), kslot);
            afh[m] = *(const f16x8*)&Ah[o];
            afl[m] = *(const f16x8*)&Al[o];
        }
        #pragma unroll
        for (int n = 0; n < 4; ++n) {
            int o = hoff(wc * 64 + n * 16 + (lane & 15), kslot);
            f16x8 bfh = *(const f16x8*)&Bh[o];
            f16x8 bfl = *(const f16x8*)&Bl[o];
            #pragma unroll
            for (int m = 0; m < 4; ++m) {
                acc[m][n] = __builtin_amdgcn_mfma_f32_16x16x32_f16(afh[m], bfh, acc[m][n], 0, 0, 0);
                acc[m][n] = __builtin_amdgcn_mfma_f32_16x16x32_f16(afh[m], bfl, acc[m][n], 0, 0, 0);
                acc[m][n] = __builtin_amdgcn_mfma_f32_16x16x32_f16(afl[m], bfh, acc[m][n], 0, 0, 0);
            }
        }
    }
    // epilogue
    #pragma unroll
    for (int m = 0; m < 4; ++m) {
        #pragma unroll
        for (int n = 0; n < 4; ++n) {
            int gcol = n0 + wc * 64 + n * 16 + (lane & 15);
            int rbase = m0 + wr * 64 + m * 16 + (lane >> 4) * 4;
            if (MODE == 1) {
                #pragma unroll
                for (int r = 0; r < 4; ++r)
                    out0[(size_t)(rbase + r) * DIM + gcol] = acc[m][n][r];
            } else {
                int which = gcol >> 9, h = (gcol >> 6) & 7, d = gcol & 63;
                #pragma unroll
                for (int r = 0; r < 4; ++r) {
                    int row = rbase + r;
                    int bi = row / NTOT;
                    int p = row - bi * NTOT;
                    float v = acc[m][n][r];
                    if (which == 0) {
                        if (p < NP) out0[(((size_t)bi * Hh + h) * NP + p) * DH + d] = v * SCALE;
                    } else if (which == 1) {
                        out1[(((size_t)bi * Hh + h) * NTOT + p) * DH + d] = v;
                    } else {
                        out2[(((size_t)bi * Hh + h) * NTOT + p) * DH + d] = v;
                    }
                }
            }
        }
    }
}

// ---------------- K2: landmark means ----------------
__global__ __launch_bounds__(64) void k_land(const float* __restrict__ mq,
    const float* __restrict__ kb, float* __restrict__ ql, float* __restrict__ kl)
{
    const int d = threadIdx.x;
    int idx = blockIdx.x;
    if (idx < 2048) {
        int bh = idx >> 6, i = idx & 63;
        const float* src = mq + ((size_t)bh * NP + i * 64) * DH + d;
        float s = 0.f;
        for (int j = 0; j < 64; ++j) s += src[(size_t)j * DH];
        ql[((size_t)bh * 64 + i) * 64 + d] = s * (1.f / 64.f);
    } else {
        idx -= 2048;
        int bh = idx >> 6, i = idx & 63;
        const float* src = kb + ((size_t)bh * NTOT + i * 192) * DH + d;
        float s = 0.f;
        for (int j = 0; j < 192; ++j) s += src[(size_t)j * DH];
        kl[((size_t)bh * 64 + i) * 64 + d] = s * (1.f / 192.f);
    }
}

// ---------------- K3: attn2 = softmax(q_l @ k_l^T) ----------------
__global__ __launch_bounds__(256) void k_sim2(const float* __restrict__ ql,
    const float* __restrict__ kl, float* __restrict__ a2)
{
    __shared__ float qs[64][64];
    __shared__ float ks[64][65];
    __shared__ float S[64][65];
    const int tid = threadIdx.x;
    const int bh = blockIdx.x;
    for (int e = tid; e < 4096; e += 256) {
        qs[e >> 6][e & 63] = ql[(size_t)bh * 4096 + e];
        ks[e >> 6][e & 63] = kl[(size_t)bh * 4096 + e];
    }
    __syncthreads();
    for (int sI = 0; sI < 16; ++sI) {
        int e = (sI << 8) + tid;
        int i = e >> 6, j = e & 63;
        float acc = 0.f;
        #pragma unroll 16
        for (int d = 0; d < 64; ++d) acc = fmaf(qs[i][d], ks[j][d], acc);
        S[i][j] = acc;
    }
    __syncthreads();
    const int wv = tid >> 6, lane = tid & 63;
    for (int i = wv; i < 64; i += 4) {
        float v = S[i][lane];
        float mxv = v;
        #pragma unroll
        for (int off = 32; off; off >>= 1) mxv = fmaxf(mxv, __shfl_xor(mxv, off));
        float p = expf(v - mxv);
        float sm = p;
        #pragma unroll
        for (int off = 32; off; off >>= 1) sm += __shfl_xor(sm, off);
        a2[((size_t)bh * 64 + i) * 64 + lane] = p / sm;
    }
}

// ---------------- K4: global max of row/col abs-sums of attn2 ----------------
__global__ __launch_bounds__(256) void k_maxes(const float* __restrict__ a2,
    float* __restrict__ mx)
{
    __shared__ float red[256];
    const int tid = threadIdx.x;
    float mc = 0.f, mr = 0.f;
    for (int idx = tid; idx < 32 * 64; idx += 256) {
        int bh = idx >> 6, i = idx & 63;
        const float* base = a2 + (size_t)bh * 4096;
        float cs = 0.f, rs = 0.f;
        for (int j = 0; j < 64; ++j) {
            cs += fabsf(base[i * 64 + j]);
            rs += fabsf(base[j * 64 + i]);
        }
        mc = fmaxf(mc, cs); mr = fmaxf(mr, rs);
    }
    red[tid] = mc; __syncthreads();
    for (int s = 128; s; s >>= 1) { if (tid < s) red[tid] = fmaxf(red[tid], red[tid + s]); __syncthreads(); }
    if (tid == 0) mx[0] = red[0];
    __syncthreads();
    red[tid] = mr; __syncthreads();
    for (int s = 128; s; s >>= 1) { if (tid < s) red[tid] = fmaxf(red[tid], red[tid + s]); __syncthreads(); }
    if (tid == 0) mx[1] = red[0];
}

// ---------------- K5a: sim3 partials — flash over a 512-row chunk ----------------
__global__ __launch_bounds__(256) void k_sim3part(const float* __restrict__ ql,
    const float* __restrict__ kb, const float* __restrict__ vb,
    float* __restrict__ pacc, float* __restrict__ pm, float* __restrict__ pl)
{
    __shared__ float qs[64][68];
    __shared__ float kv[64][64];
    __shared__ float pss[64][68];
    const int bh = blockIdx.x, ch = blockIdx.y;
    const int tid = threadIdx.x;
    const int ty = tid >> 4, tx = tid & 15;

    for (int e = tid; e < 4096; e += 256) qs[e >> 6][e & 63] = ql[(size_t)bh * 4096 + e];

    float m_run[4] = {-INFINITY, -INFINITY, -INFINITY, -INFINITY};
    float l_run[4] = {};
    float acc[4][4] = {};

    const float* kc = kb + ((size_t)bh * NTOT + ch * CHUNK) * DH;
    const float* vc = vb + ((size_t)bh * NTOT + ch * CHUNK) * DH;

    for (int t = 0; t < CHUNK / 64; ++t) {
        __syncthreads();
        #pragma unroll
        for (int e = tid; e < 1024; e += 256) {
            int r = e >> 4, slot = e & 15;
            float4 kx = *(const float4*)(kc + ((size_t)(t * 64 + r)) * DH + (slot << 2));
            *(float4*)&kv[r][((slot ^ ((r >> 2) & 15)) << 2)] = kx;
        }
        __syncthreads();
        float s[4][4] = {};
        #pragma unroll
        for (int d4 = 0; d4 < 16; ++d4) {
            float4 qv[4], kvv[4];
            #pragma unroll
            for (int ii = 0; ii < 4; ++ii) qv[ii] = *(const float4*)&qs[(ty << 2) + ii][d4 << 2];
            #pragma unroll
            for (int jj = 0; jj < 4; ++jj)
                kvv[jj] = *(const float4*)&kv[(tx << 2) + jj][((d4 ^ tx) & 15) << 2];
            #pragma unroll
            for (int ii = 0; ii < 4; ++ii)
                #pragma unroll
                for (int jj = 0; jj < 4; ++jj) {
                    s[ii][jj] = fmaf(qv[ii].x, kvv[jj].x, s[ii][jj]);
                    s[ii][jj] = fmaf(qv[ii].y, kvv[jj].y, s[ii][jj]);
                    s[ii][jj] = fmaf(qv[ii].z, kvv[jj].z, s[ii][jj]);
                    s[ii][jj] = fmaf(qv[ii].w, kvv[jj].w, s[ii][jj]);
                }
        }
        #pragma unroll
        for (int ii = 0; ii < 4; ++ii) {
            float rmax = fmaxf(fmaxf(s[ii][0], s[ii][1]), fmaxf(s[ii][2], s[ii][3]));
            #pragma unroll
            for (int off = 8; off; off >>= 1) rmax = fmaxf(rmax, __shfl_xor(rmax, off));
            float mnew = fmaxf(m_run[ii], rmax);
            float corr = expf(m_run[ii] - mnew);
            float rs = 0.f;
            #pragma unroll
            for (int jj = 0; jj < 4; ++jj) { s[ii][jj] = expf(s[ii][jj] - mnew); rs += s[ii][jj]; }
            #pragma unroll
            for (int off = 8; off; off >>= 1) rs += __shfl_xor(rs, off);
            l_run[ii] = l_run[ii] * corr + rs;
            m_run[ii] = mnew;
            #pragma unroll
            for (int dd = 0; dd < 4; ++dd) acc[ii][dd] *= corr;
            *(float4*)&pss[(ty << 2) + ii][tx << 2] = make_float4(s[ii][0], s[ii][1], s[ii][2], s[ii][3]);
        }
        __syncthreads();
        #pragma unroll
        for (int e = tid; e < 1024; e += 256) {
            int r = e >> 4, slot = e & 15;
            float4 vx = *(const float4*)(vc + ((size_t)(t * 64 + r)) * DH + (slot << 2));
            *(float4*)&kv[r][((slot ^ ((r >> 2) & 15)) << 2)] = vx;
        }
        __syncthreads();
        #pragma unroll
        for (int j4 = 0; j4 < 16; ++j4) {
            float4 pv4[4], vv[4];
            #pragma unroll
            for (int ii = 0; ii < 4; ++ii) pv4[ii] = *(const float4*)&pss[(ty << 2) + ii][j4 << 2];
            #pragma unroll
            for (int jj = 0; jj < 4; ++jj)
                vv[jj] = *(const float4*)&kv[(j4 << 2) + jj][((tx ^ j4) & 15) << 2];
            #pragma unroll
            for (int ii = 0; ii < 4; ++ii) {
                #pragma unroll
                for (int jj = 0; jj < 4; ++jj) {
                    float pj = ((const float*)&pv4[ii])[jj];
                    #pragma unroll
                    for (int dd = 0; dd < 4; ++dd)
                        acc[ii][dd] = fmaf(pj, ((const float*)&vv[jj])[dd], acc[ii][dd]);
                }
            }
        }
    }
    const size_t base = ((size_t)bh * NCH + ch) * 64;
    #pragma unroll
    for (int ii = 0; ii < 4; ++ii) {
        int i = (ty << 2) + ii;
        *(float4*)(pacc + (base + i) * 64 + (tx << 2)) =
            make_float4(acc[ii][0], acc[ii][1], acc[ii][2], acc[ii][3]);
        if (tx == 0) { pm[base + i] = m_run[ii]; pl[base + i] = l_run[ii]; }
    }
}

// ---------------- K5b: combine sim3 partials -> t3 ----------------
__global__ __launch_bounds__(256) void k_sim3comb(const float* __restrict__ pacc,
    const float* __restrict__ pm, const float* __restrict__ pl, float* __restrict__ t3)
{
    __shared__ float w[NCH][64];
    __shared__ float Linv[64];
    const int bh = blockIdx.x;
    const int tid = threadIdx.x;
    if (tid < 64) {
        float M = -INFINITY;
        for (int c = 0; c < NCH; ++c)
            M = fmaxf(M, pm[((size_t)bh * NCH + c) * 64 + tid]);
        float L = 0.f;
        for (int c = 0; c < NCH; ++c) {
            float e = expf(pm[((size_t)bh * NCH + c) * 64 + tid] - M);
            w[c][tid] = e;
            L = fmaf(e, pl[((size_t)bh * NCH + c) * 64 + tid], L);
        }
        Linv[tid] = 1.f / L;
    }
    __syncthreads();
    const int wv = tid >> 6, lane = tid & 63;
    for (int p = 0; p < 16; ++p) {
        int i = (p << 2) + wv;
        float o = 0.f;
        for (int c = 0; c < NCH; ++c)
            o = fmaf(w[c][i], pacc[(((size_t)bh * NCH + c) * 64 + i) * 64 + lane], o);
        t3[((size_t)bh * 64 + i) * 64 + lane] = o * Linv[i];
    }
}

// ---------------- K6: pinv iterations (LDS-resident, 48KB) + t2 = z @ t3 ----------------
__device__ __forceinline__ void mm64r(float* __restrict__ C, const float* A,
    const float* Bm, const float* S, float sa, float sm, int tid)
{
    float r[16];
    __syncthreads();
    #pragma unroll
    for (int s = 0; s < 16; ++s) {
        int e = (s << 8) + tid;
        int i = e >> 6, j = e & 63;
        float acc = 0.f;
        #pragma unroll 16
        for (int k = 0; k < 64; ++k)
            acc = fmaf(A[(i << 6) + k], Bm[(k << 6) + j], acc);
        float v = sm * acc;
        if (S) v = fmaf(sa, S[e], v);
        r[s] = v;
    }
    __syncthreads();
    #pragma unroll
    for (int s = 0; s < 16; ++s) C[(s << 8) + tid] = r[s];
    __syncthreads();
}

__device__ __forceinline__ void mm64g(float* __restrict__ C, const float* __restrict__ Ag,
    const float* __restrict__ Bm, int tid)
{
    float r[16];
    __syncthreads();
    #pragma unroll
    for (int s = 0; s < 16; ++s) {
        int e = (s << 8) + tid;
        int i = e >> 6, j = e & 63;
        float acc = 0.f;
        #pragma unroll 16
        for (int k = 0; k < 64; ++k)
            acc = fmaf(Ag[(i << 6) + k], Bm[(k << 6) + j], acc);
        r[s] = acc;
    }
    __syncthreads();
    #pragma unroll
    for (int s = 0; s < 16; ++s) C[(s << 8) + tid] = r[s];
    __syncthreads();
}

__global__ __launch_bounds__(256) void k_pinv(const float* __restrict__ attn2,
    const float* __restrict__ mx, const float* __restrict__ t3g, float* __restrict__ t2g)
{
    __shared__ float Zs[4096], Ab[4096], Db[4096];
    const int tid = threadIdx.x;
    const int bh = blockIdx.x;
    const float inv = 1.0f / (mx[0] * mx[1]);
    const float* a2 = attn2 + (size_t)bh * 4096;
    for (int e = tid; e < 4096; e += 256) {
        int i = e >> 6, j = e & 63;
        Zs[e] = a2[(j << 6) + i] * inv;
    }
    for (int it = 0; it < 6; ++it) {
        mm64g(Ab, a2, Zs, tid);
        mm64r(Db, Ab, Ab, Ab, 7.f, -1.f, tid);
        for (int e = tid; e < 4096; e += 256) {
            int i = e >> 6, j = e & 63;
            Db[e] = ((i == j) ? 15.f : 0.f) - Db[e];
        }
        mm64r(Ab, Zs, Ab, nullptr, 0.f, 1.f, tid);
        mm64r(Zs, Ab, Db, Zs, 3.25f, -0.25f, tid);
    }
    for (int e = tid; e < 4096; e += 256) Ab[e] = t3g[(size_t)bh * 4096 + e];
    mm64r(Db, Zs, Ab, nullptr, 0.f, 1.f, tid);
    for (int e = tid; e < 4096; e += 256) t2g[(size_t)bh * 4096 + e] = Db[e];
}

// ---------------- K7: out1 = softmax(mq@k_l^T) @ t2 + depthwise conv(v) ----------------
__global__ __launch_bounds__(256) void k_attn1(const float* __restrict__ mq,
    const float* __restrict__ kl, const float* __restrict__ t2,
    const float* __restrict__ vb, const float* __restrict__ cwg,
    float* __restrict__ opre)
{
    __shared__ float kls[64][65];
    __shared__ float t2s[64][65];
    __shared__ float cw[33];
    const int bh = blockIdx.x;
    const int b = bh >> 3, h = bh & 7;
    const int rg = blockIdx.y;
    const int tid = threadIdx.x;
    const int wv = tid >> 6, lane = tid & 63;
    for (int e = tid; e < 4096; e += 256) {
        kls[e >> 6][e & 63] = kl[(size_t)bh * 4096 + e];
        t2s[e >> 6][e & 63] = t2[(size_t)bh * 4096 + e];
    }
    if (tid < 33) cw[tid] = cwg[h * 33 + tid];
    __syncthreads();
    const float* mqb = mq + (size_t)bh * NP * DH;
    const float* vp = vb + (size_t)bh * NTOT * DH + lane;
    for (int rr = 0; rr < 16; ++rr) {
        int row = (rg << 6) + (wv << 4) + rr;
        float qv = mqb[(size_t)row * DH + lane];
        float s = 0.f;
        #pragma unroll 16
        for (int d = 0; d < 64; ++d) s = fmaf(__shfl(qv, d), kls[lane][d], s);
        float mxv = s;
        #pragma unroll
        for (int off = 32; off; off >>= 1) mxv = fmaxf(mxv, __shfl_xor(mxv, off));
        float p = expf(s - mxv);
        float psum = p;
        #pragma unroll
        for (int off = 32; off; off >>= 1) psum += __shfl_xor(psum, off);
        p /= psum;
        float o = 0.f;
        #pragma unroll 16
        for (int j = 0; j < 64; ++j) o = fmaf(__shfl(p, j), t2s[j][lane], o);
        float c = 0.f;
        int kk0 = (row >= 16) ? 0 : (16 - row);
        for (int k = kk0; k < 33; ++k)
            c = fmaf(cw[k], vp[(size_t)(row - 16 + k) * DH], c);
        opre[((size_t)b * NP + row) * DIM + h * DH + lane] = o + c;
    }
}

extern "C" void kernel_launch(void* const* d_in, const int* in_sizes, int n_in,
                              void* d_out, int out_size, void* d_ws, size_t ws_size,
                              hipStream_t stream)
{
    const float* x   = (const float*)d_in[0];
    const float* ps  = (const float*)d_in[1];
    const float* wq  = (const float*)d_in[2];
    const float* wo  = (const float*)d_in[3];
    const float* cwg = (const float*)d_in[4];
    float* out = (float*)d_out;
    float* ws  = (float*)d_ws;

    float* mq   = out;               // d_out doubles as mq scratch; k_gemm<1> overwrites last
    float* kb   = ws + OFF_K;
    float* vb   = ws + OFF_V;
    float* ql   = ws + OFF_QL;
    float* kl   = ws + OFF_KL;
    float* a2   = ws + OFF_A2;
    float* t3   = ws + OFF_T3;
    float* t2   = ws + OFF_T2;
    float* mx   = ws + OFF_MAX;
    float* opre = ws + OFF_OPRE;
    // sim3 partials alias opre (consumed before k_attn1 writes opre)
    float* pacc = opre;
    float* pm   = opre + 3145728ull;
    float* pl   = pm + 49152ull;
    // BTq (w_qkv^T fp16 hi/lo) aliases ql.. region: alive only during k_gemm<0>
    _Float16* BTqh = (_Float16*)(ws + OFF_QL);
    _Float16* BTql = BTqh + 1536 * 512;
    // BTo (w_out^T fp16 hi/lo) aliases kb region: written after kb's last use
    _Float16* BToh = (_Float16*)(ws + OFF_K);
    _Float16* BTol = BToh + 512 * 512;

    k_cvtw        <<<dim3(24, 8), 256, 0, stream>>>(wq, BTqh, BTql, 512, 1536);
    k_gemm_split<0><<<dim3(12, 384), 256, 0, stream>>>(x, ps, BTqh, BTql, mq, kb, vb);
    k_land        <<<4096, 64, 0, stream>>>(mq, kb, ql, kl);
    k_sim2        <<<32, 256, 0, stream>>>(ql, kl, a2);
    k_maxes       <<<1, 256, 0, stream>>>(a2, mx);
    k_sim3part    <<<dim3(32, NCH), 256, 0, stream>>>(ql, kb, vb, pacc, pm, pl);
    k_sim3comb    <<<32, 256, 0, stream>>>(pacc, pm, pl, t3);
    k_cvtw        <<<dim3(8, 8), 256, 0, stream>>>(wo, BToh, BTol, 512, 512);
    k_pinv        <<<32, 256, 0, stream>>>(a2, mx, t3, t2);
    k_attn1       <<<dim3(32, 64), 256, 0, stream>>>(mq, kl, t2, vb, cwg, opre);
    k_gemm_split<1><<<dim3(4, 128), 256, 0, stream>>>(opre, nullptr, BToh, BTol, out, nullptr, nullptr);
}

// Round 5
// 1095.185 us; speedup vs baseline: 2.5042x; 1.0251x over previous
//
#include <hip/hip_runtime.h>
#include <math.h>

#define Bb 4
#define Hh 8
#define NP 4096
#define PTOT 8192
#define NTOT 12288
#define DIM 512
#define DH 64
#define SCALE 0.125f
#define NCH 24
#define CHUNK 512

typedef __attribute__((ext_vector_type(8))) _Float16 f16x8;
typedef __attribute__((ext_vector_type(4))) float f32x4;

// ---------------- workspace layout (float offsets) ----------------
#define SZ_K    (4ull*8*12288*64)      // 25,165,824
#define SZ_L    (32ull*64*64)          // 131,072
#define OFF_K    0ull
#define OFF_V    (OFF_K + SZ_K)
#define OFF_QL   (OFF_V + SZ_K)
#define OFF_KL   (OFF_QL + SZ_L)
#define OFF_A2   (OFF_KL + SZ_L)
#define OFF_T3   (OFF_A2 + SZ_L)
#define OFF_T2   (OFF_T3 + SZ_L)
#define OFF_MAX  (OFF_T2 + SZ_L)
#define OFF_OPRE (OFF_MAX + 16ull)
// total = 59,375,648 floats (237.5 MB) — proven fit.
// BTq aliases [OFF_QL...), BTo aliases kb (dead after k_sim3part).

// ---------------- transpose + fp16-split weights: w[K][N] -> BT[N][K] hi/lo ----------------
__global__ __launch_bounds__(256) void k_cvtw(const float* __restrict__ w,
    _Float16* __restrict__ bh, _Float16* __restrict__ bl, int K, int N)
{
    __shared__ float t[64][65];
    const int n0 = blockIdx.x * 64, k0 = blockIdx.y * 64;
    const int tid = threadIdx.x;
    #pragma unroll
    for (int i = 0; i < 4; ++i) {
        int r = (tid >> 4) + i * 16;
        int c = (tid & 15) * 4;
        float4 v = *(const float4*)(w + (size_t)(k0 + r) * N + n0 + c);
        t[r][c] = v.x; t[r][c+1] = v.y; t[r][c+2] = v.z; t[r][c+3] = v.w;
    }
    __syncthreads();
    const int n = tid >> 2, kq = (tid & 3) * 16;
    f16x8 h8[2], l8[2];
    #pragma unroll
    for (int j = 0; j < 16; ++j) {
        float a = t[kq + j][n];
        _Float16 hh = (_Float16)a;
        _Float16 ll = (_Float16)(a - (float)hh);
        h8[j >> 3][j & 7] = hh;
        l8[j >> 3][j & 7] = ll;
    }
    size_t o = (size_t)(n0 + n) * K + k0 + kq;
    *(f16x8*)(bh + o) = h8[0]; *(f16x8*)(bh + o + 8) = h8[1];
    *(f16x8*)(bl + o) = l8[0]; *(f16x8*)(bl + o + 8) = l8[1];
}

// ---------------- fp16-split MFMA GEMM (3 products: hh + hl + lh) ----------------
__device__ __forceinline__ int hoff(int r, int slot) {
    return r * 32 + (((slot ^ (r >> 1)) & 3) << 3);
}

template<int MODE>
__global__ __launch_bounds__(256) void k_gemm_split(
    const float* __restrict__ Asrc0, const float* __restrict__ Asrc1,
    const _Float16* __restrict__ BTh, const _Float16* __restrict__ BTl,
    float* __restrict__ out0, float* __restrict__ out1, float* __restrict__ out2)
{
    __shared__ __align__(16) _Float16 Ah[128 * 32], Al[128 * 32];
    __shared__ __align__(16) _Float16 Bh[128 * 32], Bl[128 * 32];
    const int tid = threadIdx.x;
    const int n0 = blockIdx.x * 128;
    const int m0 = blockIdx.y * 128;
    const int wv = tid >> 6, lane = tid & 63;
    const int wr = wv >> 1, wc = wv & 1;
    const int kslot = lane >> 4;

    int ar[2], asl[2];
    const float* aptr[2];
    #pragma unroll
    for (int i = 0; i < 2; ++i) {
        int id = tid + 256 * i;
        ar[i] = id >> 2; asl[i] = id & 3;
        int grow = m0 + ar[i];
        if (MODE == 0) {
            int bi = grow / NTOT;
            int pos = grow - bi * NTOT;
            aptr[i] = (pos < NP) ? (Asrc0 + ((size_t)bi * NP + pos) * DIM)
                                 : (Asrc1 + ((size_t)bi * PTOT + (pos - NP)) * DIM);
        } else {
            aptr[i] = Asrc0 + (size_t)grow * DIM;
        }
    }

    f32x4 acc[4][4] = {};
    for (int k0 = 0; k0 < DIM; k0 += 32) {
        float4 a0[2], a1[2];
        f16x8 vbh[2], vbl[2];
        #pragma unroll
        for (int i = 0; i < 2; ++i) {
            a0[i] = *(const float4*)(aptr[i] + k0 + asl[i] * 8);
            a1[i] = *(const float4*)(aptr[i] + k0 + asl[i] * 8 + 4);
            size_t bo = (size_t)(n0 + ar[i]) * DIM + k0 + asl[i] * 8;
            vbh[i] = *(const f16x8*)(BTh + bo);
            vbl[i] = *(const f16x8*)(BTl + bo);
        }
        __syncthreads();
        #pragma unroll
        for (int i = 0; i < 2; ++i) {
            f16x8 h, l;
            float vals[8] = {a0[i].x, a0[i].y, a0[i].z, a0[i].w,
                             a1[i].x, a1[i].y, a1[i].z, a1[i].w};
            #pragma unroll
            for (int j = 0; j < 8; ++j) {
                _Float16 hh = (_Float16)vals[j];
                h[j] = hh;
                l[j] = (_Float16)(vals[j] - (float)hh);
            }
            int o = hoff(ar[i], asl[i]);
            *(f16x8*)&Ah[o] = h;
            *(f16x8*)&Al[o] = l;
            *(f16x8*)&Bh[o] = vbh[i];
            *(f16x8*)&Bl[o] = vbl[i];
        }
        __syncthreads();
        f16x8 afh[4], afl[4];
        #pragma unroll
        for (int m = 0; m < 4; ++m) {
            int o = hoff(wr * 64 + m * 16 + (lane & 15), kslot);
            afh[m] = *(const f16x8*)&Ah[o];
            afl[m] = *(const f16x8*)&Al[o];
        }
        #pragma unroll
        for (int n = 0; n < 4; ++n) {
            int o = hoff(wc * 64 + n * 16 + (lane & 15), kslot);
            f16x8 bfh = *(const f16x8*)&Bh[o];
            f16x8 bfl = *(const f16x8*)&Bl[o];
            #pragma unroll
            for (int m = 0; m < 4; ++m) {
                acc[m][n] = __builtin_amdgcn_mfma_f32_16x16x32_f16(afh[m], bfh, acc[m][n], 0, 0, 0);
                acc[m][n] = __builtin_amdgcn_mfma_f32_16x16x32_f16(afh[m], bfl, acc[m][n], 0, 0, 0);
                acc[m][n] = __builtin_amdgcn_mfma_f32_16x16x32_f16(afl[m], bfh, acc[m][n], 0, 0, 0);
            }
        }
    }
    #pragma unroll
    for (int m = 0; m < 4; ++m) {
        #pragma unroll
        for (int n = 0; n < 4; ++n) {
            int gcol = n0 + wc * 64 + n * 16 + (lane & 15);
            int rbase = m0 + wr * 64 + m * 16 + (lane >> 4) * 4;
            if (MODE == 1) {
                #pragma unroll
                for (int r = 0; r < 4; ++r)
                    out0[(size_t)(rbase + r) * DIM + gcol] = acc[m][n][r];
            } else {
                int which = gcol >> 9, h = (gcol >> 6) & 7, d = gcol & 63;
                #pragma unroll
                for (int r = 0; r < 4; ++r) {
                    int row = rbase + r;
                    int bi = row / NTOT;
                    int p = row - bi * NTOT;
                    float v = acc[m][n][r];
                    if (which == 0) {
                        if (p < NP) out0[(((size_t)bi * Hh + h) * NP + p) * DH + d] = v * SCALE;
                    } else if (which == 1) {
                        out1[(((size_t)bi * Hh + h) * NTOT + p) * DH + d] = v;
                    } else {
                        out2[(((size_t)bi * Hh + h) * NTOT + p) * DH + d] = v;
                    }
                }
            }
        }
    }
}

// ---------------- K2: landmark means (vectorized) ----------------
// one block per (bh, landmark): idx<2048 -> ql (64 rows), else kl (192 rows)
__global__ __launch_bounds__(256) void k_land(const float* __restrict__ mq,
    const float* __restrict__ kb, float* __restrict__ ql, float* __restrict__ kl)
{
    __shared__ float part[16][64];
    int idx = blockIdx.x;
    const int tid = threadIdx.x;
    const int rg = tid >> 4, c4 = (tid & 15) << 2;
    const float* src;
    float* dst;
    int R; float sc;
    if (idx < 2048) {
        int bh = idx >> 6, i = idx & 63;
        src = mq + ((size_t)bh * NP + i * 64) * DH;
        dst = ql + ((size_t)bh * 64 + i) * 64;
        R = 64; sc = 1.f / 64.f;
    } else {
        idx -= 2048;
        int bh = idx >> 6, i = idx & 63;
        src = kb + ((size_t)bh * NTOT + i * 192) * DH;
        dst = kl + ((size_t)bh * 64 + i) * 64;
        R = 192; sc = 1.f / 192.f;
    }
    float4 a = make_float4(0.f, 0.f, 0.f, 0.f);
    for (int r = rg; r < R; r += 16) {
        float4 v = *(const float4*)(src + (size_t)r * DH + c4);
        a.x += v.x; a.y += v.y; a.z += v.z; a.w += v.w;
    }
    *(float4*)&part[rg][c4] = a;
    __syncthreads();
    if (tid < 64) {
        float s = 0.f;
        #pragma unroll
        for (int g = 0; g < 16; ++g) s += part[g][tid];
        dst[tid] = s * sc;
    }
}

// ---------------- K3: attn2 = softmax(q_l @ k_l^T) ----------------
__global__ __launch_bounds__(256) void k_sim2(const float* __restrict__ ql,
    const float* __restrict__ kl, float* __restrict__ a2)
{
    __shared__ float qs[64][64];
    __shared__ float ks[64][65];
    __shared__ float S[64][65];
    const int tid = threadIdx.x;
    const int bh = blockIdx.x;
    for (int e = tid; e < 4096; e += 256) {
        qs[e >> 6][e & 63] = ql[(size_t)bh * 4096 + e];
        ks[e >> 6][e & 63] = kl[(size_t)bh * 4096 + e];
    }
    __syncthreads();
    for (int sI = 0; sI < 16; ++sI) {
        int e = (sI << 8) + tid;
        int i = e >> 6, j = e & 63;
        float acc = 0.f;
        #pragma unroll 16
        for (int d = 0; d < 64; ++d) acc = fmaf(qs[i][d], ks[j][d], acc);
        S[i][j] = acc;
    }
    __syncthreads();
    const int wv = tid >> 6, lane = tid & 63;
    for (int i = wv; i < 64; i += 4) {
        float v = S[i][lane];
        float mxv = v;
        #pragma unroll
        for (int off = 32; off; off >>= 1) mxv = fmaxf(mxv, __shfl_xor(mxv, off));
        float p = expf(v - mxv);
        float sm = p;
        #pragma unroll
        for (int off = 32; off; off >>= 1) sm += __shfl_xor(sm, off);
        a2[((size_t)bh * 64 + i) * 64 + lane] = p / sm;
    }
}

// ---------------- K4: global max of row/col abs-sums of attn2 ----------------
__global__ __launch_bounds__(256) void k_maxes(const float* __restrict__ a2,
    float* __restrict__ mx)
{
    __shared__ float red[256];
    const int tid = threadIdx.x;
    float mc = 0.f, mr = 0.f;
    for (int idx = tid; idx < 32 * 64; idx += 256) {
        int bh = idx >> 6, i = idx & 63;
        const float* base = a2 + (size_t)bh * 4096;
        float cs = 0.f, rs = 0.f;
        for (int j = 0; j < 64; ++j) {
            cs += fabsf(base[i * 64 + j]);
            rs += fabsf(base[j * 64 + i]);
        }
        mc = fmaxf(mc, cs); mr = fmaxf(mr, rs);
    }
    red[tid] = mc; __syncthreads();
    for (int s = 128; s; s >>= 1) { if (tid < s) red[tid] = fmaxf(red[tid], red[tid + s]); __syncthreads(); }
    if (tid == 0) mx[0] = red[0];
    __syncthreads();
    red[tid] = mr; __syncthreads();
    for (int s = 128; s; s >>= 1) { if (tid < s) red[tid] = fmaxf(red[tid], red[tid + s]); __syncthreads(); }
    if (tid == 0) mx[1] = red[0];
}

// ---------------- K5a: sim3 partials — flash over a 512-row chunk ----------------
__global__ __launch_bounds__(256) void k_sim3part(const float* __restrict__ ql,
    const float* __restrict__ kb, const float* __restrict__ vb,
    float* __restrict__ pacc, float* __restrict__ pm, float* __restrict__ pl)
{
    __shared__ float qs[64][68];
    __shared__ float kv[64][64];
    __shared__ float pss[64][68];
    const int bh = blockIdx.x, ch = blockIdx.y;
    const int tid = threadIdx.x;
    const int ty = tid >> 4, tx = tid & 15;

    for (int e = tid; e < 4096; e += 256) qs[e >> 6][e & 63] = ql[(size_t)bh * 4096 + e];

    float m_run[4] = {-INFINITY, -INFINITY, -INFINITY, -INFINITY};
    float l_run[4] = {};
    float acc[4][4] = {};

    const float* kc = kb + ((size_t)bh * NTOT + ch * CHUNK) * DH;
    const float* vc = vb + ((size_t)bh * NTOT + ch * CHUNK) * DH;

    for (int t = 0; t < CHUNK / 64; ++t) {
        __syncthreads();
        #pragma unroll
        for (int e = tid; e < 1024; e += 256) {
            int r = e >> 4, slot = e & 15;
            float4 kx = *(const float4*)(kc + ((size_t)(t * 64 + r)) * DH + (slot << 2));
            *(float4*)&kv[r][((slot ^ ((r >> 2) & 15)) << 2)] = kx;
        }
        __syncthreads();
        float s[4][4] = {};
        #pragma unroll
        for (int d4 = 0; d4 < 16; ++d4) {
            float4 qv[4], kvv[4];
            #pragma unroll
            for (int ii = 0; ii < 4; ++ii) qv[ii] = *(const float4*)&qs[(ty << 2) + ii][d4 << 2];
            #pragma unroll
            for (int jj = 0; jj < 4; ++jj)
                kvv[jj] = *(const float4*)&kv[(tx << 2) + jj][((d4 ^ tx) & 15) << 2];
            #pragma unroll
            for (int ii = 0; ii < 4; ++ii)
                #pragma unroll
                for (int jj = 0; jj < 4; ++jj) {
                    s[ii][jj] = fmaf(qv[ii].x, kvv[jj].x, s[ii][jj]);
                    s[ii][jj] = fmaf(qv[ii].y, kvv[jj].y, s[ii][jj]);
                    s[ii][jj] = fmaf(qv[ii].z, kvv[jj].z, s[ii][jj]);
                    s[ii][jj] = fmaf(qv[ii].w, kvv[jj].w, s[ii][jj]);
                }
        }
        #pragma unroll
        for (int ii = 0; ii < 4; ++ii) {
            float rmax = fmaxf(fmaxf(s[ii][0], s[ii][1]), fmaxf(s[ii][2], s[ii][3]));
            #pragma unroll
            for (int off = 8; off; off >>= 1) rmax = fmaxf(rmax, __shfl_xor(rmax, off));
            float mnew = fmaxf(m_run[ii], rmax);
            float corr = expf(m_run[ii] - mnew);
            float rs = 0.f;
            #pragma unroll
            for (int jj = 0; jj < 4; ++jj) { s[ii][jj] = expf(s[ii][jj] - mnew); rs += s[ii][jj]; }
            #pragma unroll
            for (int off = 8; off; off >>= 1) rs += __shfl_xor(rs, off);
            l_run[ii] = l_run[ii] * corr + rs;
            m_run[ii] = mnew;
            #pragma unroll
            for (int dd = 0; dd < 4; ++dd) acc[ii][dd] *= corr;
            *(float4*)&pss[(ty << 2) + ii][tx << 2] = make_float4(s[ii][0], s[ii][1], s[ii][2], s[ii][3]);
        }
        __syncthreads();
        #pragma unroll
        for (int e = tid; e < 1024; e += 256) {
            int r = e >> 4, slot = e & 15;
            float4 vx = *(const float4*)(vc + ((size_t)(t * 64 + r)) * DH + (slot << 2));
            *(float4*)&kv[r][((slot ^ ((r >> 2) & 15)) << 2)] = vx;
        }
        __syncthreads();
        #pragma unroll
        for (int j4 = 0; j4 < 16; ++j4) {
            float4 pv4[4], vv[4];
            #pragma unroll
            for (int ii = 0; ii < 4; ++ii) pv4[ii] = *(const float4*)&pss[(ty << 2) + ii][j4 << 2];
            #pragma unroll
            for (int jj = 0; jj < 4; ++jj)
                vv[jj] = *(const float4*)&kv[(j4 << 2) + jj][((tx ^ j4) & 15) << 2];
            #pragma unroll
            for (int ii = 0; ii < 4; ++ii) {
                #pragma unroll
                for (int jj = 0; jj < 4; ++jj) {
                    float pj = ((const float*)&pv4[ii])[jj];
                    #pragma unroll
                    for (int dd = 0; dd < 4; ++dd)
                        acc[ii][dd] = fmaf(pj, ((const float*)&vv[jj])[dd], acc[ii][dd]);
                }
            }
        }
    }
    const size_t base = ((size_t)bh * NCH + ch) * 64;
    #pragma unroll
    for (int ii = 0; ii < 4; ++ii) {
        int i = (ty << 2) + ii;
        *(float4*)(pacc + (base + i) * 64 + (tx << 2)) =
            make_float4(acc[ii][0], acc[ii][1], acc[ii][2], acc[ii][3]);
        if (tx == 0) { pm[base + i] = m_run[ii]; pl[base + i] = l_run[ii]; }
    }
}

// ---------------- K5b: combine sim3 partials -> t3 ----------------
__global__ __launch_bounds__(256) void k_sim3comb(const float* __restrict__ pacc,
    const float* __restrict__ pm, const float* __restrict__ pl, float* __restrict__ t3)
{
    __shared__ float w[NCH][64];
    __shared__ float Linv[64];
    const int bh = blockIdx.x;
    const int tid = threadIdx.x;
    if (tid < 64) {
        float M = -INFINITY;
        for (int c = 0; c < NCH; ++c)
            M = fmaxf(M, pm[((size_t)bh * NCH + c) * 64 + tid]);
        float L = 0.f;
        for (int c = 0; c < NCH; ++c) {
            float e = expf(pm[((size_t)bh * NCH + c) * 64 + tid] - M);
            w[c][tid] = e;
            L = fmaf(e, pl[((size_t)bh * NCH + c) * 64 + tid], L);
        }
        Linv[tid] = 1.f / L;
    }
    __syncthreads();
    const int wv = tid >> 6, lane = tid & 63;
    for (int p = 0; p < 16; ++p) {
        int i = (p << 2) + wv;
        float o = 0.f;
        for (int c = 0; c < NCH; ++c)
            o = fmaf(w[c][i], pacc[(((size_t)bh * NCH + c) * 64 + i) * 64 + lane], o);
        t3[((size_t)bh * 64 + i) * 64 + lane] = o * Linv[i];
    }
}

// ---------------- K6: pinv iterations (LDS-resident, 48KB) + t2 = z @ t3 ----------------
__device__ __forceinline__ void mm64r(float* __restrict__ C, const float* A,
    const float* Bm, const float* S, float sa, float sm, int tid)
{
    float r[16];
    __syncthreads();
    #pragma unroll
    for (int s = 0; s < 16; ++s) {
        int e = (s << 8) + tid;
        int i = e >> 6, j = e & 63;
        float acc = 0.f;
        #pragma unroll 16
        for (int k = 0; k < 64; ++k)
            acc = fmaf(A[(i << 6) + k], Bm[(k << 6) + j], acc);
        float v = sm * acc;
        if (S) v = fmaf(sa, S[e], v);
        r[s] = v;
    }
    __syncthreads();
    #pragma unroll
    for (int s = 0; s < 16; ++s) C[(s << 8) + tid] = r[s];
    __syncthreads();
}

__device__ __forceinline__ void mm64g(float* __restrict__ C, const float* __restrict__ Ag,
    const float* __restrict__ Bm, int tid)
{
    float r[16];
    __syncthreads();
    #pragma unroll
    for (int s = 0; s < 16; ++s) {
        int e = (s << 8) + tid;
        int i = e >> 6, j = e & 63;
        float acc = 0.f;
        #pragma unroll 16
        for (int k = 0; k < 64; ++k)
            acc = fmaf(Ag[(i << 6) + k], Bm[(k << 6) + j], acc);
        r[s] = acc;
    }
    __syncthreads();
    #pragma unroll
    for (int s = 0; s < 16; ++s) C[(s << 8) + tid] = r[s];
    __syncthreads();
}

__global__ __launch_bounds__(256) void k_pinv(const float* __restrict__ attn2,
    const float* __restrict__ mx, const float* __restrict__ t3g, float* __restrict__ t2g)
{
    __shared__ float Zs[4096], Ab[4096], Db[4096];
    const int tid = threadIdx.x;
    const int bh = blockIdx.x;
    const float inv = 1.0f / (mx[0] * mx[1]);
    const float* a2 = attn2 + (size_t)bh * 4096;
    for (int e = tid; e < 4096; e += 256) {
        int i = e >> 6, j = e & 63;
        Zs[e] = a2[(j << 6) + i] * inv;
    }
    for (int it = 0; it < 6; ++it) {
        mm64g(Ab, a2, Zs, tid);
        mm64r(Db, Ab, Ab, Ab, 7.f, -1.f, tid);
        for (int e = tid; e < 4096; e += 256) {
            int i = e >> 6, j = e & 63;
            Db[e] = ((i == j) ? 15.f : 0.f) - Db[e];
        }
        mm64r(Ab, Zs, Ab, nullptr, 0.f, 1.f, tid);
        mm64r(Zs, Ab, Db, Zs, 3.25f, -0.25f, tid);
    }
    for (int e = tid; e < 4096; e += 256) Ab[e] = t3g[(size_t)bh * 4096 + e];
    mm64r(Db, Zs, Ab, nullptr, 0.f, 1.f, tid);
    for (int e = tid; e < 4096; e += 256) t2g[(size_t)bh * 4096 + e] = Db[e];
}

// ---------------- K7: out1 = softmax(mq@k_l^T) @ t2 + depthwise conv(v) ----------------
// register-tiled: grid (32 bh, 16 groups of 256 rows), 256 thr, 4x4 per thread
__global__ __launch_bounds__(256) void k_attn1(const float* __restrict__ mq,
    const float* __restrict__ kl, const float* __restrict__ t2,
    const float* __restrict__ vb, const float* __restrict__ cwg,
    float* __restrict__ opre)
{
    __shared__ float kls[64][64];   // swizzled
    __shared__ float t2s[64][64];   // swizzled
    __shared__ float qp[64][68];    // time-shared: q subtile, then P
    __shared__ float cw[33];
    const int bh = blockIdx.x;
    const int b = bh >> 3, h = bh & 7;
    const int rg = blockIdx.y;
    const int tid = threadIdx.x;
    const int ty = tid >> 4, tx = tid & 15;

    for (int e = tid; e < 1024; e += 256) {
        int r = e >> 4, slot = e & 15;
        float4 kx = *(const float4*)(kl + (size_t)bh * 4096 + r * 64 + (slot << 2));
        *(float4*)&kls[r][((slot ^ ((r >> 2) & 15)) << 2)] = kx;
        float4 tx4 = *(const float4*)(t2 + (size_t)bh * 4096 + r * 64 + (slot << 2));
        *(float4*)&t2s[r][((slot ^ ((r >> 2) & 15)) << 2)] = tx4;
    }
    if (tid < 33) cw[tid] = cwg[h * 33 + tid];

    const float* mqb = mq + (size_t)bh * NP * DH;
    const float* vbase = vb + (size_t)bh * NTOT * DH;

    for (int sub = 0; sub < 4; ++sub) {
        const int row0 = (rg << 8) + (sub << 6);
        __syncthreads();   // kls/t2s ready (iter 0); prev PV done with qp
        for (int e = tid; e < 1024; e += 256) {
            int r = e >> 4, slot = e & 15;
            *(float4*)&qp[r][slot << 2] =
                *(const float4*)(mqb + (size_t)(row0 + r) * DH + (slot << 2));
        }
        __syncthreads();
        // S = q @ kl^T
        float s[4][4] = {};
        #pragma unroll
        for (int d4 = 0; d4 < 16; ++d4) {
            float4 qv[4], kvv[4];
            #pragma unroll
            for (int ii = 0; ii < 4; ++ii) qv[ii] = *(const float4*)&qp[(ty << 2) + ii][d4 << 2];
            #pragma unroll
            for (int jj = 0; jj < 4; ++jj)
                kvv[jj] = *(const float4*)&kls[(tx << 2) + jj][((d4 ^ tx) & 15) << 2];
            #pragma unroll
            for (int ii = 0; ii < 4; ++ii)
                #pragma unroll
                for (int jj = 0; jj < 4; ++jj) {
                    s[ii][jj] = fmaf(qv[ii].x, kvv[jj].x, s[ii][jj]);
                    s[ii][jj] = fmaf(qv[ii].y, kvv[jj].y, s[ii][jj]);
                    s[ii][jj] = fmaf(qv[ii].z, kvv[jj].z, s[ii][jj]);
                    s[ii][jj] = fmaf(qv[ii].w, kvv[jj].w, s[ii][jj]);
                }
        }
        // full-row softmax (16-lane groups own a row)
        float p[4][4];
        #pragma unroll
        for (int ii = 0; ii < 4; ++ii) {
            float rmax = fmaxf(fmaxf(s[ii][0], s[ii][1]), fmaxf(s[ii][2], s[ii][3]));
            #pragma unroll
            for (int off = 8; off; off >>= 1) rmax = fmaxf(rmax, __shfl_xor(rmax, off));
            float rs = 0.f;
            #pragma unroll
            for (int jj = 0; jj < 4; ++jj) { p[ii][jj] = expf(s[ii][jj] - rmax); rs += p[ii][jj]; }
            #pragma unroll
            for (int off = 8; off; off >>= 1) rs += __shfl_xor(rs, off);
            float rinv = 1.f / rs;
            #pragma unroll
            for (int jj = 0; jj < 4; ++jj) p[ii][jj] *= rinv;
        }
        __syncthreads();   // all reads of q from qp complete
        #pragma unroll
        for (int ii = 0; ii < 4; ++ii)
            *(float4*)&qp[(ty << 2) + ii][tx << 2] =
                make_float4(p[ii][0], p[ii][1], p[ii][2], p[ii][3]);
        __syncthreads();
        // O = P @ t2
        float o[4][4] = {};
        #pragma unroll
        for (int j4 = 0; j4 < 16; ++j4) {
            float4 pv4[4], vv[4];
            #pragma unroll
            for (int ii = 0; ii < 4; ++ii) pv4[ii] = *(const float4*)&qp[(ty << 2) + ii][j4 << 2];
            #pragma unroll
            for (int jj = 0; jj < 4; ++jj)
                vv[jj] = *(const float4*)&t2s[(j4 << 2) + jj][((tx ^ j4) & 15) << 2];
            #pragma unroll
            for (int ii = 0; ii < 4; ++ii) {
                #pragma unroll
                for (int jj = 0; jj < 4; ++jj) {
                    float pj = ((const float*)&pv4[ii])[jj];
                    #pragma unroll
                    for (int dd = 0; dd < 4; ++dd)
                        o[ii][dd] = fmaf(pj, ((const float*)&vv[jj])[dd], o[ii][dd]);
                }
            }
        }
        // depthwise conv: sliding window over 36 v-rows per thread
        float cacc[4][4] = {};
        const int rbase = row0 + (ty << 2);
        #pragma unroll
        for (int kk = 0; kk < 36; ++kk) {
            int rr = rbase - 16 + kk;
            if (rr >= 0) {
                float4 vx = *(const float4*)(vbase + (size_t)rr * DH + (tx << 2));
                #pragma unroll
                for (int ii = 0; ii < 4; ++ii) {
                    int k = kk - ii;
                    if (k >= 0 && k < 33) {
                        float wv = cw[k];
                        cacc[ii][0] = fmaf(wv, vx.x, cacc[ii][0]);
                        cacc[ii][1] = fmaf(wv, vx.y, cacc[ii][1]);
                        cacc[ii][2] = fmaf(wv, vx.z, cacc[ii][2]);
                        cacc[ii][3] = fmaf(wv, vx.w, cacc[ii][3]);
                    }
                }
            }
        }
        #pragma unroll
        for (int ii = 0; ii < 4; ++ii) {
            int row = rbase + ii;
            float4 ov = make_float4(o[ii][0] + cacc[ii][0], o[ii][1] + cacc[ii][1],
                                    o[ii][2] + cacc[ii][2], o[ii][3] + cacc[ii][3]);
            *(float4*)(opre + ((size_t)b * NP + row) * DIM + h * DH + (tx << 2)) = ov;
        }
    }
}

extern "C" void kernel_launch(void* const* d_in, const int* in_sizes, int n_in,
                              void* d_out, int out_size, void* d_ws, size_t ws_size,
                              hipStream_t stream)
{
    const float* x   = (const float*)d_in[0];
    const float* ps  = (const float*)d_in[1];
    const float* wq  = (const float*)d_in[2];
    const float* wo  = (const float*)d_in[3];
    const float* cwg = (const float*)d_in[4];
    float* out = (float*)d_out;
    float* ws  = (float*)d_ws;

    float* mq   = out;               // d_out doubles as mq scratch; k_gemm<1> overwrites last
    float* kb   = ws + OFF_K;
    float* vb   = ws + OFF_V;
    float* ql   = ws + OFF_QL;
    float* kl   = ws + OFF_KL;
    float* a2   = ws + OFF_A2;
    float* t3   = ws + OFF_T3;
    float* t2   = ws + OFF_T2;
    float* mx   = ws + OFF_MAX;
    float* opre = ws + OFF_OPRE;
    float* pacc = opre;
    float* pm   = opre + 3145728ull;
    float* pl   = pm + 49152ull;
    _Float16* BTqh = (_Float16*)(ws + OFF_QL);
    _Float16* BTql = BTqh + 1536 * 512;
    _Float16* BToh = (_Float16*)(ws + OFF_K);
    _Float16* BTol = BToh + 512 * 512;

    k_cvtw        <<<dim3(24, 8), 256, 0, stream>>>(wq, BTqh, BTql, 512, 1536);
    k_gemm_split<0><<<dim3(12, 384), 256, 0, stream>>>(x, ps, BTqh, BTql, mq, kb, vb);
    k_land        <<<4096, 256, 0, stream>>>(mq, kb, ql, kl);
    k_sim2        <<<32, 256, 0, stream>>>(ql, kl, a2);
    k_maxes       <<<1, 256, 0, stream>>>(a2, mx);
    k_sim3part    <<<dim3(32, NCH), 256, 0, stream>>>(ql, kb, vb, pacc, pm, pl);
    k_sim3comb    <<<32, 256, 0, stream>>>(pacc, pm, pl, t3);
    k_cvtw        <<<dim3(8, 8), 256, 0, stream>>>(wo, BToh, BTol, 512, 512);
    k_pinv        <<<32, 256, 0, stream>>>(a2, mx, t3, t2);
    k_attn1       <<<dim3(32, 16), 256, 0, stream>>>(mq, kl, t2, vb, cwg, opre);
    k_gemm_split<1><<<dim3(4, 128), 256, 0, stream>>>(opre, nullptr, BToh, BTol, out, nullptr, nullptr);
}

// Round 6
// 1000.847 us; speedup vs baseline: 2.7403x; 1.0943x over previous
//
#include <hip/hip_runtime.h>
#include <math.h>

#define Bb 4
#define Hh 8
#define NP 4096
#define PTOT 8192
#define NTOT 12288
#define DIM 512
#define DH 64
#define SCALE 0.125f
#define NCH 24
#define CHUNK 512

typedef __attribute__((ext_vector_type(8))) _Float16 f16x8;
typedef __attribute__((ext_vector_type(4))) float f32x4;

// ---------------- workspace layout (float offsets) ----------------
#define SZ_K    (4ull*8*12288*64)      // 25,165,824
#define SZ_L    (32ull*64*64)          // 131,072
#define OFF_K    0ull
#define OFF_V    (OFF_K + SZ_K)
#define OFF_QL   (OFF_V + SZ_K)
#define OFF_KL   (OFF_QL + SZ_L)
#define OFF_A2   (OFF_KL + SZ_L)
#define OFF_T3   (OFF_A2 + SZ_L)
#define OFF_T2   (OFF_T3 + SZ_L)
#define OFF_MAX  (OFF_T2 + SZ_L)
#define OFF_OPRE (OFF_MAX + 16ull)
// total = 59,375,648 floats (237.5 MB) — proven fit.
// BTq aliases [OFF_QL...), BTo aliases kb (dead after k_sim3part).

// ---------------- transpose + fp16-split weights: w[K][N] -> BT[N][K] hi/lo ----------------
__global__ __launch_bounds__(256) void k_cvtw(const float* __restrict__ w,
    _Float16* __restrict__ bh, _Float16* __restrict__ bl, int K, int N)
{
    __shared__ float t[64][65];
    const int n0 = blockIdx.x * 64, k0 = blockIdx.y * 64;
    const int tid = threadIdx.x;
    #pragma unroll
    for (int i = 0; i < 4; ++i) {
        int r = (tid >> 4) + i * 16;
        int c = (tid & 15) * 4;
        float4 v = *(const float4*)(w + (size_t)(k0 + r) * N + n0 + c);
        t[r][c] = v.x; t[r][c+1] = v.y; t[r][c+2] = v.z; t[r][c+3] = v.w;
    }
    __syncthreads();
    const int n = tid >> 2, kq = (tid & 3) * 16;
    f16x8 h8[2], l8[2];
    #pragma unroll
    for (int j = 0; j < 16; ++j) {
        float a = t[kq + j][n];
        _Float16 hh = (_Float16)a;
        _Float16 ll = (_Float16)(a - (float)hh);
        h8[j >> 3][j & 7] = hh;
        l8[j >> 3][j & 7] = ll;
    }
    size_t o = (size_t)(n0 + n) * K + k0 + kq;
    *(f16x8*)(bh + o) = h8[0]; *(f16x8*)(bh + o + 8) = h8[1];
    *(f16x8*)(bl + o) = l8[0]; *(f16x8*)(bl + o + 8) = l8[1];
}

// ---------------- fp16-split MFMA GEMM, 2-phase double-buffered ----------------
__device__ __forceinline__ int hoff(int r, int slot) {
    return r * 32 + (((slot ^ (r >> 1)) & 3) << 3);
}

template<int MODE>
__global__ __launch_bounds__(256) void k_gemm_split(
    const float* __restrict__ Asrc0, const float* __restrict__ Asrc1,
    const _Float16* __restrict__ BTh, const _Float16* __restrict__ BTl,
    float* __restrict__ out0, float* __restrict__ out1, float* __restrict__ out2)
{
    __shared__ __align__(16) _Float16 Ah[2][128 * 32], Al[2][128 * 32];
    __shared__ __align__(16) _Float16 Bh[2][128 * 32], Bl[2][128 * 32];
    const int tid = threadIdx.x;
    const int n0 = blockIdx.x * 128;
    const int m0 = blockIdx.y * 128;
    const int wv = tid >> 6, lane = tid & 63;
    const int wr = wv >> 1, wc = wv & 1;
    const int kslot = lane >> 4;

    int ar[2], asl[2];
    const float* aptr[2];
    #pragma unroll
    for (int i = 0; i < 2; ++i) {
        int id = tid + 256 * i;
        ar[i] = id >> 2; asl[i] = id & 3;
        int grow = m0 + ar[i];
        if (MODE == 0) {
            int bi = grow / NTOT;
            int pos = grow - bi * NTOT;
            aptr[i] = (pos < NP) ? (Asrc0 + ((size_t)bi * NP + pos) * DIM)
                                 : (Asrc1 + ((size_t)bi * PTOT + (pos - NP)) * DIM);
        } else {
            aptr[i] = Asrc0 + (size_t)grow * DIM;
        }
    }

    float4 a0[2], a1[2];
    f16x8 vbh[2], vbl[2];

    // issue global loads for K-tile at k0
    auto LOADT = [&](int k0) {
        #pragma unroll
        for (int i = 0; i < 2; ++i) {
            a0[i] = *(const float4*)(aptr[i] + k0 + asl[i] * 8);
            a1[i] = *(const float4*)(aptr[i] + k0 + asl[i] * 8 + 4);
            size_t bo = (size_t)(n0 + ar[i]) * DIM + k0 + asl[i] * 8;
            vbh[i] = *(const f16x8*)(BTh + bo);
            vbl[i] = *(const f16x8*)(BTl + bo);
        }
    };
    // convert + write staged regs into LDS buffer `buf`
    auto WRITET = [&](int buf) {
        #pragma unroll
        for (int i = 0; i < 2; ++i) {
            f16x8 h, l;
            float vals[8] = {a0[i].x, a0[i].y, a0[i].z, a0[i].w,
                             a1[i].x, a1[i].y, a1[i].z, a1[i].w};
            #pragma unroll
            for (int j = 0; j < 8; ++j) {
                _Float16 hh = (_Float16)vals[j];
                h[j] = hh;
                l[j] = (_Float16)(vals[j] - (float)hh);
            }
            int o = hoff(ar[i], asl[i]);
            *(f16x8*)&Ah[buf][o] = h;
            *(f16x8*)&Al[buf][o] = l;
            *(f16x8*)&Bh[buf][o] = vbh[i];
            *(f16x8*)&Bl[buf][o] = vbl[i];
        }
    };

    LOADT(0);
    WRITET(0);
    int cur = 0;

    f32x4 acc[4][4] = {};
    for (int t = 0; t < 16; ++t) {
        if (t < 15) LOADT((t + 1) * 32);   // overlap next-tile loads with MFMA
        __syncthreads();                   // buf[cur] writes visible; prev reads of buf[cur^1] done
        f16x8 afh[4], afl[4];
        #pragma unroll
        for (int m = 0; m < 4; ++m) {
            int o = hoff(wr * 64 + m * 16 + (lane & 15), kslot);
            afh[m] = *(const f16x8*)&Ah[cur][o];
            afl[m] = *(const f16x8*)&Al[cur][o];
        }
        #pragma unroll
        for (int n = 0; n < 4; ++n) {
            int o = hoff(wc * 64 + n * 16 + (lane & 15), kslot);
            f16x8 bfh = *(const f16x8*)&Bh[cur][o];
            f16x8 bfl = *(const f16x8*)&Bl[cur][o];
            #pragma unroll
            for (int m = 0; m < 4; ++m) {
                acc[m][n] = __builtin_amdgcn_mfma_f32_16x16x32_f16(afh[m], bfh, acc[m][n], 0, 0, 0);
                acc[m][n] = __builtin_amdgcn_mfma_f32_16x16x32_f16(afh[m], bfl, acc[m][n], 0, 0, 0);
                acc[m][n] = __builtin_amdgcn_mfma_f32_16x16x32_f16(afl[m], bfh, acc[m][n], 0, 0, 0);
            }
        }
        if (t < 15) WRITET(cur ^ 1);       // safe: all waves passed barrier => done reading cur^1
        cur ^= 1;
    }
    #pragma unroll
    for (int m = 0; m < 4; ++m) {
        #pragma unroll
        for (int n = 0; n < 4; ++n) {
            int gcol = n0 + wc * 64 + n * 16 + (lane & 15);
            int rbase = m0 + wr * 64 + m * 16 + (lane >> 4) * 4;
            if (MODE == 1) {
                #pragma unroll
                for (int r = 0; r < 4; ++r)
                    out0[(size_t)(rbase + r) * DIM + gcol] = acc[m][n][r];
            } else {
                int which = gcol >> 9, h = (gcol >> 6) & 7, d = gcol & 63;
                #pragma unroll
                for (int r = 0; r < 4; ++r) {
                    int row = rbase + r;
                    int bi = row / NTOT;
                    int p = row - bi * NTOT;
                    float v = acc[m][n][r];
                    if (which == 0) {
                        if (p < NP) out0[(((size_t)bi * Hh + h) * NP + p) * DH + d] = v * SCALE;
                    } else if (which == 1) {
                        out1[(((size_t)bi * Hh + h) * NTOT + p) * DH + d] = v;
                    } else {
                        out2[(((size_t)bi * Hh + h) * NTOT + p) * DH + d] = v;
                    }
                }
            }
        }
    }
}

// ---------------- K2: landmark means (vectorized) ----------------
__global__ __launch_bounds__(256) void k_land(const float* __restrict__ mq,
    const float* __restrict__ kb, float* __restrict__ ql, float* __restrict__ kl)
{
    __shared__ float part[16][64];
    int idx = blockIdx.x;
    const int tid = threadIdx.x;
    const int rg = tid >> 4, c4 = (tid & 15) << 2;
    const float* src;
    float* dst;
    int R; float sc;
    if (idx < 2048) {
        int bh = idx >> 6, i = idx & 63;
        src = mq + ((size_t)bh * NP + i * 64) * DH;
        dst = ql + ((size_t)bh * 64 + i) * 64;
        R = 64; sc = 1.f / 64.f;
    } else {
        idx -= 2048;
        int bh = idx >> 6, i = idx & 63;
        src = kb + ((size_t)bh * NTOT + i * 192) * DH;
        dst = kl + ((size_t)bh * 64 + i) * 64;
        R = 192; sc = 1.f / 192.f;
    }
    float4 a = make_float4(0.f, 0.f, 0.f, 0.f);
    for (int r = rg; r < R; r += 16) {
        float4 v = *(const float4*)(src + (size_t)r * DH + c4);
        a.x += v.x; a.y += v.y; a.z += v.z; a.w += v.w;
    }
    *(float4*)&part[rg][c4] = a;
    __syncthreads();
    if (tid < 64) {
        float s = 0.f;
        #pragma unroll
        for (int g = 0; g < 16; ++g) s += part[g][tid];
        dst[tid] = s * sc;
    }
}

// ---------------- K3: attn2 = softmax(q_l @ k_l^T); also zero-inits mx ----------------
__global__ __launch_bounds__(256) void k_sim2(const float* __restrict__ ql,
    const float* __restrict__ kl, float* __restrict__ a2, float* __restrict__ mx)
{
    __shared__ float qs[64][64];
    __shared__ float ks[64][65];
    __shared__ float S[64][65];
    const int tid = threadIdx.x;
    const int bh = blockIdx.x;
    if (bh == 0 && tid < 2) mx[tid] = 0.f;   // consumed by k_maxes (stream-ordered)
    for (int e = tid; e < 4096; e += 256) {
        qs[e >> 6][e & 63] = ql[(size_t)bh * 4096 + e];
        ks[e >> 6][e & 63] = kl[(size_t)bh * 4096 + e];
    }
    __syncthreads();
    for (int sI = 0; sI < 16; ++sI) {
        int e = (sI << 8) + tid;
        int i = e >> 6, j = e & 63;
        float acc = 0.f;
        #pragma unroll 16
        for (int d = 0; d < 64; ++d) acc = fmaf(qs[i][d], ks[j][d], acc);
        S[i][j] = acc;
    }
    __syncthreads();
    const int wv = tid >> 6, lane = tid & 63;
    for (int i = wv; i < 64; i += 4) {
        float v = S[i][lane];
        float mxv = v;
        #pragma unroll
        for (int off = 32; off; off >>= 1) mxv = fmaxf(mxv, __shfl_xor(mxv, off));
        float p = expf(v - mxv);
        float sm = p;
        #pragma unroll
        for (int off = 32; off; off >>= 1) sm += __shfl_xor(sm, off);
        a2[((size_t)bh * 64 + i) * 64 + lane] = p / sm;
    }
}

// ---------------- K4: global max of row/col abs-sums of attn2 (32 blocks + atomicMax) ----------------
__global__ __launch_bounds__(64) void k_maxes(const float* __restrict__ a2,
    float* __restrict__ mx)
{
    const int bh = blockIdx.x;
    const int i = threadIdx.x;   // 64 threads, one row/col pair each
    const float* base = a2 + (size_t)bh * 4096;
    float cs = 0.f, rs = 0.f;
    for (int j = 0; j < 64; ++j) {
        cs += fabsf(base[i * 64 + j]);   // sum over last axis
        rs += fabsf(base[j * 64 + i]);   // sum over axis -2
    }
    #pragma unroll
    for (int off = 32; off; off >>= 1) {
        cs = fmaxf(cs, __shfl_xor(cs, off));
        rs = fmaxf(rs, __shfl_xor(rs, off));
    }
    if (i == 0) {   // positive floats: uint compare == float compare
        atomicMax((unsigned int*)&mx[0], __float_as_uint(cs));
        atomicMax((unsigned int*)&mx[1], __float_as_uint(rs));
    }
}

// ---------------- K5a: sim3 partials — flash over a 512-row chunk ----------------
__global__ __launch_bounds__(256) void k_sim3part(const float* __restrict__ ql,
    const float* __restrict__ kb, const float* __restrict__ vb,
    float* __restrict__ pacc, float* __restrict__ pm, float* __restrict__ pl)
{
    __shared__ float qs[64][68];
    __shared__ float kv[64][64];
    __shared__ float pss[64][68];
    const int bh = blockIdx.x, ch = blockIdx.y;
    const int tid = threadIdx.x;
    const int ty = tid >> 4, tx = tid & 15;

    for (int e = tid; e < 4096; e += 256) qs[e >> 6][e & 63] = ql[(size_t)bh * 4096 + e];

    float m_run[4] = {-INFINITY, -INFINITY, -INFINITY, -INFINITY};
    float l_run[4] = {};
    float acc[4][4] = {};

    const float* kc = kb + ((size_t)bh * NTOT + ch * CHUNK) * DH;
    const float* vc = vb + ((size_t)bh * NTOT + ch * CHUNK) * DH;

    for (int t = 0; t < CHUNK / 64; ++t) {
        __syncthreads();
        #pragma unroll
        for (int e = tid; e < 1024; e += 256) {
            int r = e >> 4, slot = e & 15;
            float4 kx = *(const float4*)(kc + ((size_t)(t * 64 + r)) * DH + (slot << 2));
            *(float4*)&kv[r][((slot ^ ((r >> 2) & 15)) << 2)] = kx;
        }
        __syncthreads();
        float s[4][4] = {};
        #pragma unroll
        for (int d4 = 0; d4 < 16; ++d4) {
            float4 qv[4], kvv[4];
            #pragma unroll
            for (int ii = 0; ii < 4; ++ii) qv[ii] = *(const float4*)&qs[(ty << 2) + ii][d4 << 2];
            #pragma unroll
            for (int jj = 0; jj < 4; ++jj)
                kvv[jj] = *(const float4*)&kv[(tx << 2) + jj][((d4 ^ tx) & 15) << 2];
            #pragma unroll
            for (int ii = 0; ii < 4; ++ii)
                #pragma unroll
                for (int jj = 0; jj < 4; ++jj) {
                    s[ii][jj] = fmaf(qv[ii].x, kvv[jj].x, s[ii][jj]);
                    s[ii][jj] = fmaf(qv[ii].y, kvv[jj].y, s[ii][jj]);
                    s[ii][jj] = fmaf(qv[ii].z, kvv[jj].z, s[ii][jj]);
                    s[ii][jj] = fmaf(qv[ii].w, kvv[jj].w, s[ii][jj]);
                }
        }
        #pragma unroll
        for (int ii = 0; ii < 4; ++ii) {
            float rmax = fmaxf(fmaxf(s[ii][0], s[ii][1]), fmaxf(s[ii][2], s[ii][3]));
            #pragma unroll
            for (int off = 8; off; off >>= 1) rmax = fmaxf(rmax, __shfl_xor(rmax, off));
            float mnew = fmaxf(m_run[ii], rmax);
            float corr = expf(m_run[ii] - mnew);
            float rs = 0.f;
            #pragma unroll
            for (int jj = 0; jj < 4; ++jj) { s[ii][jj] = expf(s[ii][jj] - mnew); rs += s[ii][jj]; }
            #pragma unroll
            for (int off = 8; off; off >>= 1) rs += __shfl_xor(rs, off);
            l_run[ii] = l_run[ii] * corr + rs;
            m_run[ii] = mnew;
            #pragma unroll
            for (int dd = 0; dd < 4; ++dd) acc[ii][dd] *= corr;
            *(float4*)&pss[(ty << 2) + ii][tx << 2] = make_float4(s[ii][0], s[ii][1], s[ii][2], s[ii][3]);
        }
        __syncthreads();
        #pragma unroll
        for (int e = tid; e < 1024; e += 256) {
            int r = e >> 4, slot = e & 15;
            float4 vx = *(const float4*)(vc + ((size_t)(t * 64 + r)) * DH + (slot << 2));
            *(float4*)&kv[r][((slot ^ ((r >> 2) & 15)) << 2)] = vx;
        }
        __syncthreads();
        #pragma unroll
        for (int j4 = 0; j4 < 16; ++j4) {
            float4 pv4[4], vv[4];
            #pragma unroll
            for (int ii = 0; ii < 4; ++ii) pv4[ii] = *(const float4*)&pss[(ty << 2) + ii][j4 << 2];
            #pragma unroll
            for (int jj = 0; jj < 4; ++jj)
                vv[jj] = *(const float4*)&kv[(j4 << 2) + jj][((tx ^ j4) & 15) << 2];
            #pragma unroll
            for (int ii = 0; ii < 4; ++ii) {
                #pragma unroll
                for (int jj = 0; jj < 4; ++jj) {
                    float pj = ((const float*)&pv4[ii])[jj];
                    #pragma unroll
                    for (int dd = 0; dd < 4; ++dd)
                        acc[ii][dd] = fmaf(pj, ((const float*)&vv[jj])[dd], acc[ii][dd]);
                }
            }
        }
    }
    const size_t base = ((size_t)bh * NCH + ch) * 64;
    #pragma unroll
    for (int ii = 0; ii < 4; ++ii) {
        int i = (ty << 2) + ii;
        *(float4*)(pacc + (base + i) * 64 + (tx << 2)) =
            make_float4(acc[ii][0], acc[ii][1], acc[ii][2], acc[ii][3]);
        if (tx == 0) { pm[base + i] = m_run[ii]; pl[base + i] = l_run[ii]; }
    }
}

// ---------------- K5b: combine sim3 partials -> t3 ----------------
__global__ __launch_bounds__(256) void k_sim3comb(const float* __restrict__ pacc,
    const float* __restrict__ pm, const float* __restrict__ pl, float* __restrict__ t3)
{
    __shared__ float w[NCH][64];
    __shared__ float Linv[64];
    const int bh = blockIdx.x;
    const int tid = threadIdx.x;
    if (tid < 64) {
        float M = -INFINITY;
        for (int c = 0; c < NCH; ++c)
            M = fmaxf(M, pm[((size_t)bh * NCH + c) * 64 + tid]);
        float L = 0.f;
        for (int c = 0; c < NCH; ++c) {
            float e = expf(pm[((size_t)bh * NCH + c) * 64 + tid] - M);
            w[c][tid] = e;
            L = fmaf(e, pl[((size_t)bh * NCH + c) * 64 + tid], L);
        }
        Linv[tid] = 1.f / L;
    }
    __syncthreads();
    const int wv = tid >> 6, lane = tid & 63;
    for (int p = 0; p < 16; ++p) {
        int i = (p << 2) + wv;
        float o = 0.f;
        for (int c = 0; c < NCH; ++c)
            o = fmaf(w[c][i], pacc[(((size_t)bh * NCH + c) * 64 + i) * 64 + lane], o);
        t3[((size_t)bh * 64 + i) * 64 + lane] = o * Linv[i];
    }
}

// ---------------- K6: pinv (LDS-resident, 1024 threads) + t2 = z @ t3 ----------------
__device__ __forceinline__ void mm64r(float* __restrict__ C, const float* A,
    const float* Bm, const float* S, float sa, float sm, int tid)
{
    float r[4];
    __syncthreads();
    #pragma unroll
    for (int s = 0; s < 4; ++s) {
        int e = (s << 10) + tid;
        int i = e >> 6, j = e & 63;
        float acc = 0.f;
        #pragma unroll 16
        for (int k = 0; k < 64; ++k)
            acc = fmaf(A[(i << 6) + k], Bm[(k << 6) + j], acc);
        float v = sm * acc;
        if (S) v = fmaf(sa, S[e], v);
        r[s] = v;
    }
    __syncthreads();
    #pragma unroll
    for (int s = 0; s < 4; ++s) C[(s << 10) + tid] = r[s];
    __syncthreads();
}

__device__ __forceinline__ void mm64g(float* __restrict__ C, const float* __restrict__ Ag,
    const float* __restrict__ Bm, int tid)
{
    float r[4];
    __syncthreads();
    #pragma unroll
    for (int s = 0; s < 4; ++s) {
        int e = (s << 10) + tid;
        int i = e >> 6, j = e & 63;
        float acc = 0.f;
        #pragma unroll 16
        for (int k = 0; k < 64; ++k)
            acc = fmaf(Ag[(i << 6) + k], Bm[(k << 6) + j], acc);
        r[s] = acc;
    }
    __syncthreads();
    #pragma unroll
    for (int s = 0; s < 4; ++s) C[(s << 10) + tid] = r[s];
    __syncthreads();
}

__global__ __launch_bounds__(1024) void k_pinv(const float* __restrict__ attn2,
    const float* __restrict__ mx, const float* __restrict__ t3g, float* __restrict__ t2g)
{
    __shared__ float Zs[4096], Ab[4096], Db[4096];
    const int tid = threadIdx.x;
    const int bh = blockIdx.x;
    const float inv = 1.0f / (mx[0] * mx[1]);
    const float* a2 = attn2 + (size_t)bh * 4096;
    for (int e = tid; e < 4096; e += 1024) {
        int i = e >> 6, j = e & 63;
        Zs[e] = a2[(j << 6) + i] * inv;
    }
    for (int it = 0; it < 6; ++it) {
        mm64g(Ab, a2, Zs, tid);                     // A = X@Z
        mm64r(Db, Ab, Ab, Ab, 7.f, -1.f, tid);      // D' = 7A - A@A
        for (int e = tid; e < 4096; e += 1024) {
            int i = e >> 6, j = e & 63;
            Db[e] = ((i == j) ? 15.f : 0.f) - Db[e];
        }
        mm64r(Ab, Zs, Ab, nullptr, 0.f, 1.f, tid);  // A <- P = Z@A
        mm64r(Zs, Ab, Db, Zs, 3.25f, -0.25f, tid);  // Z <- 3.25Z - 0.25 P@D
    }
    for (int e = tid; e < 4096; e += 1024) Ab[e] = t3g[(size_t)bh * 4096 + e];
    mm64r(Db, Zs, Ab, nullptr, 0.f, 1.f, tid);      // t2 = Z @ t3
    for (int e = tid; e < 4096; e += 1024) t2g[(size_t)bh * 4096 + e] = Db[e];
}

// ---------------- K7: out1 = softmax(mq@k_l^T) @ t2 + depthwise conv(v) ----------------
__global__ __launch_bounds__(256) void k_attn1(const float* __restrict__ mq,
    const float* __restrict__ kl, const float* __restrict__ t2,
    const float* __restrict__ vb, const float* __restrict__ cwg,
    float* __restrict__ opre)
{
    __shared__ float kls[64][64];   // swizzled
    __shared__ float t2s[64][64];   // swizzled
    __shared__ float qp[64][68];    // time-shared: q subtile, then P
    __shared__ float cw[33];
    const int bh = blockIdx.x;
    const int b = bh >> 3, h = bh & 7;
    const int rg = blockIdx.y;
    const int tid = threadIdx.x;
    const int ty = tid >> 4, tx = tid & 15;

    for (int e = tid; e < 1024; e += 256) {
        int r = e >> 4, slot = e & 15;
        float4 kx = *(const float4*)(kl + (size_t)bh * 4096 + r * 64 + (slot << 2));
        *(float4*)&kls[r][((slot ^ ((r >> 2) & 15)) << 2)] = kx;
        float4 tx4 = *(const float4*)(t2 + (size_t)bh * 4096 + r * 64 + (slot << 2));
        *(float4*)&t2s[r][((slot ^ ((r >> 2) & 15)) << 2)] = tx4;
    }
    if (tid < 33) cw[tid] = cwg[h * 33 + tid];

    const float* mqb = mq + (size_t)bh * NP * DH;
    const float* vbase = vb + (size_t)bh * NTOT * DH;

    for (int sub = 0; sub < 4; ++sub) {
        const int row0 = (rg << 8) + (sub << 6);
        __syncthreads();
        for (int e = tid; e < 1024; e += 256) {
            int r = e >> 4, slot = e & 15;
            *(float4*)&qp[r][slot << 2] =
                *(const float4*)(mqb + (size_t)(row0 + r) * DH + (slot << 2));
        }
        __syncthreads();
        float s[4][4] = {};
        #pragma unroll
        for (int d4 = 0; d4 < 16; ++d4) {
            float4 qv[4], kvv[4];
            #pragma unroll
            for (int ii = 0; ii < 4; ++ii) qv[ii] = *(const float4*)&qp[(ty << 2) + ii][d4 << 2];
            #pragma unroll
            for (int jj = 0; jj < 4; ++jj)
                kvv[jj] = *(const float4*)&kls[(tx << 2) + jj][((d4 ^ tx) & 15) << 2];
            #pragma unroll
            for (int ii = 0; ii < 4; ++ii)
                #pragma unroll
                for (int jj = 0; jj < 4; ++jj) {
                    s[ii][jj] = fmaf(qv[ii].x, kvv[jj].x, s[ii][jj]);
                    s[ii][jj] = fmaf(qv[ii].y, kvv[jj].y, s[ii][jj]);
                    s[ii][jj] = fmaf(qv[ii].z, kvv[jj].z, s[ii][jj]);
                    s[ii][jj] = fmaf(qv[ii].w, kvv[jj].w, s[ii][jj]);
                }
        }
        float p[4][4];
        #pragma unroll
        for (int ii = 0; ii < 4; ++ii) {
            float rmax = fmaxf(fmaxf(s[ii][0], s[ii][1]), fmaxf(s[ii][2], s[ii][3]));
            #pragma unroll
            for (int off = 8; off; off >>= 1) rmax = fmaxf(rmax, __shfl_xor(rmax, off));
            float rs = 0.f;
            #pragma unroll
            for (int jj = 0; jj < 4; ++jj) { p[ii][jj] = expf(s[ii][jj] - rmax); rs += p[ii][jj]; }
            #pragma unroll
            for (int off = 8; off; off >>= 1) rs += __shfl_xor(rs, off);
            float rinv = 1.f / rs;
            #pragma unroll
            for (int jj = 0; jj < 4; ++jj) p[ii][jj] *= rinv;
        }
        __syncthreads();
        #pragma unroll
        for (int ii = 0; ii < 4; ++ii)
            *(float4*)&qp[(ty << 2) + ii][tx << 2] =
                make_float4(p[ii][0], p[ii][1], p[ii][2], p[ii][3]);
        __syncthreads();
        float o[4][4] = {};
        #pragma unroll
        for (int j4 = 0; j4 < 16; ++j4) {
            float4 pv4[4], vv[4];
            #pragma unroll
            for (int ii = 0; ii < 4; ++ii) pv4[ii] = *(const float4*)&qp[(ty << 2) + ii][j4 << 2];
            #pragma unroll
            for (int jj = 0; jj < 4; ++jj)
                vv[jj] = *(const float4*)&t2s[(j4 << 2) + jj][((tx ^ j4) & 15) << 2];
            #pragma unroll
            for (int ii = 0; ii < 4; ++ii) {
                #pragma unroll
                for (int jj = 0; jj < 4; ++jj) {
                    float pj = ((const float*)&pv4[ii])[jj];
                    #pragma unroll
                    for (int dd = 0; dd < 4; ++dd)
                        o[ii][dd] = fmaf(pj, ((const float*)&vv[jj])[dd], o[ii][dd]);
                }
            }
        }
        float cacc[4][4] = {};
        const int rbase = row0 + (ty << 2);
        #pragma unroll
        for (int kk = 0; kk < 36; ++kk) {
            int rr = rbase - 16 + kk;
            if (rr >= 0) {
                float4 vx = *(const float4*)(vbase + (size_t)rr * DH + (tx << 2));
                #pragma unroll
                for (int ii = 0; ii < 4; ++ii) {
                    int k = kk - ii;
                    if (k >= 0 && k < 33) {
                        float wv = cw[k];
                        cacc[ii][0] = fmaf(wv, vx.x, cacc[ii][0]);
                        cacc[ii][1] = fmaf(wv, vx.y, cacc[ii][1]);
                        cacc[ii][2] = fmaf(wv, vx.z, cacc[ii][2]);
                        cacc[ii][3] = fmaf(wv, vx.w, cacc[ii][3]);
                    }
                }
            }
        }
        #pragma unroll
        for (int ii = 0; ii < 4; ++ii) {
            int row = rbase + ii;
            float4 ov = make_float4(o[ii][0] + cacc[ii][0], o[ii][1] + cacc[ii][1],
                                    o[ii][2] + cacc[ii][2], o[ii][3] + cacc[ii][3]);
            *(float4*)(opre + ((size_t)b * NP + row) * DIM + h * DH + (tx << 2)) = ov;
        }
    }
}

extern "C" void kernel_launch(void* const* d_in, const int* in_sizes, int n_in,
                              void* d_out, int out_size, void* d_ws, size_t ws_size,
                              hipStream_t stream)
{
    const float* x   = (const float*)d_in[0];
    const float* ps  = (const float*)d_in[1];
    const float* wq  = (const float*)d_in[2];
    const float* wo  = (const float*)d_in[3];
    const float* cwg = (const float*)d_in[4];
    float* out = (float*)d_out;
    float* ws  = (float*)d_ws;

    float* mq   = out;               // d_out doubles as mq scratch; k_gemm<1> overwrites last
    float* kb   = ws + OFF_K;
    float* vb   = ws + OFF_V;
    float* ql   = ws + OFF_QL;
    float* kl   = ws + OFF_KL;
    float* a2   = ws + OFF_A2;
    float* t3   = ws + OFF_T3;
    float* t2   = ws + OFF_T2;
    float* mx   = ws + OFF_MAX;
    float* opre = ws + OFF_OPRE;
    float* pacc = opre;
    float* pm   = opre + 3145728ull;
    float* pl   = pm + 49152ull;
    _Float16* BTqh = (_Float16*)(ws + OFF_QL);
    _Float16* BTql = BTqh + 1536 * 512;
    _Float16* BToh = (_Float16*)(ws + OFF_K);
    _Float16* BTol = BToh + 512 * 512;

    k_cvtw        <<<dim3(24, 8), 256, 0, stream>>>(wq, BTqh, BTql, 512, 1536);
    k_gemm_split<0><<<dim3(12, 384), 256, 0, stream>>>(x, ps, BTqh, BTql, mq, kb, vb);
    k_land        <<<4096, 256, 0, stream>>>(mq, kb, ql, kl);
    k_sim2        <<<32, 256, 0, stream>>>(ql, kl, a2, mx);
    k_maxes       <<<32, 64, 0, stream>>>(a2, mx);
    k_sim3part    <<<dim3(32, NCH), 256, 0, stream>>>(ql, kb, vb, pacc, pm, pl);
    k_sim3comb    <<<32, 256, 0, stream>>>(pacc, pm, pl, t3);
    k_cvtw        <<<dim3(8, 8), 256, 0, stream>>>(wo, BToh, BTol, 512, 512);
    k_pinv        <<<32, 1024, 0, stream>>>(a2, mx, t3, t2);
    k_attn1       <<<dim3(32, 16), 256, 0, stream>>>(mq, kl, t2, vb, cwg, opre);
    k_gemm_split<1><<<dim3(4, 128), 256, 0, stream>>>(opre, nullptr, BToh, BTol, out, nullptr, nullptr);
}

// Round 7
// 891.831 us; speedup vs baseline: 3.0752x; 1.1222x over previous
//
#include <hip/hip_runtime.h>
#include <math.h>

#define Bb 4
#define Hh 8
#define NP 4096
#define PTOT 8192
#define NTOT 12288
#define DIM 512
#define DH 64
#define SCALE 0.125f
#define NCH 24
#define CHUNK 512

typedef __attribute__((ext_vector_type(8))) _Float16 f16x8;
typedef __attribute__((ext_vector_type(4))) _Float16 f16x4;
typedef __attribute__((ext_vector_type(4))) float f32x4;

// ---------------- workspace layout (float offsets) ----------------
#define SZ_K    (4ull*8*12288*64)      // 25,165,824
#define SZ_L    (32ull*64*64)          // 131,072
#define OFF_K    0ull
#define OFF_V    (OFF_K + SZ_K)
#define OFF_QL   (OFF_V + SZ_K)
#define OFF_KL   (OFF_QL + SZ_L)
#define OFF_A2   (OFF_KL + SZ_L)
#define OFF_T3   (OFF_A2 + SZ_L)
#define OFF_T2   (OFF_T3 + SZ_L)
#define OFF_MAX  (OFF_T2 + SZ_L)
#define OFF_OPRE (OFF_MAX + 16ull)
// total = 59,375,648 floats (237.5 MB) — proven fit.
// BTq aliases [OFF_QL...), BTo aliases kb (dead after k_sim3part).

__device__ __forceinline__ unsigned short hbits(_Float16 x) {
    union { _Float16 f; unsigned short u; } c; c.f = x; return c.u;
}

// ---------------- transpose + fp16-split weights: w[K][N] -> BT[N][K] hi/lo ----------------
__global__ __launch_bounds__(256) void k_cvtw(const float* __restrict__ w,
    _Float16* __restrict__ bh, _Float16* __restrict__ bl, int K, int N)
{
    __shared__ float t[64][65];
    const int n0 = blockIdx.x * 64, k0 = blockIdx.y * 64;
    const int tid = threadIdx.x;
    #pragma unroll
    for (int i = 0; i < 4; ++i) {
        int r = (tid >> 4) + i * 16;
        int c = (tid & 15) * 4;
        float4 v = *(const float4*)(w + (size_t)(k0 + r) * N + n0 + c);
        t[r][c] = v.x; t[r][c+1] = v.y; t[r][c+2] = v.z; t[r][c+3] = v.w;
    }
    __syncthreads();
    const int n = tid >> 2, kq = (tid & 3) * 16;
    f16x8 h8[2], l8[2];
    #pragma unroll
    for (int j = 0; j < 16; ++j) {
        float a = t[kq + j][n];
        _Float16 hh = (_Float16)a;
        _Float16 ll = (_Float16)(a - (float)hh);
        h8[j >> 3][j & 7] = hh;
        l8[j >> 3][j & 7] = ll;
    }
    size_t o = (size_t)(n0 + n) * K + k0 + kq;
    *(f16x8*)(bh + o) = h8[0]; *(f16x8*)(bh + o + 8) = h8[1];
    *(f16x8*)(bl + o) = l8[0]; *(f16x8*)(bl + o + 8) = l8[1];
}

// ---------------- fp16-split MFMA GEMM, 2-phase double-buffered ----------------
__device__ __forceinline__ int hoff(int r, int slot) {
    return r * 32 + (((slot ^ (r >> 1)) & 3) << 3);
}

template<int MODE>
__global__ __launch_bounds__(256) void k_gemm_split(
    const float* __restrict__ Asrc0, const float* __restrict__ Asrc1,
    const _Float16* __restrict__ BTh, const _Float16* __restrict__ BTl,
    float* __restrict__ out0, float* __restrict__ out1, float* __restrict__ out2)
{
    __shared__ __align__(16) _Float16 Ah[2][128 * 32], Al[2][128 * 32];
    __shared__ __align__(16) _Float16 Bh[2][128 * 32], Bl[2][128 * 32];
    const int tid = threadIdx.x;
    const int n0 = blockIdx.x * 128;
    const int m0 = blockIdx.y * 128;
    const int wv = tid >> 6, lane = tid & 63;
    const int wr = wv >> 1, wc = wv & 1;
    const int kslot = lane >> 4;

    int ar[2], asl[2];
    const float* aptr[2];
    #pragma unroll
    for (int i = 0; i < 2; ++i) {
        int id = tid + 256 * i;
        ar[i] = id >> 2; asl[i] = id & 3;
        int grow = m0 + ar[i];
        if (MODE == 0) {
            int bi = grow / NTOT;
            int pos = grow - bi * NTOT;
            aptr[i] = (pos < NP) ? (Asrc0 + ((size_t)bi * NP + pos) * DIM)
                                 : (Asrc1 + ((size_t)bi * PTOT + (pos - NP)) * DIM);
        } else {
            aptr[i] = Asrc0 + (size_t)grow * DIM;
        }
    }

    float4 a0[2], a1[2];
    f16x8 vbh[2], vbl[2];

    auto LOADT = [&](int k0) {
        #pragma unroll
        for (int i = 0; i < 2; ++i) {
            a0[i] = *(const float4*)(aptr[i] + k0 + asl[i] * 8);
            a1[i] = *(const float4*)(aptr[i] + k0 + asl[i] * 8 + 4);
            size_t bo = (size_t)(n0 + ar[i]) * DIM + k0 + asl[i] * 8;
            vbh[i] = *(const f16x8*)(BTh + bo);
            vbl[i] = *(const f16x8*)(BTl + bo);
        }
    };
    auto WRITET = [&](int buf) {
        #pragma unroll
        for (int i = 0; i < 2; ++i) {
            f16x8 h, l;
            float vals[8] = {a0[i].x, a0[i].y, a0[i].z, a0[i].w,
                             a1[i].x, a1[i].y, a1[i].z, a1[i].w};
            #pragma unroll
            for (int j = 0; j < 8; ++j) {
                _Float16 hh = (_Float16)vals[j];
                h[j] = hh;
                l[j] = (_Float16)(vals[j] - (float)hh);
            }
            int o = hoff(ar[i], asl[i]);
            *(f16x8*)&Ah[buf][o] = h;
            *(f16x8*)&Al[buf][o] = l;
            *(f16x8*)&Bh[buf][o] = vbh[i];
            *(f16x8*)&Bl[buf][o] = vbl[i];
        }
    };

    LOADT(0);
    WRITET(0);
    int cur = 0;

    f32x4 acc[4][4] = {};
    for (int t = 0; t < 16; ++t) {
        if (t < 15) LOADT((t + 1) * 32);
        __syncthreads();
        f16x8 afh[4], afl[4];
        #pragma unroll
        for (int m = 0; m < 4; ++m) {
            int o = hoff(wr * 64 + m * 16 + (lane & 15), kslot);
            afh[m] = *(const f16x8*)&Ah[cur][o];
            afl[m] = *(const f16x8*)&Al[cur][o];
        }
        #pragma unroll
        for (int n = 0; n < 4; ++n) {
            int o = hoff(wc * 64 + n * 16 + (lane & 15), kslot);
            f16x8 bfh = *(const f16x8*)&Bh[cur][o];
            f16x8 bfl = *(const f16x8*)&Bl[cur][o];
            #pragma unroll
            for (int m = 0; m < 4; ++m) {
                acc[m][n] = __builtin_amdgcn_mfma_f32_16x16x32_f16(afh[m], bfh, acc[m][n], 0, 0, 0);
                acc[m][n] = __builtin_amdgcn_mfma_f32_16x16x32_f16(afh[m], bfl, acc[m][n], 0, 0, 0);
                acc[m][n] = __builtin_amdgcn_mfma_f32_16x16x32_f16(afl[m], bfh, acc[m][n], 0, 0, 0);
            }
        }
        if (t < 15) WRITET(cur ^ 1);
        cur ^= 1;
    }
    #pragma unroll
    for (int m = 0; m < 4; ++m) {
        #pragma unroll
        for (int n = 0; n < 4; ++n) {
            int gcol = n0 + wc * 64 + n * 16 + (lane & 15);
            int rbase = m0 + wr * 64 + m * 16 + (lane >> 4) * 4;
            if (MODE == 1) {
                #pragma unroll
                for (int r = 0; r < 4; ++r)
                    out0[(size_t)(rbase + r) * DIM + gcol] = acc[m][n][r];
            } else {
                int which = gcol >> 9, h = (gcol >> 6) & 7, d = gcol & 63;
                #pragma unroll
                for (int r = 0; r < 4; ++r) {
                    int row = rbase + r;
                    int bi = row / NTOT;
                    int p = row - bi * NTOT;
                    float v = acc[m][n][r];
                    if (which == 0) {
                        if (p < NP) out0[(((size_t)bi * Hh + h) * NP + p) * DH + d] = v * SCALE;
                    } else if (which == 1) {
                        out1[(((size_t)bi * Hh + h) * NTOT + p) * DH + d] = v;
                    } else {
                        out2[(((size_t)bi * Hh + h) * NTOT + p) * DH + d] = v;
                    }
                }
            }
        }
    }
}

// ---------------- K2: landmark means (vectorized) ----------------
__global__ __launch_bounds__(256) void k_land(const float* __restrict__ mq,
    const float* __restrict__ kb, float* __restrict__ ql, float* __restrict__ kl)
{
    __shared__ float part[16][64];
    int idx = blockIdx.x;
    const int tid = threadIdx.x;
    const int rg = tid >> 4, c4 = (tid & 15) << 2;
    const float* src;
    float* dst;
    int R; float sc;
    if (idx < 2048) {
        int bh = idx >> 6, i = idx & 63;
        src = mq + ((size_t)bh * NP + i * 64) * DH;
        dst = ql + ((size_t)bh * 64 + i) * 64;
        R = 64; sc = 1.f / 64.f;
    } else {
        idx -= 2048;
        int bh = idx >> 6, i = idx & 63;
        src = kb + ((size_t)bh * NTOT + i * 192) * DH;
        dst = kl + ((size_t)bh * 64 + i) * 64;
        R = 192; sc = 1.f / 192.f;
    }
    float4 a = make_float4(0.f, 0.f, 0.f, 0.f);
    for (int r = rg; r < R; r += 16) {
        float4 v = *(const float4*)(src + (size_t)r * DH + c4);
        a.x += v.x; a.y += v.y; a.z += v.z; a.w += v.w;
    }
    *(float4*)&part[rg][c4] = a;
    __syncthreads();
    if (tid < 64) {
        float s = 0.f;
        #pragma unroll
        for (int g = 0; g < 16; ++g) s += part[g][tid];
        dst[tid] = s * sc;
    }
}

// ---------------- K3: attn2 = softmax(q_l @ k_l^T); also zero-inits mx ----------------
__global__ __launch_bounds__(256) void k_sim2(const float* __restrict__ ql,
    const float* __restrict__ kl, float* __restrict__ a2, float* __restrict__ mx)
{
    __shared__ float qs[64][64];
    __shared__ float ks[64][65];
    __shared__ float S[64][65];
    const int tid = threadIdx.x;
    const int bh = blockIdx.x;
    if (bh == 0 && tid < 2) mx[tid] = 0.f;
    for (int e = tid; e < 4096; e += 256) {
        qs[e >> 6][e & 63] = ql[(size_t)bh * 4096 + e];
        ks[e >> 6][e & 63] = kl[(size_t)bh * 4096 + e];
    }
    __syncthreads();
    for (int sI = 0; sI < 16; ++sI) {
        int e = (sI << 8) + tid;
        int i = e >> 6, j = e & 63;
        float acc = 0.f;
        #pragma unroll 16
        for (int d = 0; d < 64; ++d) acc = fmaf(qs[i][d], ks[j][d], acc);
        S[i][j] = acc;
    }
    __syncthreads();
    const int wv = tid >> 6, lane = tid & 63;
    for (int i = wv; i < 64; i += 4) {
        float v = S[i][lane];
        float mxv = v;
        #pragma unroll
        for (int off = 32; off; off >>= 1) mxv = fmaxf(mxv, __shfl_xor(mxv, off));
        float p = expf(v - mxv);
        float sm = p;
        #pragma unroll
        for (int off = 32; off; off >>= 1) sm += __shfl_xor(sm, off);
        a2[((size_t)bh * 64 + i) * 64 + lane] = p / sm;
    }
}

// ---------------- K4: global max of row/col abs-sums of attn2 ----------------
__global__ __launch_bounds__(64) void k_maxes(const float* __restrict__ a2,
    float* __restrict__ mx)
{
    const int bh = blockIdx.x;
    const int i = threadIdx.x;
    const float* base = a2 + (size_t)bh * 4096;
    float cs = 0.f, rs = 0.f;
    for (int j = 0; j < 64; ++j) {
        cs += fabsf(base[i * 64 + j]);
        rs += fabsf(base[j * 64 + i]);
    }
    #pragma unroll
    for (int off = 32; off; off >>= 1) {
        cs = fmaxf(cs, __shfl_xor(cs, off));
        rs = fmaxf(rs, __shfl_xor(rs, off));
    }
    if (i == 0) {
        atomicMax((unsigned int*)&mx[0], __float_as_uint(cs));
        atomicMax((unsigned int*)&mx[1], __float_as_uint(rs));
    }
}

// ---------------- K5a: sim3 partials — fp16-split MFMA flash over a 512-row chunk ----------
// 4 waves; wave w owns S-cols / O-cols(dh) 16w..16w+15. LDS ~50KB.
// qsh/qsl: q_l split, [row][k] 16B-slot XOR swizzle. kvh/kvl: K tile [row][k], then V^T [dh][kv].
// pss (u32 [64][68]): S f32 (cols 0..63) -> P packed: h-plane cols 0..31, l-plane 32..63.
__global__ __launch_bounds__(256) void k_sim3part(const float* __restrict__ qlg,
    const float* __restrict__ kb, const float* __restrict__ vb,
    float* __restrict__ pacc, float* __restrict__ pm, float* __restrict__ pl)
{
    __shared__ __align__(16) _Float16 qsh[4096], qsl[4096];
    __shared__ __align__(16) _Float16 kvh[4096], kvl[4096];
    __shared__ __align__(16) unsigned int pss[64][68];
    __shared__ float corr_s[64];
    const int bh = blockIdx.x, ch = blockIdx.y;
    const int tid = threadIdx.x;
    const int wv = tid >> 6, lane = tid & 63;
    const int lg = lane >> 4, ll = lane & 15;   // k-slot group, frag row/col

    // stage q_l split (once)
    #pragma unroll
    for (int it = 0; it < 4; ++it) {
        int e = tid + 256 * it;            // 0..1023 quads
        int r = e >> 4, c0 = (e & 15) << 2;
        float4 qv = *(const float4*)(qlg + (size_t)bh * 4096 + r * 64 + c0);
        f16x4 h, l;
        float vals[4] = {qv.x, qv.y, qv.z, qv.w};
        #pragma unroll
        for (int i = 0; i < 4; ++i) {
            _Float16 hh = (_Float16)vals[i];
            h[i] = hh; l[i] = (_Float16)(vals[i] - (float)hh);
        }
        int off = r * 64 + (((c0 >> 3) ^ (r & 7)) << 3) + (c0 & 7);
        *(f16x4*)&qsh[off] = h;
        *(f16x4*)&qsl[off] = l;
    }

    const float* kc = kb + ((size_t)bh * NTOT + ch * CHUNK) * DH;
    const float* vc = vb + ((size_t)bh * NTOT + ch * CHUNK) * DH;

    float m_run = -INFINITY, l_run = 0.f;    // valid in softmax role (row tid>>2)
    f32x4 acc_o[4] = {};                     // O rows 16m+lg*4+reg, col 16wv+ll

    for (int t = 0; t < CHUNK / 64; ++t) {
        __syncthreads();                     // (1) prev PV done with kv/pss; qs ready (t=0)
        // ---- stage K tile h/l ----
        #pragma unroll
        for (int it = 0; it < 4; ++it) {
            int e = tid + 256 * it;
            int r = e >> 4, c0 = (e & 15) << 2;
            float4 kx = *(const float4*)(kc + (size_t)(t * 64 + r) * DH + c0);
            f16x4 h, l;
            float vals[4] = {kx.x, kx.y, kx.z, kx.w};
            #pragma unroll
            for (int i = 0; i < 4; ++i) {
                _Float16 hh = (_Float16)vals[i];
                h[i] = hh; l[i] = (_Float16)(vals[i] - (float)hh);
            }
            int off = r * 64 + (((c0 >> 3) ^ (r & 7)) << 3) + (c0 & 7);
            *(f16x4*)&kvh[off] = h;
            *(f16x4*)&kvl[off] = l;
        }
        __syncthreads();                     // (2)
        // ---- S = q @ K^T (MFMA) ----
        f32x4 accs[4] = {};
        #pragma unroll
        for (int ks = 0; ks < 2; ++ks) {
            int k0 = 32 * ks + (lg << 3);
            int brow = 16 * wv + ll;
            int boff = brow * 64 + (((k0 >> 3) ^ (brow & 7)) << 3);
            f16x8 bh8 = *(const f16x8*)&kvh[boff];
            f16x8 bl8 = *(const f16x8*)&kvl[boff];
            #pragma unroll
            for (int m = 0; m < 4; ++m) {
                int arow = 16 * m + ll;
                int aoff = arow * 64 + (((k0 >> 3) ^ (arow & 7)) << 3);
                f16x8 ah8 = *(const f16x8*)&qsh[aoff];
                f16x8 al8 = *(const f16x8*)&qsl[aoff];
                accs[m] = __builtin_amdgcn_mfma_f32_16x16x32_f16(ah8, bh8, accs[m], 0, 0, 0);
                accs[m] = __builtin_amdgcn_mfma_f32_16x16x32_f16(ah8, bl8, accs[m], 0, 0, 0);
                accs[m] = __builtin_amdgcn_mfma_f32_16x16x32_f16(al8, bh8, accs[m], 0, 0, 0);
            }
        }
        // write S (f32 bits) to pss cols 16wv..+15
        #pragma unroll
        for (int m = 0; m < 4; ++m)
            #pragma unroll
            for (int rg = 0; rg < 4; ++rg)
                pss[16 * m + lg * 4 + rg][16 * wv + ll] = __float_as_uint(accs[m][rg]);
        __syncthreads();                     // (3) S complete; K reads complete
        // ---- online softmax (rows wave-partitioned) -> P packed h/l planes ----
        {
            const int r = tid >> 2, q = tid & 3;
            float s[16];
            uint4 u0 = *(const uint4*)&pss[r][q * 16];
            uint4 u1 = *(const uint4*)&pss[r][q * 16 + 4];
            uint4 u2 = *(const uint4*)&pss[r][q * 16 + 8];
            uint4 u3 = *(const uint4*)&pss[r][q * 16 + 12];
            s[0]=__uint_as_float(u0.x); s[1]=__uint_as_float(u0.y); s[2]=__uint_as_float(u0.z); s[3]=__uint_as_float(u0.w);
            s[4]=__uint_as_float(u1.x); s[5]=__uint_as_float(u1.y); s[6]=__uint_as_float(u1.z); s[7]=__uint_as_float(u1.w);
            s[8]=__uint_as_float(u2.x); s[9]=__uint_as_float(u2.y); s[10]=__uint_as_float(u2.z); s[11]=__uint_as_float(u2.w);
            s[12]=__uint_as_float(u3.x); s[13]=__uint_as_float(u3.y); s[14]=__uint_as_float(u3.z); s[15]=__uint_as_float(u3.w);
            float lmax = s[0];
            #pragma unroll
            for (int i = 1; i < 16; ++i) lmax = fmaxf(lmax, s[i]);
            lmax = fmaxf(lmax, __shfl_xor(lmax, 1));
            lmax = fmaxf(lmax, __shfl_xor(lmax, 2));
            float mnew = fmaxf(m_run, lmax);
            float corr = expf(m_run - mnew);
            float p[16], rsum = 0.f;
            #pragma unroll
            for (int i = 0; i < 16; ++i) { p[i] = expf(s[i] - mnew); rsum += p[i]; }
            rsum += __shfl_xor(rsum, 1);
            rsum += __shfl_xor(rsum, 2);
            l_run = l_run * corr + rsum;
            m_run = mnew;
            if (q == 0) corr_s[r] = corr;
            #pragma unroll
            for (int i2 = 0; i2 < 8; ++i2) {
                float p0 = p[2 * i2], p1 = p[2 * i2 + 1];
                _Float16 h0 = (_Float16)p0, h1 = (_Float16)p1;
                _Float16 e0 = (_Float16)(p0 - (float)h0), e1 = (_Float16)(p1 - (float)h1);
                pss[r][q * 8 + i2]      = (unsigned int)hbits(h0) | ((unsigned int)hbits(h1) << 16);
                pss[r][32 + q * 8 + i2] = (unsigned int)hbits(e0) | ((unsigned int)hbits(e1) << 16);
            }
        }
        // ---- stage V transposed h/l into kv (K reads done before barrier 3) ----
        {
            const int r0 = (tid & 31) * 2, cb = (tid >> 5) * 4;
            #pragma unroll
            for (int ci = 0; ci < 2; ++ci) {
                int c0 = cb + 32 * ci;
                float4 v0 = *(const float4*)(vc + (size_t)(t * 64 + r0) * DH + c0);
                float4 v1 = *(const float4*)(vc + (size_t)(t * 64 + r0 + 1) * DH + c0);
                float a0[4] = {v0.x, v0.y, v0.z, v0.w};
                float a1[4] = {v1.x, v1.y, v1.z, v1.w};
                #pragma unroll
                for (int i = 0; i < 4; ++i) {
                    int c = c0 + i;
                    _Float16 h0 = (_Float16)a0[i], h1 = (_Float16)a1[i];
                    _Float16 e0 = (_Float16)(a0[i] - (float)h0), e1 = (_Float16)(a1[i] - (float)h1);
                    int off = c * 64 + (((r0 >> 3) ^ (c & 7)) << 3) + (r0 & 7);
                    *(unsigned int*)&kvh[off] = (unsigned int)hbits(h0) | ((unsigned int)hbits(h1) << 16);
                    *(unsigned int*)&kvl[off] = (unsigned int)hbits(e0) | ((unsigned int)hbits(e1) << 16);
                }
            }
        }
        __syncthreads();                     // (4) P + V^T + corr ready
        // ---- rescale O by corr, then O += P @ V (MFMA) ----
        #pragma unroll
        for (int m = 0; m < 4; ++m)
            #pragma unroll
            for (int rg = 0; rg < 4; ++rg)
                acc_o[m][rg] *= corr_s[16 * m + lg * 4 + rg];
        #pragma unroll
        for (int ks = 0; ks < 2; ++ks) {
            int k0 = 32 * ks + (lg << 3);
            int dh = 16 * wv + ll;
            int boff = dh * 64 + (((k0 >> 3) ^ (dh & 7)) << 3);
            f16x8 vh8 = *(const f16x8*)&kvh[boff];
            f16x8 vl8 = *(const f16x8*)&kvl[boff];
            #pragma unroll
            for (int m = 0; m < 4; ++m) {
                int prow = 16 * m + ll;
                union { uint4 u; f16x8 f; } ph, pe;
                ph.u = *(const uint4*)&pss[prow][16 * ks + lg * 4];
                pe.u = *(const uint4*)&pss[prow][32 + 16 * ks + lg * 4];
                acc_o[m] = __builtin_amdgcn_mfma_f32_16x16x32_f16(ph.f, vh8, acc_o[m], 0, 0, 0);
                acc_o[m] = __builtin_amdgcn_mfma_f32_16x16x32_f16(ph.f, vl8, acc_o[m], 0, 0, 0);
                acc_o[m] = __builtin_amdgcn_mfma_f32_16x16x32_f16(pe.f, vh8, acc_o[m], 0, 0, 0);
            }
        }
    }
    // ---- write partials (unnormalized) ----
    const size_t base = ((size_t)bh * NCH + ch) * 64;
    #pragma unroll
    for (int m = 0; m < 4; ++m)
        #pragma unroll
        for (int rg = 0; rg < 4; ++rg) {
            int row = 16 * m + lg * 4 + rg;
            pacc[(base + row) * 64 + 16 * wv + ll] = acc_o[m][rg];
        }
    if ((tid & 3) == 0) {
        int r = tid >> 2;
        pm[base + r] = m_run;
        pl[base + r] = l_run;
    }
}

// ---------------- K5b: combine sim3 partials -> t3 ----------------
__global__ __launch_bounds__(256) void k_sim3comb(const float* __restrict__ pacc,
    const float* __restrict__ pm, const float* __restrict__ pl, float* __restrict__ t3)
{
    __shared__ float w[NCH][64];
    __shared__ float Linv[64];
    const int bh = blockIdx.x;
    const int tid = threadIdx.x;
    if (tid < 64) {
        float M = -INFINITY;
        for (int c = 0; c < NCH; ++c)
            M = fmaxf(M, pm[((size_t)bh * NCH + c) * 64 + tid]);
        float L = 0.f;
        for (int c = 0; c < NCH; ++c) {
            float e = expf(pm[((size_t)bh * NCH + c) * 64 + tid] - M);
            w[c][tid] = e;
            L = fmaf(e, pl[((size_t)bh * NCH + c) * 64 + tid], L);
        }
        Linv[tid] = 1.f / L;
    }
    __syncthreads();
    const int wv = tid >> 6, lane = tid & 63;
    for (int p = 0; p < 16; ++p) {
        int i = (p << 2) + wv;
        float o = 0.f;
        for (int c = 0; c < NCH; ++c)
            o = fmaf(w[c][i], pacc[(((size_t)bh * NCH + c) * 64 + i) * 64 + lane], o);
        t3[((size_t)bh * 64 + i) * 64 + lane] = o * Linv[i];
    }
}

// ---------------- K6: pinv (LDS-resident, 1024 threads) + t2 = z @ t3 ----------------
__device__ __forceinline__ void mm64r(float* __restrict__ C, const float* A,
    const float* Bm, const float* S, float sa, float sm, int tid)
{
    float r[4];
    __syncthreads();
    #pragma unroll
    for (int s = 0; s < 4; ++s) {
        int e = (s << 10) + tid;
        int i = e >> 6, j = e & 63;
        float acc = 0.f;
        #pragma unroll 16
        for (int k = 0; k < 64; ++k)
            acc = fmaf(A[(i << 6) + k], Bm[(k << 6) + j], acc);
        float v = sm * acc;
        if (S) v = fmaf(sa, S[e], v);
        r[s] = v;
    }
    __syncthreads();
    #pragma unroll
    for (int s = 0; s < 4; ++s) C[(s << 10) + tid] = r[s];
    __syncthreads();
}

__device__ __forceinline__ void mm64g(float* __restrict__ C, const float* __restrict__ Ag,
    const float* __restrict__ Bm, int tid)
{
    float r[4];
    __syncthreads();
    #pragma unroll
    for (int s = 0; s < 4; ++s) {
        int e = (s << 10) + tid;
        int i = e >> 6, j = e & 63;
        float acc = 0.f;
        #pragma unroll 16
        for (int k = 0; k < 64; ++k)
            acc = fmaf(Ag[(i << 6) + k], Bm[(k << 6) + j], acc);
        r[s] = acc;
    }
    __syncthreads();
    #pragma unroll
    for (int s = 0; s < 4; ++s) C[(s << 10) + tid] = r[s];
    __syncthreads();
}

__global__ __launch_bounds__(1024) void k_pinv(const float* __restrict__ attn2,
    const float* __restrict__ mx, const float* __restrict__ t3g, float* __restrict__ t2g)
{
    __shared__ float Zs[4096], Ab[4096], Db[4096];
    const int tid = threadIdx.x;
    const int bh = blockIdx.x;
    const float inv = 1.0f / (mx[0] * mx[1]);
    const float* a2 = attn2 + (size_t)bh * 4096;
    for (int e = tid; e < 4096; e += 1024) {
        int i = e >> 6, j = e & 63;
        Zs[e] = a2[(j << 6) + i] * inv;
    }
    for (int it = 0; it < 6; ++it) {
        mm64g(Ab, a2, Zs, tid);
        mm64r(Db, Ab, Ab, Ab, 7.f, -1.f, tid);
        for (int e = tid; e < 4096; e += 1024) {
            int i = e >> 6, j = e & 63;
            Db[e] = ((i == j) ? 15.f : 0.f) - Db[e];
        }
        mm64r(Ab, Zs, Ab, nullptr, 0.f, 1.f, tid);
        mm64r(Zs, Ab, Db, Zs, 3.25f, -0.25f, tid);
    }
    for (int e = tid; e < 4096; e += 1024) Ab[e] = t3g[(size_t)bh * 4096 + e];
    mm64r(Db, Zs, Ab, nullptr, 0.f, 1.f, tid);
    for (int e = tid; e < 4096; e += 1024) t2g[(size_t)bh * 4096 + e] = Db[e];
}

// ---------------- K7: out1 = softmax(mq@k_l^T) @ t2 + depthwise conv(v) ----------------
__global__ __launch_bounds__(256) void k_attn1(const float* __restrict__ mq,
    const float* __restrict__ kl, const float* __restrict__ t2,
    const float* __restrict__ vb, const float* __restrict__ cwg,
    float* __restrict__ opre)
{
    __shared__ float kls[64][64];
    __shared__ float t2s[64][64];
    __shared__ float qp[64][68];
    __shared__ float cw[33];
    const int bh = blockIdx.x;
    const int b = bh >> 3, h = bh & 7;
    const int rg = blockIdx.y;
    const int tid = threadIdx.x;
    const int ty = tid >> 4, tx = tid & 15;

    for (int e = tid; e < 1024; e += 256) {
        int r = e >> 4, slot = e & 15;
        float4 kx = *(const float4*)(kl + (size_t)bh * 4096 + r * 64 + (slot << 2));
        *(float4*)&kls[r][((slot ^ ((r >> 2) & 15)) << 2)] = kx;
        float4 tx4 = *(const float4*)(t2 + (size_t)bh * 4096 + r * 64 + (slot << 2));
        *(float4*)&t2s[r][((slot ^ ((r >> 2) & 15)) << 2)] = tx4;
    }
    if (tid < 33) cw[tid] = cwg[h * 33 + tid];

    const float* mqb = mq + (size_t)bh * NP * DH;
    const float* vbase = vb + (size_t)bh * NTOT * DH;

    for (int sub = 0; sub < 4; ++sub) {
        const int row0 = (rg << 8) + (sub << 6);
        __syncthreads();
        for (int e = tid; e < 1024; e += 256) {
            int r = e >> 4, slot = e & 15;
            *(float4*)&qp[r][slot << 2] =
                *(const float4*)(mqb + (size_t)(row0 + r) * DH + (slot << 2));
        }
        __syncthreads();
        float s[4][4] = {};
        #pragma unroll
        for (int d4 = 0; d4 < 16; ++d4) {
            float4 qv[4], kvv[4];
            #pragma unroll
            for (int ii = 0; ii < 4; ++ii) qv[ii] = *(const float4*)&qp[(ty << 2) + ii][d4 << 2];
            #pragma unroll
            for (int jj = 0; jj < 4; ++jj)
                kvv[jj] = *(const float4*)&kls[(tx << 2) + jj][((d4 ^ tx) & 15) << 2];
            #pragma unroll
            for (int ii = 0; ii < 4; ++ii)
                #pragma unroll
                for (int jj = 0; jj < 4; ++jj) {
                    s[ii][jj] = fmaf(qv[ii].x, kvv[jj].x, s[ii][jj]);
                    s[ii][jj] = fmaf(qv[ii].y, kvv[jj].y, s[ii][jj]);
                    s[ii][jj] = fmaf(qv[ii].z, kvv[jj].z, s[ii][jj]);
                    s[ii][jj] = fmaf(qv[ii].w, kvv[jj].w, s[ii][jj]);
                }
        }
        float p[4][4];
        #pragma unroll
        for (int ii = 0; ii < 4; ++ii) {
            float rmax = fmaxf(fmaxf(s[ii][0], s[ii][1]), fmaxf(s[ii][2], s[ii][3]));
            #pragma unroll
            for (int off = 8; off; off >>= 1) rmax = fmaxf(rmax, __shfl_xor(rmax, off));
            float rs = 0.f;
            #pragma unroll
            for (int jj = 0; jj < 4; ++jj) { p[ii][jj] = expf(s[ii][jj] - rmax); rs += p[ii][jj]; }
            #pragma unroll
            for (int off = 8; off; off >>= 1) rs += __shfl_xor(rs, off);
            float rinv = 1.f / rs;
            #pragma unroll
            for (int jj = 0; jj < 4; ++jj) p[ii][jj] *= rinv;
        }
        __syncthreads();
        #pragma unroll
        for (int ii = 0; ii < 4; ++ii)
            *(float4*)&qp[(ty << 2) + ii][tx << 2] =
                make_float4(p[ii][0], p[ii][1], p[ii][2], p[ii][3]);
        __syncthreads();
        float o[4][4] = {};
        #pragma unroll
        for (int j4 = 0; j4 < 16; ++j4) {
            float4 pv4[4], vv[4];
            #pragma unroll
            for (int ii = 0; ii < 4; ++ii) pv4[ii] = *(const float4*)&qp[(ty << 2) + ii][j4 << 2];
            #pragma unroll
            for (int jj = 0; jj < 4; ++jj)
                vv[jj] = *(const float4*)&t2s[(j4 << 2) + jj][((tx ^ j4) & 15) << 2];
            #pragma unroll
            for (int ii = 0; ii < 4; ++ii) {
                #pragma unroll
                for (int jj = 0; jj < 4; ++jj) {
                    float pj = ((const float*)&pv4[ii])[jj];
                    #pragma unroll
                    for (int dd = 0; dd < 4; ++dd)
                        o[ii][dd] = fmaf(pj, ((const float*)&vv[jj])[dd], o[ii][dd]);
                }
            }
        }
        float cacc[4][4] = {};
        const int rbase = row0 + (ty << 2);
        #pragma unroll
        for (int kk = 0; kk < 36; ++kk) {
            int rr = rbase - 16 + kk;
            if (rr >= 0) {
                float4 vx = *(const float4*)(vbase + (size_t)rr * DH + (tx << 2));
                #pragma unroll
                for (int ii = 0; ii < 4; ++ii) {
                    int k = kk - ii;
                    if (k >= 0 && k < 33) {
                        float wv = cw[k];
                        cacc[ii][0] = fmaf(wv, vx.x, cacc[ii][0]);
                        cacc[ii][1] = fmaf(wv, vx.y, cacc[ii][1]);
                        cacc[ii][2] = fmaf(wv, vx.z, cacc[ii][2]);
                        cacc[ii][3] = fmaf(wv, vx.w, cacc[ii][3]);
                    }
                }
            }
        }
        #pragma unroll
        for (int ii = 0; ii < 4; ++ii) {
            int row = rbase + ii;
            float4 ov = make_float4(o[ii][0] + cacc[ii][0], o[ii][1] + cacc[ii][1],
                                    o[ii][2] + cacc[ii][2], o[ii][3] + cacc[ii][3]);
            *(float4*)(opre + ((size_t)b * NP + row) * DIM + h * DH + (tx << 2)) = ov;
        }
    }
}

extern "C" void kernel_launch(void* const* d_in, const int* in_sizes, int n_in,
                              void* d_out, int out_size, void* d_ws, size_t ws_size,
                              hipStream_t stream)
{
    const float* x   = (const float*)d_in[0];
    const float* ps  = (const float*)d_in[1];
    const float* wq  = (const float*)d_in[2];
    const float* wo  = (const float*)d_in[3];
    const float* cwg = (const float*)d_in[4];
    float* out = (float*)d_out;
    float* ws  = (float*)d_ws;

    float* mq   = out;               // d_out doubles as mq scratch; k_gemm<1> overwrites last
    float* kb   = ws + OFF_K;
    float* vb   = ws + OFF_V;
    float* ql   = ws + OFF_QL;
    float* kl   = ws + OFF_KL;
    float* a2   = ws + OFF_A2;
    float* t3   = ws + OFF_T3;
    float* t2   = ws + OFF_T2;
    float* mx   = ws + OFF_MAX;
    float* opre = ws + OFF_OPRE;
    float* pacc = opre;
    float* pm   = opre + 3145728ull;
    float* pl   = pm + 49152ull;
    _Float16* BTqh = (_Float16*)(ws + OFF_QL);
    _Float16* BTql = BTqh + 1536 * 512;
    _Float16* BToh = (_Float16*)(ws + OFF_K);
    _Float16* BTol = BToh + 512 * 512;

    k_cvtw        <<<dim3(24, 8), 256, 0, stream>>>(wq, BTqh, BTql, 512, 1536);
    k_gemm_split<0><<<dim3(12, 384), 256, 0, stream>>>(x, ps, BTqh, BTql, mq, kb, vb);
    k_land        <<<4096, 256, 0, stream>>>(mq, kb, ql, kl);
    k_sim2        <<<32, 256, 0, stream>>>(ql, kl, a2, mx);
    k_maxes       <<<32, 64, 0, stream>>>(a2, mx);
    k_sim3part    <<<dim3(32, NCH), 256, 0, stream>>>(ql, kb, vb, pacc, pm, pl);
    k_sim3comb    <<<32, 256, 0, stream>>>(pacc, pm, pl, t3);
    k_cvtw        <<<dim3(8, 8), 256, 0, stream>>>(wo, BToh, BTol, 512, 512);
    k_pinv        <<<32, 1024, 0, stream>>>(a2, mx, t3, t2);
    k_attn1       <<<dim3(32, 16), 256, 0, stream>>>(mq, kl, t2, vb, cwg, opre);
    k_gemm_split<1><<<dim3(4, 128), 256, 0, stream>>>(opre, nullptr, BToh, BTol, out, nullptr, nullptr);
}

// Round 8
// 793.319 us; speedup vs baseline: 3.4571x; 1.1242x over previous
//
#include <hip/hip_runtime.h>
#include <math.h>

#define Bb 4
#define Hh 8
#define NP 4096
#define PTOT 8192
#define NTOT 12288
#define DIM 512
#define DH 64
#define SCALE 0.125f
#define NCH 24
#define CHUNK 512

typedef __attribute__((ext_vector_type(8))) _Float16 f16x8;
typedef __attribute__((ext_vector_type(4))) _Float16 f16x4;
typedef __attribute__((ext_vector_type(4))) float f32x4;

// ---------------- workspace layout (float offsets) ----------------
#define SZ_K    (4ull*8*12288*64)      // 25,165,824
#define SZ_L    (32ull*64*64)          // 131,072
#define OFF_K    0ull
#define OFF_V    (OFF_K + SZ_K)
#define OFF_QL   (OFF_V + SZ_K)
#define OFF_KL   (OFF_QL + SZ_L)
#define OFF_A2   (OFF_KL + SZ_L)
#define OFF_T3   (OFF_A2 + SZ_L)
#define OFF_T2   (OFF_T3 + SZ_L)
#define OFF_MAX  (OFF_T2 + SZ_L)
#define OFF_OPRE (OFF_MAX + 16ull)
// total = 59,375,648 floats (237.5 MB) — proven fit.
// BTq aliases [OFF_QL...), BTo aliases kb (dead after k_sim3part).

__device__ __forceinline__ unsigned short hbits(_Float16 x) {
    union { _Float16 f; unsigned short u; } c; c.f = x; return c.u;
}

// ---------------- transpose + fp16-split weights: w[K][N] -> BT[N][K] hi/lo ----------------
__global__ __launch_bounds__(256) void k_cvtw(const float* __restrict__ w,
    _Float16* __restrict__ bh, _Float16* __restrict__ bl, int K, int N)
{
    __shared__ float t[64][65];
    const int n0 = blockIdx.x * 64, k0 = blockIdx.y * 64;
    const int tid = threadIdx.x;
    #pragma unroll
    for (int i = 0; i < 4; ++i) {
        int r = (tid >> 4) + i * 16;
        int c = (tid & 15) * 4;
        float4 v = *(const float4*)(w + (size_t)(k0 + r) * N + n0 + c);
        t[r][c] = v.x; t[r][c+1] = v.y; t[r][c+2] = v.z; t[r][c+3] = v.w;
    }
    __syncthreads();
    const int n = tid >> 2, kq = (tid & 3) * 16;
    f16x8 h8[2], l8[2];
    #pragma unroll
    for (int j = 0; j < 16; ++j) {
        float a = t[kq + j][n];
        _Float16 hh = (_Float16)a;
        _Float16 ll = (_Float16)(a - (float)hh);
        h8[j >> 3][j & 7] = hh;
        l8[j >> 3][j & 7] = ll;
    }
    size_t o = (size_t)(n0 + n) * K + k0 + kq;
    *(f16x8*)(bh + o) = h8[0]; *(f16x8*)(bh + o + 8) = h8[1];
    *(f16x8*)(bl + o) = l8[0]; *(f16x8*)(bl + o + 8) = l8[1];
}

// ---------------- fp16-split MFMA GEMM, 2-phase dbuf, depth-2 prefetch, XCD swizzle ------
__device__ __forceinline__ int hoff(int r, int slot) {
    return r * 32 + (((slot ^ (r >> 1)) & 3) << 3);
}

// 1D grid; NB n-tiles per m-row. id -> (m,n) such that the NB blocks of one m-row
// land on ONE XCD (ids differ by 8 -> same XCD under round-robin dispatch).
template<int MODE>
__global__ __launch_bounds__(256) void k_gemm_split(
    const float* __restrict__ Asrc0, const float* __restrict__ Asrc1,
    const _Float16* __restrict__ BTh, const _Float16* __restrict__ BTl,
    float* __restrict__ out0, float* __restrict__ out1, float* __restrict__ out2)
{
    __shared__ __align__(16) _Float16 Ah[2][128 * 32], Al[2][128 * 32];
    __shared__ __align__(16) _Float16 Bh[2][128 * 32], Bl[2][128 * 32];
    const int NB = (MODE == 0) ? 12 : 4;
    const int id = blockIdx.x;
    const int w8 = id % (NB * 8);
    const int n0 = (w8 >> 3) * 128;
    const int m0 = ((id / (NB * 8)) * 8 + (w8 & 7)) * 128;
    const int tid = threadIdx.x;
    const int wv = tid >> 6, lane = tid & 63;
    const int wr = wv >> 1, wc = wv & 1;
    const int kslot = lane >> 4;

    int ar[2], asl[2];
    const float* aptr[2];
    #pragma unroll
    for (int i = 0; i < 2; ++i) {
        int id2 = tid + 256 * i;
        ar[i] = id2 >> 2; asl[i] = id2 & 3;
        int grow = m0 + ar[i];
        if (MODE == 0) {
            int bi = grow / NTOT;
            int pos = grow - bi * NTOT;
            aptr[i] = (pos < NP) ? (Asrc0 + ((size_t)bi * NP + pos) * DIM)
                                 : (Asrc1 + ((size_t)bi * PTOT + (pos - NP)) * DIM);
        } else {
            aptr[i] = Asrc0 + (size_t)grow * DIM;
        }
    }

    float4 a0[2], a1[2];
    f16x8 vbh[2], vbl[2];

    auto LOADT = [&](int k0) {
        #pragma unroll
        for (int i = 0; i < 2; ++i) {
            a0[i] = *(const float4*)(aptr[i] + k0 + asl[i] * 8);
            a1[i] = *(const float4*)(aptr[i] + k0 + asl[i] * 8 + 4);
            size_t bo = (size_t)(n0 + ar[i]) * DIM + k0 + asl[i] * 8;
            vbh[i] = *(const f16x8*)(BTh + bo);
            vbl[i] = *(const f16x8*)(BTl + bo);
        }
    };
    auto WRITET = [&](int buf) {
        #pragma unroll
        for (int i = 0; i < 2; ++i) {
            f16x8 h, l;
            float vals[8] = {a0[i].x, a0[i].y, a0[i].z, a0[i].w,
                             a1[i].x, a1[i].y, a1[i].z, a1[i].w};
            #pragma unroll
            for (int j = 0; j < 8; ++j) {
                _Float16 hh = (_Float16)vals[j];
                h[j] = hh;
                l[j] = (_Float16)(vals[j] - (float)hh);
            }
            int o = hoff(ar[i], asl[i]);
            *(f16x8*)&Ah[buf][o] = h;
            *(f16x8*)&Al[buf][o] = l;
            *(f16x8*)&Bh[buf][o] = vbh[i];
            *(f16x8*)&Bl[buf][o] = vbl[i];
        }
    };

    LOADT(0);
    WRITET(0);
    LOADT(32);          // tile 1 in regs
    int cur = 0;

    f32x4 acc[4][4] = {};
    for (int t = 0; t < 16; ++t) {
        __syncthreads();                   // buf[cur] complete; all reads of buf[cur^1] done
        f16x8 afh[4], afl[4];
        #pragma unroll
        for (int m = 0; m < 4; ++m) {
            int o = hoff(wr * 64 + m * 16 + (lane & 15), kslot);
            afh[m] = *(const f16x8*)&Ah[cur][o];
            afl[m] = *(const f16x8*)&Al[cur][o];
        }
        f16x8 bfh[4], bfl[4];
        #pragma unroll
        for (int n = 0; n < 4; ++n) {
            int o = hoff(wc * 64 + n * 16 + (lane & 15), kslot);
            bfh[n] = *(const f16x8*)&Bh[cur][o];
            bfl[n] = *(const f16x8*)&Bl[cur][o];
        }
        if (t < 15) WRITET(cur ^ 1);       // write tile t+1 (regs) while MFMA below runs
        if (t < 14) LOADT((t + 2) * 32);   // issue tile t+2 loads — a full iter to land
        #pragma unroll
        for (int n = 0; n < 4; ++n)
            #pragma unroll
            for (int m = 0; m < 4; ++m) {
                acc[m][n] = __builtin_amdgcn_mfma_f32_16x16x32_f16(afh[m], bfh[n], acc[m][n], 0, 0, 0);
                acc[m][n] = __builtin_amdgcn_mfma_f32_16x16x32_f16(afh[m], bfl[n], acc[m][n], 0, 0, 0);
                acc[m][n] = __builtin_amdgcn_mfma_f32_16x16x32_f16(afl[m], bfh[n], acc[m][n], 0, 0, 0);
            }
        cur ^= 1;
    }
    #pragma unroll
    for (int m = 0; m < 4; ++m) {
        #pragma unroll
        for (int n = 0; n < 4; ++n) {
            int gcol = n0 + wc * 64 + n * 16 + (lane & 15);
            int rbase = m0 + wr * 64 + m * 16 + (lane >> 4) * 4;
            if (MODE == 1) {
                #pragma unroll
                for (int r = 0; r < 4; ++r)
                    out0[(size_t)(rbase + r) * DIM + gcol] = acc[m][n][r];
            } else {
                int which = gcol >> 9, h = (gcol >> 6) & 7, d = gcol & 63;
                #pragma unroll
                for (int r = 0; r < 4; ++r) {
                    int row = rbase + r;
                    int bi = row / NTOT;
                    int p = row - bi * NTOT;
                    float v = acc[m][n][r];
                    if (which == 0) {
                        if (p < NP) out0[(((size_t)bi * Hh + h) * NP + p) * DH + d] = v * SCALE;
                    } else if (which == 1) {
                        out1[(((size_t)bi * Hh + h) * NTOT + p) * DH + d] = v;
                    } else {
                        out2[(((size_t)bi * Hh + h) * NTOT + p) * DH + d] = v;
                    }
                }
            }
        }
    }
}

// ---------------- K2: landmark means (vectorized) ----------------
__global__ __launch_bounds__(256) void k_land(const float* __restrict__ mq,
    const float* __restrict__ kb, float* __restrict__ ql, float* __restrict__ kl)
{
    __shared__ float part[16][64];
    int idx = blockIdx.x;
    const int tid = threadIdx.x;
    const int rg = tid >> 4, c4 = (tid & 15) << 2;
    const float* src;
    float* dst;
    int R; float sc;
    if (idx < 2048) {
        int bh = idx >> 6, i = idx & 63;
        src = mq + ((size_t)bh * NP + i * 64) * DH;
        dst = ql + ((size_t)bh * 64 + i) * 64;
        R = 64; sc = 1.f / 64.f;
    } else {
        idx -= 2048;
        int bh = idx >> 6, i = idx & 63;
        src = kb + ((size_t)bh * NTOT + i * 192) * DH;
        dst = kl + ((size_t)bh * 64 + i) * 64;
        R = 192; sc = 1.f / 192.f;
    }
    float4 a = make_float4(0.f, 0.f, 0.f, 0.f);
    for (int r = rg; r < R; r += 16) {
        float4 v = *(const float4*)(src + (size_t)r * DH + c4);
        a.x += v.x; a.y += v.y; a.z += v.z; a.w += v.w;
    }
    *(float4*)&part[rg][c4] = a;
    __syncthreads();
    if (tid < 64) {
        float s = 0.f;
        #pragma unroll
        for (int g = 0; g < 16; ++g) s += part[g][tid];
        dst[tid] = s * sc;
    }
}

// ---------------- K3: attn2 = softmax(q_l @ k_l^T); also zero-inits mx ----------------
__global__ __launch_bounds__(256) void k_sim2(const float* __restrict__ ql,
    const float* __restrict__ kl, float* __restrict__ a2, float* __restrict__ mx)
{
    __shared__ float qs[64][64];
    __shared__ float ks[64][65];
    __shared__ float S[64][65];
    const int tid = threadIdx.x;
    const int bh = blockIdx.x;
    if (bh == 0 && tid < 2) mx[tid] = 0.f;
    for (int e = tid; e < 4096; e += 256) {
        qs[e >> 6][e & 63] = ql[(size_t)bh * 4096 + e];
        ks[e >> 6][e & 63] = kl[(size_t)bh * 4096 + e];
    }
    __syncthreads();
    for (int sI = 0; sI < 16; ++sI) {
        int e = (sI << 8) + tid;
        int i = e >> 6, j = e & 63;
        float acc = 0.f;
        #pragma unroll 16
        for (int d = 0; d < 64; ++d) acc = fmaf(qs[i][d], ks[j][d], acc);
        S[i][j] = acc;
    }
    __syncthreads();
    const int wv = tid >> 6, lane = tid & 63;
    for (int i = wv; i < 64; i += 4) {
        float v = S[i][lane];
        float mxv = v;
        #pragma unroll
        for (int off = 32; off; off >>= 1) mxv = fmaxf(mxv, __shfl_xor(mxv, off));
        float p = expf(v - mxv);
        float sm = p;
        #pragma unroll
        for (int off = 32; off; off >>= 1) sm += __shfl_xor(sm, off);
        a2[((size_t)bh * 64 + i) * 64 + lane] = p / sm;
    }
}

// ---------------- K4: global max of row/col abs-sums of attn2 ----------------
__global__ __launch_bounds__(64) void k_maxes(const float* __restrict__ a2,
    float* __restrict__ mx)
{
    const int bh = blockIdx.x;
    const int i = threadIdx.x;
    const float* base = a2 + (size_t)bh * 4096;
    float cs = 0.f, rs = 0.f;
    for (int j = 0; j < 64; ++j) {
        cs += fabsf(base[i * 64 + j]);
        rs += fabsf(base[j * 64 + i]);
    }
    #pragma unroll
    for (int off = 32; off; off >>= 1) {
        cs = fmaxf(cs, __shfl_xor(cs, off));
        rs = fmaxf(rs, __shfl_xor(rs, off));
    }
    if (i == 0) {
        atomicMax((unsigned int*)&mx[0], __float_as_uint(cs));
        atomicMax((unsigned int*)&mx[1], __float_as_uint(rs));
    }
}

// ---------------- K5a: sim3 partials — fp16-split MFMA flash over a 512-row chunk ----------
__global__ __launch_bounds__(256) void k_sim3part(const float* __restrict__ qlg,
    const float* __restrict__ kb, const float* __restrict__ vb,
    float* __restrict__ pacc, float* __restrict__ pm, float* __restrict__ pl)
{
    __shared__ __align__(16) _Float16 qsh[4096], qsl[4096];
    __shared__ __align__(16) _Float16 kvh[4096], kvl[4096];
    __shared__ __align__(16) unsigned int pss[64][68];
    __shared__ float corr_s[64];
    const int bh = blockIdx.x, ch = blockIdx.y;
    const int tid = threadIdx.x;
    const int wv = tid >> 6, lane = tid & 63;
    const int lg = lane >> 4, ll = lane & 15;

    #pragma unroll
    for (int it = 0; it < 4; ++it) {
        int e = tid + 256 * it;
        int r = e >> 4, c0 = (e & 15) << 2;
        float4 qv = *(const float4*)(qlg + (size_t)bh * 4096 + r * 64 + c0);
        f16x4 h, l;
        float vals[4] = {qv.x, qv.y, qv.z, qv.w};
        #pragma unroll
        for (int i = 0; i < 4; ++i) {
            _Float16 hh = (_Float16)vals[i];
            h[i] = hh; l[i] = (_Float16)(vals[i] - (float)hh);
        }
        int off = r * 64 + (((c0 >> 3) ^ (r & 7)) << 3) + (c0 & 7);
        *(f16x4*)&qsh[off] = h;
        *(f16x4*)&qsl[off] = l;
    }

    const float* kc = kb + ((size_t)bh * NTOT + ch * CHUNK) * DH;
    const float* vc = vb + ((size_t)bh * NTOT + ch * CHUNK) * DH;

    float m_run = -INFINITY, l_run = 0.f;
    f32x4 acc_o[4] = {};

    for (int t = 0; t < CHUNK / 64; ++t) {
        __syncthreads();
        #pragma unroll
        for (int it = 0; it < 4; ++it) {
            int e = tid + 256 * it;
            int r = e >> 4, c0 = (e & 15) << 2;
            float4 kx = *(const float4*)(kc + (size_t)(t * 64 + r) * DH + c0);
            f16x4 h, l;
            float vals[4] = {kx.x, kx.y, kx.z, kx.w};
            #pragma unroll
            for (int i = 0; i < 4; ++i) {
                _Float16 hh = (_Float16)vals[i];
                h[i] = hh; l[i] = (_Float16)(vals[i] - (float)hh);
            }
            int off = r * 64 + (((c0 >> 3) ^ (r & 7)) << 3) + (c0 & 7);
            *(f16x4*)&kvh[off] = h;
            *(f16x4*)&kvl[off] = l;
        }
        __syncthreads();
        f32x4 accs[4] = {};
        #pragma unroll
        for (int ks = 0; ks < 2; ++ks) {
            int k0 = 32 * ks + (lg << 3);
            int brow = 16 * wv + ll;
            int boff = brow * 64 + (((k0 >> 3) ^ (brow & 7)) << 3);
            f16x8 bh8 = *(const f16x8*)&kvh[boff];
            f16x8 bl8 = *(const f16x8*)&kvl[boff];
            #pragma unroll
            for (int m = 0; m < 4; ++m) {
                int arow = 16 * m + ll;
                int aoff = arow * 64 + (((k0 >> 3) ^ (arow & 7)) << 3);
                f16x8 ah8 = *(const f16x8*)&qsh[aoff];
                f16x8 al8 = *(const f16x8*)&qsl[aoff];
                accs[m] = __builtin_amdgcn_mfma_f32_16x16x32_f16(ah8, bh8, accs[m], 0, 0, 0);
                accs[m] = __builtin_amdgcn_mfma_f32_16x16x32_f16(ah8, bl8, accs[m], 0, 0, 0);
                accs[m] = __builtin_amdgcn_mfma_f32_16x16x32_f16(al8, bh8, accs[m], 0, 0, 0);
            }
        }
        #pragma unroll
        for (int m = 0; m < 4; ++m)
            #pragma unroll
            for (int rg = 0; rg < 4; ++rg)
                pss[16 * m + lg * 4 + rg][16 * wv + ll] = __float_as_uint(accs[m][rg]);
        __syncthreads();
        {
            const int r = tid >> 2, q = tid & 3;
            float s[16];
            uint4 u0 = *(const uint4*)&pss[r][q * 16];
            uint4 u1 = *(const uint4*)&pss[r][q * 16 + 4];
            uint4 u2 = *(const uint4*)&pss[r][q * 16 + 8];
            uint4 u3 = *(const uint4*)&pss[r][q * 16 + 12];
            s[0]=__uint_as_float(u0.x); s[1]=__uint_as_float(u0.y); s[2]=__uint_as_float(u0.z); s[3]=__uint_as_float(u0.w);
            s[4]=__uint_as_float(u1.x); s[5]=__uint_as_float(u1.y); s[6]=__uint_as_float(u1.z); s[7]=__uint_as_float(u1.w);
            s[8]=__uint_as_float(u2.x); s[9]=__uint_as_float(u2.y); s[10]=__uint_as_float(u2.z); s[11]=__uint_as_float(u2.w);
            s[12]=__uint_as_float(u3.x); s[13]=__uint_as_float(u3.y); s[14]=__uint_as_float(u3.z); s[15]=__uint_as_float(u3.w);
            float lmax = s[0];
            #pragma unroll
            for (int i = 1; i < 16; ++i) lmax = fmaxf(lmax, s[i]);
            lmax = fmaxf(lmax, __shfl_xor(lmax, 1));
            lmax = fmaxf(lmax, __shfl_xor(lmax, 2));
            float mnew = fmaxf(m_run, lmax);
            float corr = expf(m_run - mnew);
            float p[16], rsum = 0.f;
            #pragma unroll
            for (int i = 0; i < 16; ++i) { p[i] = expf(s[i] - mnew); rsum += p[i]; }
            rsum += __shfl_xor(rsum, 1);
            rsum += __shfl_xor(rsum, 2);
            l_run = l_run * corr + rsum;
            m_run = mnew;
            if (q == 0) corr_s[r] = corr;
            #pragma unroll
            for (int i2 = 0; i2 < 8; ++i2) {
                float p0 = p[2 * i2], p1 = p[2 * i2 + 1];
                _Float16 h0 = (_Float16)p0, h1 = (_Float16)p1;
                _Float16 e0 = (_Float16)(p0 - (float)h0), e1 = (_Float16)(p1 - (float)h1);
                pss[r][q * 8 + i2]      = (unsigned int)hbits(h0) | ((unsigned int)hbits(h1) << 16);
                pss[r][32 + q * 8 + i2] = (unsigned int)hbits(e0) | ((unsigned int)hbits(e1) << 16);
            }
        }
        {
            const int r0 = (tid & 31) * 2, cb = (tid >> 5) * 4;
            #pragma unroll
            for (int ci = 0; ci < 2; ++ci) {
                int c0 = cb + 32 * ci;
                float4 v0 = *(const float4*)(vc + (size_t)(t * 64 + r0) * DH + c0);
                float4 v1 = *(const float4*)(vc + (size_t)(t * 64 + r0 + 1) * DH + c0);
                float a0[4] = {v0.x, v0.y, v0.z, v0.w};
                float a1[4] = {v1.x, v1.y, v1.z, v1.w};
                #pragma unroll
                for (int i = 0; i < 4; ++i) {
                    int c = c0 + i;
                    _Float16 h0 = (_Float16)a0[i], h1 = (_Float16)a1[i];
                    _Float16 e0 = (_Float16)(a0[i] - (float)h0), e1 = (_Float16)(a1[i] - (float)h1);
                    int off = c * 64 + (((r0 >> 3) ^ (c & 7)) << 3) + (r0 & 7);
                    *(unsigned int*)&kvh[off] = (unsigned int)hbits(h0) | ((unsigned int)hbits(h1) << 16);
                    *(unsigned int*)&kvl[off] = (unsigned int)hbits(e0) | ((unsigned int)hbits(e1) << 16);
                }
            }
        }
        __syncthreads();
        #pragma unroll
        for (int m = 0; m < 4; ++m)
            #pragma unroll
            for (int rg = 0; rg < 4; ++rg)
                acc_o[m][rg] *= corr_s[16 * m + lg * 4 + rg];
        #pragma unroll
        for (int ks = 0; ks < 2; ++ks) {
            int k0 = 32 * ks + (lg << 3);
            int dh = 16 * wv + ll;
            int boff = dh * 64 + (((k0 >> 3) ^ (dh & 7)) << 3);
            f16x8 vh8 = *(const f16x8*)&kvh[boff];
            f16x8 vl8 = *(const f16x8*)&kvl[boff];
            #pragma unroll
            for (int m = 0; m < 4; ++m) {
                int prow = 16 * m + ll;
                union { uint4 u; f16x8 f; } ph, pe;
                ph.u = *(const uint4*)&pss[prow][16 * ks + lg * 4];
                pe.u = *(const uint4*)&pss[prow][32 + 16 * ks + lg * 4];
                acc_o[m] = __builtin_amdgcn_mfma_f32_16x16x32_f16(ph.f, vh8, acc_o[m], 0, 0, 0);
                acc_o[m] = __builtin_amdgcn_mfma_f32_16x16x32_f16(ph.f, vl8, acc_o[m], 0, 0, 0);
                acc_o[m] = __builtin_amdgcn_mfma_f32_16x16x32_f16(pe.f, vh8, acc_o[m], 0, 0, 0);
            }
        }
    }
    const size_t base = ((size_t)bh * NCH + ch) * 64;
    #pragma unroll
    for (int m = 0; m < 4; ++m)
        #pragma unroll
        for (int rg = 0; rg < 4; ++rg) {
            int row = 16 * m + lg * 4 + rg;
            pacc[(base + row) * 64 + 16 * wv + ll] = acc_o[m][rg];
        }
    if ((tid & 3) == 0) {
        int r = tid >> 2;
        pm[base + r] = m_run;
        pl[base + r] = l_run;
    }
}

// ---------------- K5b: combine sim3 partials -> t3 ----------------
__global__ __launch_bounds__(256) void k_sim3comb(const float* __restrict__ pacc,
    const float* __restrict__ pm, const float* __restrict__ pl, float* __restrict__ t3)
{
    __shared__ float w[NCH][64];
    __shared__ float Linv[64];
    const int bh = blockIdx.x;
    const int tid = threadIdx.x;
    if (tid < 64) {
        float M = -INFINITY;
        for (int c = 0; c < NCH; ++c)
            M = fmaxf(M, pm[((size_t)bh * NCH + c) * 64 + tid]);
        float L = 0.f;
        for (int c = 0; c < NCH; ++c) {
            float e = expf(pm[((size_t)bh * NCH + c) * 64 + tid] - M);
            w[c][tid] = e;
            L = fmaf(e, pl[((size_t)bh * NCH + c) * 64 + tid], L);
        }
        Linv[tid] = 1.f / L;
    }
    __syncthreads();
    const int wv = tid >> 6, lane = tid & 63;
    for (int p = 0; p < 16; ++p) {
        int i = (p << 2) + wv;
        float o = 0.f;
        for (int c = 0; c < NCH; ++c)
            o = fmaf(w[c][i], pacc[(((size_t)bh * NCH + c) * 64 + i) * 64 + lane], o);
        t3[((size_t)bh * 64 + i) * 64 + lane] = o * Linv[i];
    }
}

// ---------------- K6: pinv (LDS-resident, 256 thr, 4x4 register tiles) + t2 = z @ t3 -----
// B read: one float4 per k serving 16 outputs (quad-broadcast, conflict-free);
// A read: 4 wave-broadcast b32 per k. In-place safe: all operand reads before the
// mid-barrier; S reads in the write phase only where S aliases C elementwise.
__device__ __forceinline__ void mm64t(float* __restrict__ C, const float* A,
    const float* Bm, const float* S, float sa, float sm, int tid)
{
    const int ty = tid >> 4, tx = tid & 15;
    float r[4][4] = {};
    __syncthreads();
    #pragma unroll 4
    for (int k = 0; k < 64; ++k) {
        float4 b4 = *(const float4*)&Bm[(k << 6) + (tx << 2)];
        #pragma unroll
        for (int i = 0; i < 4; ++i) {
            float a = A[(((ty << 2) + i) << 6) + k];
            r[i][0] = fmaf(a, b4.x, r[i][0]);
            r[i][1] = fmaf(a, b4.y, r[i][1]);
            r[i][2] = fmaf(a, b4.z, r[i][2]);
            r[i][3] = fmaf(a, b4.w, r[i][3]);
        }
    }
    __syncthreads();
    #pragma unroll
    for (int i = 0; i < 4; ++i) {
        int e = (((ty << 2) + i) << 6) + (tx << 2);
        float4 v = make_float4(sm * r[i][0], sm * r[i][1], sm * r[i][2], sm * r[i][3]);
        if (S) {
            v.x = fmaf(sa, S[e], v.x);     v.y = fmaf(sa, S[e + 1], v.y);
            v.z = fmaf(sa, S[e + 2], v.z); v.w = fmaf(sa, S[e + 3], v.w);
        }
        *(float4*)&C[e] = v;
    }
    __syncthreads();
}

__device__ __forceinline__ void mm64gt(float* __restrict__ C, const float* __restrict__ Ag,
    const float* __restrict__ Bm, int tid)
{
    const int ty = tid >> 4, tx = tid & 15;
    float r[4][4] = {};
    __syncthreads();
    #pragma unroll 4
    for (int k = 0; k < 64; ++k) {
        float4 b4 = *(const float4*)&Bm[(k << 6) + (tx << 2)];
        #pragma unroll
        for (int i = 0; i < 4; ++i) {
            float a = Ag[(((ty << 2) + i) << 6) + k];
            r[i][0] = fmaf(a, b4.x, r[i][0]);
            r[i][1] = fmaf(a, b4.y, r[i][1]);
            r[i][2] = fmaf(a, b4.z, r[i][2]);
            r[i][3] = fmaf(a, b4.w, r[i][3]);
        }
    }
    __syncthreads();
    #pragma unroll
    for (int i = 0; i < 4; ++i) {
        int e = (((ty << 2) + i) << 6) + (tx << 2);
        *(float4*)&C[e] = make_float4(r[i][0], r[i][1], r[i][2], r[i][3]);
    }
    __syncthreads();
}

__global__ __launch_bounds__(256) void k_pinv(const float* __restrict__ attn2,
    const float* __restrict__ mx, const float* __restrict__ t3g, float* __restrict__ t2g)
{
    __shared__ float Zs[4096], Ab[4096], Db[4096];
    const int tid = threadIdx.x;
    const int bh = blockIdx.x;
    const float inv = 1.0f / (mx[0] * mx[1]);
    const float* a2 = attn2 + (size_t)bh * 4096;
    for (int e = tid; e < 4096; e += 256) {
        int i = e >> 6, j = e & 63;
        Zs[e] = a2[(j << 6) + i] * inv;
    }
    for (int it = 0; it < 6; ++it) {
        mm64gt(Ab, a2, Zs, tid);                     // A = X@Z
        mm64t(Db, Ab, Ab, Ab, 7.f, -1.f, tid);       // D' = 7A - A@A
        for (int e = tid; e < 4096; e += 256) {
            int i = e >> 6, j = e & 63;
            Db[e] = ((i == j) ? 15.f : 0.f) - Db[e]; // D = 15I - 7A + A@A
        }
        mm64t(Ab, Zs, Ab, nullptr, 0.f, 1.f, tid);   // A <- P = Z@A
        mm64t(Zs, Ab, Db, Zs, 3.25f, -0.25f, tid);   // Z <- 3.25Z - 0.25 P@D
    }
    for (int e = tid; e < 4096; e += 256) Ab[e] = t3g[(size_t)bh * 4096 + e];
    mm64t(Db, Zs, Ab, nullptr, 0.f, 1.f, tid);       // t2 = Z @ t3
    for (int e = tid; e < 4096; e += 256) t2g[(size_t)bh * 4096 + e] = Db[e];
}

// ---------------- K7: out1 = softmax(mq@k_l^T) @ t2 + depthwise conv(v) ----------------
__global__ __launch_bounds__(256) void k_attn1(const float* __restrict__ mq,
    const float* __restrict__ kl, const float* __restrict__ t2,
    const float* __restrict__ vb, const float* __restrict__ cwg,
    float* __restrict__ opre)
{
    __shared__ float kls[64][64];
    __shared__ float t2s[64][64];
    __shared__ float qp[64][68];
    __shared__ float cw[33];
    const int bh = blockIdx.x;
    const int b = bh >> 3, h = bh & 7;
    const int rg = blockIdx.y;
    const int tid = threadIdx.x;
    const int ty = tid >> 4, tx = tid & 15;

    for (int e = tid; e < 1024; e += 256) {
        int r = e >> 4, slot = e & 15;
        float4 kx = *(const float4*)(kl + (size_t)bh * 4096 + r * 64 + (slot << 2));
        *(float4*)&kls[r][((slot ^ ((r >> 2) & 15)) << 2)] = kx;
        float4 tx4 = *(const float4*)(t2 + (size_t)bh * 4096 + r * 64 + (slot << 2));
        *(float4*)&t2s[r][((slot ^ ((r >> 2) & 15)) << 2)] = tx4;
    }
    if (tid < 33) cw[tid] = cwg[h * 33 + tid];

    const float* mqb = mq + (size_t)bh * NP * DH;
    const float* vbase = vb + (size_t)bh * NTOT * DH;

    for (int sub = 0; sub < 4; ++sub) {
        const int row0 = (rg << 8) + (sub << 6);
        __syncthreads();
        for (int e = tid; e < 1024; e += 256) {
            int r = e >> 4, slot = e & 15;
            *(float4*)&qp[r][slot << 2] =
                *(const float4*)(mqb + (size_t)(row0 + r) * DH + (slot << 2));
        }
        __syncthreads();
        float s[4][4] = {};
        #pragma unroll
        for (int d4 = 0; d4 < 16; ++d4) {
            float4 qv[4], kvv[4];
            #pragma unroll
            for (int ii = 0; ii < 4; ++ii) qv[ii] = *(const float4*)&qp[(ty << 2) + ii][d4 << 2];
            #pragma unroll
            for (int jj = 0; jj < 4; ++jj)
                kvv[jj] = *(const float4*)&kls[(tx << 2) + jj][((d4 ^ tx) & 15) << 2];
            #pragma unroll
            for (int ii = 0; ii < 4; ++ii)
                #pragma unroll
                for (int jj = 0; jj < 4; ++jj) {
                    s[ii][jj] = fmaf(qv[ii].x, kvv[jj].x, s[ii][jj]);
                    s[ii][jj] = fmaf(qv[ii].y, kvv[jj].y, s[ii][jj]);
                    s[ii][jj] = fmaf(qv[ii].z, kvv[jj].z, s[ii][jj]);
                    s[ii][jj] = fmaf(qv[ii].w, kvv[jj].w, s[ii][jj]);
                }
        }
        float p[4][4];
        #pragma unroll
        for (int ii = 0; ii < 4; ++ii) {
            float rmax = fmaxf(fmaxf(s[ii][0], s[ii][1]), fmaxf(s[ii][2], s[ii][3]));
            #pragma unroll
            for (int off = 8; off; off >>= 1) rmax = fmaxf(rmax, __shfl_xor(rmax, off));
            float rs = 0.f;
            #pragma unroll
            for (int jj = 0; jj < 4; ++jj) { p[ii][jj] = expf(s[ii][jj] - rmax); rs += p[ii][jj]; }
            #pragma unroll
            for (int off = 8; off; off >>= 1) rs += __shfl_xor(rs, off);
            float rinv = 1.f / rs;
            #pragma unroll
            for (int jj = 0; jj < 4; ++jj) p[ii][jj] *= rinv;
        }
        __syncthreads();
        #pragma unroll
        for (int ii = 0; ii < 4; ++ii)
            *(float4*)&qp[(ty << 2) + ii][tx << 2] =
                make_float4(p[ii][0], p[ii][1], p[ii][2], p[ii][3]);
        __syncthreads();
        float o[4][4] = {};
        #pragma unroll
        for (int j4 = 0; j4 < 16; ++j4) {
            float4 pv4[4], vv[4];
            #pragma unroll
            for (int ii = 0; ii < 4; ++ii) pv4[ii] = *(const float4*)&qp[(ty << 2) + ii][j4 << 2];
            #pragma unroll
            for (int jj = 0; jj < 4; ++jj)
                vv[jj] = *(const float4*)&t2s[(j4 << 2) + jj][((tx ^ j4) & 15) << 2];
            #pragma unroll
            for (int ii = 0; ii < 4; ++ii) {
                #pragma unroll
                for (int jj = 0; jj < 4; ++jj) {
                    float pj = ((const float*)&pv4[ii])[jj];
                    #pragma unroll
                    for (int dd = 0; dd < 4; ++dd)
                        o[ii][dd] = fmaf(pj, ((const float*)&vv[jj])[dd], o[ii][dd]);
                }
            }
        }
        float cacc[4][4] = {};
        const int rbase = row0 + (ty << 2);
        #pragma unroll
        for (int kk = 0; kk < 36; ++kk) {
            int rr = rbase - 16 + kk;
            if (rr >= 0) {
                float4 vx = *(const float4*)(vbase + (size_t)rr * DH + (tx << 2));
                #pragma unroll
                for (int ii = 0; ii < 4; ++ii) {
                    int k = kk - ii;
                    if (k >= 0 && k < 33) {
                        float wv = cw[k];
                        cacc[ii][0] = fmaf(wv, vx.x, cacc[ii][0]);
                        cacc[ii][1] = fmaf(wv, vx.y, cacc[ii][1]);
                        cacc[ii][2] = fmaf(wv, vx.z, cacc[ii][2]);
                        cacc[ii][3] = fmaf(wv, vx.w, cacc[ii][3]);
                    }
                }
            }
        }
        #pragma unroll
        for (int ii = 0; ii < 4; ++ii) {
            int row = rbase + ii;
            float4 ov = make_float4(o[ii][0] + cacc[ii][0], o[ii][1] + cacc[ii][1],
                                    o[ii][2] + cacc[ii][2], o[ii][3] + cacc[ii][3]);
            *(float4*)(opre + ((size_t)b * NP + row) * DIM + h * DH + (tx << 2)) = ov;
        }
    }
}

extern "C" void kernel_launch(void* const* d_in, const int* in_sizes, int n_in,
                              void* d_out, int out_size, void* d_ws, size_t ws_size,
                              hipStream_t stream)
{
    const float* x   = (const float*)d_in[0];
    const float* ps  = (const float*)d_in[1];
    const float* wq  = (const float*)d_in[2];
    const float* wo  = (const float*)d_in[3];
    const float* cwg = (const float*)d_in[4];
    float* out = (float*)d_out;
    float* ws  = (float*)d_ws;

    float* mq   = out;               // d_out doubles as mq scratch; k_gemm<1> overwrites last
    float* kb   = ws + OFF_K;
    float* vb   = ws + OFF_V;
    float* ql   = ws + OFF_QL;
    float* kl   = ws + OFF_KL;
    float* a2   = ws + OFF_A2;
    float* t3   = ws + OFF_T3;
    float* t2   = ws + OFF_T2;
    float* mx   = ws + OFF_MAX;
    float* opre = ws + OFF_OPRE;
    float* pacc = opre;
    float* pm   = opre + 3145728ull;
    float* pl   = pm + 49152ull;
    _Float16* BTqh = (_Float16*)(ws + OFF_QL);
    _Float16* BTql = BTqh + 1536 * 512;
    _Float16* BToh = (_Float16*)(ws + OFF_K);
    _Float16* BTol = BToh + 512 * 512;

    k_cvtw        <<<dim3(24, 8), 256, 0, stream>>>(wq, BTqh, BTql, 512, 1536);
    k_gemm_split<0><<<4608, 256, 0, stream>>>(x, ps, BTqh, BTql, mq, kb, vb);
    k_land        <<<4096, 256, 0, stream>>>(mq, kb, ql, kl);
    k_sim2        <<<32, 256, 0, stream>>>(ql, kl, a2, mx);
    k_maxes       <<<32, 64, 0, stream>>>(a2, mx);
    k_sim3part    <<<dim3(32, NCH), 256, 0, stream>>>(ql, kb, vb, pacc, pm, pl);
    k_sim3comb    <<<32, 256, 0, stream>>>(pacc, pm, pl, t3);
    k_cvtw        <<<dim3(8, 8), 256, 0, stream>>>(wo, BToh, BTol, 512, 512);
    k_pinv        <<<32, 256, 0, stream>>>(a2, mx, t3, t2);
    k_attn1       <<<dim3(32, 16), 256, 0, stream>>>(mq, kl, t2, vb, cwg, opre);
    k_gemm_split<1><<<512, 256, 0, stream>>>(opre, nullptr, BToh, BTol, out, nullptr, nullptr);
}

// Round 9
// 745.928 us; speedup vs baseline: 3.6767x; 1.0635x over previous
//
#include <hip/hip_runtime.h>
#include <math.h>

#define Bb 4
#define Hh 8
#define NP 4096
#define PTOT 8192
#define NTOT 12288
#define DIM 512
#define DH 64
#define SCALE 0.125f
#define NCH 24
#define CHUNK 512

typedef __attribute__((ext_vector_type(8))) _Float16 f16x8;
typedef __attribute__((ext_vector_type(4))) _Float16 f16x4;
typedef __attribute__((ext_vector_type(4))) float f32x4;

// ---------------- workspace layout (float offsets) ----------------
#define SZ_K    (4ull*8*12288*64)      // 25,165,824
#define SZ_L    (32ull*64*64)          // 131,072
#define OFF_K    0ull
#define OFF_V    (OFF_K + SZ_K)
#define OFF_QL   (OFF_V + SZ_K)
#define OFF_KL   (OFF_QL + SZ_L)
#define OFF_A2   (OFF_KL + SZ_L)
#define OFF_T3   (OFF_A2 + SZ_L)
#define OFF_T2   (OFF_T3 + SZ_L)
#define OFF_MAX  (OFF_T2 + SZ_L)
#define OFF_OPRE (OFF_MAX + 16ull)
// total = 59,375,648 floats (237.5 MB) — proven fit.
// BTq aliases [OFF_QL...), BTo aliases kb (dead after k_sim3part).

__device__ __forceinline__ unsigned short hbits(_Float16 x) {
    union { _Float16 f; unsigned short u; } c; c.f = x; return c.u;
}

// ---------------- transpose + fp16-split weights: w[K][N] -> BT[N][K] hi/lo ----------------
__global__ __launch_bounds__(256) void k_cvtw(const float* __restrict__ w,
    _Float16* __restrict__ bh, _Float16* __restrict__ bl, int K, int N)
{
    __shared__ float t[64][65];
    const int n0 = blockIdx.x * 64, k0 = blockIdx.y * 64;
    const int tid = threadIdx.x;
    #pragma unroll
    for (int i = 0; i < 4; ++i) {
        int r = (tid >> 4) + i * 16;
        int c = (tid & 15) * 4;
        float4 v = *(const float4*)(w + (size_t)(k0 + r) * N + n0 + c);
        t[r][c] = v.x; t[r][c+1] = v.y; t[r][c+2] = v.z; t[r][c+3] = v.w;
    }
    __syncthreads();
    const int n = tid >> 2, kq = (tid & 3) * 16;
    f16x8 h8[2], l8[2];
    #pragma unroll
    for (int j = 0; j < 16; ++j) {
        float a = t[kq + j][n];
        _Float16 hh = (_Float16)a;
        _Float16 ll = (_Float16)(a - (float)hh);
        h8[j >> 3][j & 7] = hh;
        l8[j >> 3][j & 7] = ll;
    }
    size_t o = (size_t)(n0 + n) * K + k0 + kq;
    *(f16x8*)(bh + o) = h8[0]; *(f16x8*)(bh + o + 8) = h8[1];
    *(f16x8*)(bl + o) = l8[0]; *(f16x8*)(bl + o + 8) = l8[1];
}

// ---------------- fp16-split MFMA GEMM, 2-phase dbuf, depth-2 prefetch, XCD swizzle ------
__device__ __forceinline__ int hoff(int r, int slot) {
    return r * 32 + (((slot ^ (r >> 1)) & 3) << 3);
}

template<int MODE>
__global__ __launch_bounds__(256) void k_gemm_split(
    const float* __restrict__ Asrc0, const float* __restrict__ Asrc1,
    const _Float16* __restrict__ BTh, const _Float16* __restrict__ BTl,
    float* __restrict__ out0, float* __restrict__ out1, float* __restrict__ out2)
{
    __shared__ __align__(16) _Float16 Ah[2][128 * 32], Al[2][128 * 32];
    __shared__ __align__(16) _Float16 Bh[2][128 * 32], Bl[2][128 * 32];
    const int NB = (MODE == 0) ? 12 : 4;
    const int id = blockIdx.x;
    const int w8 = id % (NB * 8);
    const int n0 = (w8 >> 3) * 128;
    const int m0 = ((id / (NB * 8)) * 8 + (w8 & 7)) * 128;
    const int tid = threadIdx.x;
    const int wv = tid >> 6, lane = tid & 63;
    const int wr = wv >> 1, wc = wv & 1;
    const int kslot = lane >> 4;

    int ar[2], asl[2];
    const float* aptr[2];
    #pragma unroll
    for (int i = 0; i < 2; ++i) {
        int id2 = tid + 256 * i;
        ar[i] = id2 >> 2; asl[i] = id2 & 3;
        int grow = m0 + ar[i];
        if (MODE == 0) {
            int bi = grow / NTOT;
            int pos = grow - bi * NTOT;
            aptr[i] = (pos < NP) ? (Asrc0 + ((size_t)bi * NP + pos) * DIM)
                                 : (Asrc1 + ((size_t)bi * PTOT + (pos - NP)) * DIM);
        } else {
            aptr[i] = Asrc0 + (size_t)grow * DIM;
        }
    }

    float4 a0[2], a1[2];
    f16x8 vbh[2], vbl[2];

    auto LOADT = [&](int k0) {
        #pragma unroll
        for (int i = 0; i < 2; ++i) {
            a0[i] = *(const float4*)(aptr[i] + k0 + asl[i] * 8);
            a1[i] = *(const float4*)(aptr[i] + k0 + asl[i] * 8 + 4);
            size_t bo = (size_t)(n0 + ar[i]) * DIM + k0 + asl[i] * 8;
            vbh[i] = *(const f16x8*)(BTh + bo);
            vbl[i] = *(const f16x8*)(BTl + bo);
        }
    };
    auto WRITET = [&](int buf) {
        #pragma unroll
        for (int i = 0; i < 2; ++i) {
            f16x8 h, l;
            float vals[8] = {a0[i].x, a0[i].y, a0[i].z, a0[i].w,
                             a1[i].x, a1[i].y, a1[i].z, a1[i].w};
            #pragma unroll
            for (int j = 0; j < 8; ++j) {
                _Float16 hh = (_Float16)vals[j];
                h[j] = hh;
                l[j] = (_Float16)(vals[j] - (float)hh);
            }
            int o = hoff(ar[i], asl[i]);
            *(f16x8*)&Ah[buf][o] = h;
            *(f16x8*)&Al[buf][o] = l;
            *(f16x8*)&Bh[buf][o] = vbh[i];
            *(f16x8*)&Bl[buf][o] = vbl[i];
        }
    };

    LOADT(0);
    WRITET(0);
    LOADT(32);
    int cur = 0;

    f32x4 acc[4][4] = {};
    for (int t = 0; t < 16; ++t) {
        __syncthreads();
        f16x8 afh[4], afl[4];
        #pragma unroll
        for (int m = 0; m < 4; ++m) {
            int o = hoff(wr * 64 + m * 16 + (lane & 15), kslot);
            afh[m] = *(const f16x8*)&Ah[cur][o];
            afl[m] = *(const f16x8*)&Al[cur][o];
        }
        f16x8 bfh[4], bfl[4];
        #pragma unroll
        for (int n = 0; n < 4; ++n) {
            int o = hoff(wc * 64 + n * 16 + (lane & 15), kslot);
            bfh[n] = *(const f16x8*)&Bh[cur][o];
            bfl[n] = *(const f16x8*)&Bl[cur][o];
        }
        if (t < 15) WRITET(cur ^ 1);
        if (t < 14) LOADT((t + 2) * 32);
        #pragma unroll
        for (int n = 0; n < 4; ++n)
            #pragma unroll
            for (int m = 0; m < 4; ++m) {
                acc[m][n] = __builtin_amdgcn_mfma_f32_16x16x32_f16(afh[m], bfh[n], acc[m][n], 0, 0, 0);
                acc[m][n] = __builtin_amdgcn_mfma_f32_16x16x32_f16(afh[m], bfl[n], acc[m][n], 0, 0, 0);
                acc[m][n] = __builtin_amdgcn_mfma_f32_16x16x32_f16(afl[m], bfh[n], acc[m][n], 0, 0, 0);
            }
        cur ^= 1;
    }
    #pragma unroll
    for (int m = 0; m < 4; ++m) {
        #pragma unroll
        for (int n = 0; n < 4; ++n) {
            int gcol = n0 + wc * 64 + n * 16 + (lane & 15);
            int rbase = m0 + wr * 64 + m * 16 + (lane >> 4) * 4;
            if (MODE == 1) {
                #pragma unroll
                for (int r = 0; r < 4; ++r)
                    out0[(size_t)(rbase + r) * DIM + gcol] = acc[m][n][r];
            } else {
                int which = gcol >> 9, h = (gcol >> 6) & 7, d = gcol & 63;
                #pragma unroll
                for (int r = 0; r < 4; ++r) {
                    int row = rbase + r;
                    int bi = row / NTOT;
                    int p = row - bi * NTOT;
                    float v = acc[m][n][r];
                    if (which == 0) {
                        if (p < NP) out0[(((size_t)bi * Hh + h) * NP + p) * DH + d] = v * SCALE;
                    } else if (which == 1) {
                        out1[(((size_t)bi * Hh + h) * NTOT + p) * DH + d] = v;
                    } else {
                        out2[(((size_t)bi * Hh + h) * NTOT + p) * DH + d] = v;
                    }
                }
            }
        }
    }
}

// ---------------- K2: landmark means (vectorized) ----------------
__global__ __launch_bounds__(256) void k_land(const float* __restrict__ mq,
    const float* __restrict__ kb, float* __restrict__ ql, float* __restrict__ kl)
{
    __shared__ float part[16][64];
    int idx = blockIdx.x;
    const int tid = threadIdx.x;
    const int rg = tid >> 4, c4 = (tid & 15) << 2;
    const float* src;
    float* dst;
    int R; float sc;
    if (idx < 2048) {
        int bh = idx >> 6, i = idx & 63;
        src = mq + ((size_t)bh * NP + i * 64) * DH;
        dst = ql + ((size_t)bh * 64 + i) * 64;
        R = 64; sc = 1.f / 64.f;
    } else {
        idx -= 2048;
        int bh = idx >> 6, i = idx & 63;
        src = kb + ((size_t)bh * NTOT + i * 192) * DH;
        dst = kl + ((size_t)bh * 64 + i) * 64;
        R = 192; sc = 1.f / 192.f;
    }
    float4 a = make_float4(0.f, 0.f, 0.f, 0.f);
    for (int r = rg; r < R; r += 16) {
        float4 v = *(const float4*)(src + (size_t)r * DH + c4);
        a.x += v.x; a.y += v.y; a.z += v.z; a.w += v.w;
    }
    *(float4*)&part[rg][c4] = a;
    __syncthreads();
    if (tid < 64) {
        float s = 0.f;
        #pragma unroll
        for (int g = 0; g < 16; ++g) s += part[g][tid];
        dst[tid] = s * sc;
    }
}

// ---------------- K3: attn2 = softmax(q_l @ k_l^T); also zero-inits mx ----------------
__global__ __launch_bounds__(256) void k_sim2(const float* __restrict__ ql,
    const float* __restrict__ kl, float* __restrict__ a2, float* __restrict__ mx)
{
    __shared__ float qs[64][64];
    __shared__ float ks[64][65];
    __shared__ float S[64][65];
    const int tid = threadIdx.x;
    const int bh = blockIdx.x;
    if (bh == 0 && tid < 2) mx[tid] = 0.f;
    for (int e = tid; e < 4096; e += 256) {
        qs[e >> 6][e & 63] = ql[(size_t)bh * 4096 + e];
        ks[e >> 6][e & 63] = kl[(size_t)bh * 4096 + e];
    }
    __syncthreads();
    for (int sI = 0; sI < 16; ++sI) {
        int e = (sI << 8) + tid;
        int i = e >> 6, j = e & 63;
        float acc = 0.f;
        #pragma unroll 16
        for (int d = 0; d < 64; ++d) acc = fmaf(qs[i][d], ks[j][d], acc);
        S[i][j] = acc;
    }
    __syncthreads();
    const int wv = tid >> 6, lane = tid & 63;
    for (int i = wv; i < 64; i += 4) {
        float v = S[i][lane];
        float mxv = v;
        #pragma unroll
        for (int off = 32; off; off >>= 1) mxv = fmaxf(mxv, __shfl_xor(mxv, off));
        float p = expf(v - mxv);
        float sm = p;
        #pragma unroll
        for (int off = 32; off; off >>= 1) sm += __shfl_xor(sm, off);
        a2[((size_t)bh * 64 + i) * 64 + lane] = p / sm;
    }
}

// ---------------- K4: global max of row/col abs-sums of attn2 ----------------
__global__ __launch_bounds__(64) void k_maxes(const float* __restrict__ a2,
    float* __restrict__ mx)
{
    const int bh = blockIdx.x;
    const int i = threadIdx.x;
    const float* base = a2 + (size_t)bh * 4096;
    float cs = 0.f, rs = 0.f;
    for (int j = 0; j < 64; ++j) {
        cs += fabsf(base[i * 64 + j]);
        rs += fabsf(base[j * 64 + i]);
    }
    #pragma unroll
    for (int off = 32; off; off >>= 1) {
        cs = fmaxf(cs, __shfl_xor(cs, off));
        rs = fmaxf(rs, __shfl_xor(rs, off));
    }
    if (i == 0) {
        atomicMax((unsigned int*)&mx[0], __float_as_uint(cs));
        atomicMax((unsigned int*)&mx[1], __float_as_uint(rs));
    }
}

// ---------------- K5a: sim3 partials — fp16-split MFMA flash over a 512-row chunk ----------
__global__ __launch_bounds__(256) void k_sim3part(const float* __restrict__ qlg,
    const float* __restrict__ kb, const float* __restrict__ vb,
    float* __restrict__ pacc, float* __restrict__ pm, float* __restrict__ pl)
{
    __shared__ __align__(16) _Float16 qsh[4096], qsl[4096];
    __shared__ __align__(16) _Float16 kvh[4096], kvl[4096];
    __shared__ __align__(16) unsigned int pss[64][68];
    __shared__ float corr_s[64];
    const int bh = blockIdx.x, ch = blockIdx.y;
    const int tid = threadIdx.x;
    const int wv = tid >> 6, lane = tid & 63;
    const int lg = lane >> 4, ll = lane & 15;

    #pragma unroll
    for (int it = 0; it < 4; ++it) {
        int e = tid + 256 * it;
        int r = e >> 4, c0 = (e & 15) << 2;
        float4 qv = *(const float4*)(qlg + (size_t)bh * 4096 + r * 64 + c0);
        f16x4 h, l;
        float vals[4] = {qv.x, qv.y, qv.z, qv.w};
        #pragma unroll
        for (int i = 0; i < 4; ++i) {
            _Float16 hh = (_Float16)vals[i];
            h[i] = hh; l[i] = (_Float16)(vals[i] - (float)hh);
        }
        int off = r * 64 + (((c0 >> 3) ^ (r & 7)) << 3) + (c0 & 7);
        *(f16x4*)&qsh[off] = h;
        *(f16x4*)&qsl[off] = l;
    }

    const float* kc = kb + ((size_t)bh * NTOT + ch * CHUNK) * DH;
    const float* vc = vb + ((size_t)bh * NTOT + ch * CHUNK) * DH;

    float m_run = -INFINITY, l_run = 0.f;
    f32x4 acc_o[4] = {};

    for (int t = 0; t < CHUNK / 64; ++t) {
        __syncthreads();
        #pragma unroll
        for (int it = 0; it < 4; ++it) {
            int e = tid + 256 * it;
            int r = e >> 4, c0 = (e & 15) << 2;
            float4 kx = *(const float4*)(kc + (size_t)(t * 64 + r) * DH + c0);
            f16x4 h, l;
            float vals[4] = {kx.x, kx.y, kx.z, kx.w};
            #pragma unroll
            for (int i = 0; i < 4; ++i) {
                _Float16 hh = (_Float16)vals[i];
                h[i] = hh; l[i] = (_Float16)(vals[i] - (float)hh);
            }
            int off = r * 64 + (((c0 >> 3) ^ (r & 7)) << 3) + (c0 & 7);
            *(f16x4*)&kvh[off] = h;
            *(f16x4*)&kvl[off] = l;
        }
        __syncthreads();
        f32x4 accs[4] = {};
        #pragma unroll
        for (int ks = 0; ks < 2; ++ks) {
            int k0 = 32 * ks + (lg << 3);
            int brow = 16 * wv + ll;
            int boff = brow * 64 + (((k0 >> 3) ^ (brow & 7)) << 3);
            f16x8 bh8 = *(const f16x8*)&kvh[boff];
            f16x8 bl8 = *(const f16x8*)&kvl[boff];
            #pragma unroll
            for (int m = 0; m < 4; ++m) {
                int arow = 16 * m + ll;
                int aoff = arow * 64 + (((k0 >> 3) ^ (arow & 7)) << 3);
                f16x8 ah8 = *(const f16x8*)&qsh[aoff];
                f16x8 al8 = *(const f16x8*)&qsl[aoff];
                accs[m] = __builtin_amdgcn_mfma_f32_16x16x32_f16(ah8, bh8, accs[m], 0, 0, 0);
                accs[m] = __builtin_amdgcn_mfma_f32_16x16x32_f16(ah8, bl8, accs[m], 0, 0, 0);
                accs[m] = __builtin_amdgcn_mfma_f32_16x16x32_f16(al8, bh8, accs[m], 0, 0, 0);
            }
        }
        #pragma unroll
        for (int m = 0; m < 4; ++m)
            #pragma unroll
            for (int rg = 0; rg < 4; ++rg)
                pss[16 * m + lg * 4 + rg][16 * wv + ll] = __float_as_uint(accs[m][rg]);
        __syncthreads();
        {
            const int r = tid >> 2, q = tid & 3;
            float s[16];
            uint4 u0 = *(const uint4*)&pss[r][q * 16];
            uint4 u1 = *(const uint4*)&pss[r][q * 16 + 4];
            uint4 u2 = *(const uint4*)&pss[r][q * 16 + 8];
            uint4 u3 = *(const uint4*)&pss[r][q * 16 + 12];
            s[0]=__uint_as_float(u0.x); s[1]=__uint_as_float(u0.y); s[2]=__uint_as_float(u0.z); s[3]=__uint_as_float(u0.w);
            s[4]=__uint_as_float(u1.x); s[5]=__uint_as_float(u1.y); s[6]=__uint_as_float(u1.z); s[7]=__uint_as_float(u1.w);
            s[8]=__uint_as_float(u2.x); s[9]=__uint_as_float(u2.y); s[10]=__uint_as_float(u2.z); s[11]=__uint_as_float(u2.w);
            s[12]=__uint_as_float(u3.x); s[13]=__uint_as_float(u3.y); s[14]=__uint_as_float(u3.z); s[15]=__uint_as_float(u3.w);
            float lmax = s[0];
            #pragma unroll
            for (int i = 1; i < 16; ++i) lmax = fmaxf(lmax, s[i]);
            lmax = fmaxf(lmax, __shfl_xor(lmax, 1));
            lmax = fmaxf(lmax, __shfl_xor(lmax, 2));
            float mnew = fmaxf(m_run, lmax);
            float corr = expf(m_run - mnew);
            float p[16], rsum = 0.f;
            #pragma unroll
            for (int i = 0; i < 16; ++i) { p[i] = expf(s[i] - mnew); rsum += p[i]; }
            rsum += __shfl_xor(rsum, 1);
            rsum += __shfl_xor(rsum, 2);
            l_run = l_run * corr + rsum;
            m_run = mnew;
            if (q == 0) corr_s[r] = corr;
            #pragma unroll
            for (int i2 = 0; i2 < 8; ++i2) {
                float p0 = p[2 * i2], p1 = p[2 * i2 + 1];
                _Float16 h0 = (_Float16)p0, h1 = (_Float16)p1;
                _Float16 e0 = (_Float16)(p0 - (float)h0), e1 = (_Float16)(p1 - (float)h1);
                pss[r][q * 8 + i2]      = (unsigned int)hbits(h0) | ((unsigned int)hbits(h1) << 16);
                pss[r][32 + q * 8 + i2] = (unsigned int)hbits(e0) | ((unsigned int)hbits(e1) << 16);
            }
        }
        {
            const int r0 = (tid & 31) * 2, cb = (tid >> 5) * 4;
            #pragma unroll
            for (int ci = 0; ci < 2; ++ci) {
                int c0 = cb + 32 * ci;
                float4 v0 = *(const float4*)(vc + (size_t)(t * 64 + r0) * DH + c0);
                float4 v1 = *(const float4*)(vc + (size_t)(t * 64 + r0 + 1) * DH + c0);
                float a0[4] = {v0.x, v0.y, v0.z, v0.w};
                float a1[4] = {v1.x, v1.y, v1.z, v1.w};
                #pragma unroll
                for (int i = 0; i < 4; ++i) {
                    int c = c0 + i;
                    _Float16 h0 = (_Float16)a0[i], h1 = (_Float16)a1[i];
                    _Float16 e0 = (_Float16)(a0[i] - (float)h0), e1 = (_Float16)(a1[i] - (float)h1);
                    int off = c * 64 + (((r0 >> 3) ^ (c & 7)) << 3) + (r0 & 7);
                    *(unsigned int*)&kvh[off] = (unsigned int)hbits(h0) | ((unsigned int)hbits(h1) << 16);
                    *(unsigned int*)&kvl[off] = (unsigned int)hbits(e0) | ((unsigned int)hbits(e1) << 16);
                }
            }
        }
        __syncthreads();
        #pragma unroll
        for (int m = 0; m < 4; ++m)
            #pragma unroll
            for (int rg = 0; rg < 4; ++rg)
                acc_o[m][rg] *= corr_s[16 * m + lg * 4 + rg];
        #pragma unroll
        for (int ks = 0; ks < 2; ++ks) {
            int k0 = 32 * ks + (lg << 3);
            int dh = 16 * wv + ll;
            int boff = dh * 64 + (((k0 >> 3) ^ (dh & 7)) << 3);
            f16x8 vh8 = *(const f16x8*)&kvh[boff];
            f16x8 vl8 = *(const f16x8*)&kvl[boff];
            #pragma unroll
            for (int m = 0; m < 4; ++m) {
                int prow = 16 * m + ll;
                union { uint4 u; f16x8 f; } ph, pe;
                ph.u = *(const uint4*)&pss[prow][16 * ks + lg * 4];
                pe.u = *(const uint4*)&pss[prow][32 + 16 * ks + lg * 4];
                acc_o[m] = __builtin_amdgcn_mfma_f32_16x16x32_f16(ph.f, vh8, acc_o[m], 0, 0, 0);
                acc_o[m] = __builtin_amdgcn_mfma_f32_16x16x32_f16(ph.f, vl8, acc_o[m], 0, 0, 0);
                acc_o[m] = __builtin_amdgcn_mfma_f32_16x16x32_f16(pe.f, vh8, acc_o[m], 0, 0, 0);
            }
        }
    }
    const size_t base = ((size_t)bh * NCH + ch) * 64;
    #pragma unroll
    for (int m = 0; m < 4; ++m)
        #pragma unroll
        for (int rg = 0; rg < 4; ++rg) {
            int row = 16 * m + lg * 4 + rg;
            pacc[(base + row) * 64 + 16 * wv + ll] = acc_o[m][rg];
        }
    if ((tid & 3) == 0) {
        int r = tid >> 2;
        pm[base + r] = m_run;
        pl[base + r] = l_run;
    }
}

// ---------------- K5b: combine sim3 partials -> t3 ----------------
__global__ __launch_bounds__(256) void k_sim3comb(const float* __restrict__ pacc,
    const float* __restrict__ pm, const float* __restrict__ pl, float* __restrict__ t3)
{
    __shared__ float w[NCH][64];
    __shared__ float Linv[64];
    const int bh = blockIdx.x;
    const int tid = threadIdx.x;
    if (tid < 64) {
        float M = -INFINITY;
        for (int c = 0; c < NCH; ++c)
            M = fmaxf(M, pm[((size_t)bh * NCH + c) * 64 + tid]);
        float L = 0.f;
        for (int c = 0; c < NCH; ++c) {
            float e = expf(pm[((size_t)bh * NCH + c) * 64 + tid] - M);
            w[c][tid] = e;
            L = fmaf(e, pl[((size_t)bh * NCH + c) * 64 + tid], L);
        }
        Linv[tid] = 1.f / L;
    }
    __syncthreads();
    const int wv = tid >> 6, lane = tid & 63;
    for (int p = 0; p < 16; ++p) {
        int i = (p << 2) + wv;
        float o = 0.f;
        for (int c = 0; c < NCH; ++c)
            o = fmaf(w[c][i], pacc[(((size_t)bh * NCH + c) * 64 + i) * 64 + lane], o);
        t3[((size_t)bh * 64 + i) * 64 + lane] = o * Linv[i];
    }
}

// ---------------- K6: pinv (LDS-resident, 256 thr, 4x4 register tiles) + t2 = z @ t3 -----
__device__ __forceinline__ void mm64t(float* __restrict__ C, const float* A,
    const float* Bm, const float* S, float sa, float sm, int tid)
{
    const int ty = tid >> 4, tx = tid & 15;
    float r[4][4] = {};
    __syncthreads();
    #pragma unroll 4
    for (int k = 0; k < 64; ++k) {
        float4 b4 = *(const float4*)&Bm[(k << 6) + (tx << 2)];
        #pragma unroll
        for (int i = 0; i < 4; ++i) {
            float a = A[(((ty << 2) + i) << 6) + k];
            r[i][0] = fmaf(a, b4.x, r[i][0]);
            r[i][1] = fmaf(a, b4.y, r[i][1]);
            r[i][2] = fmaf(a, b4.z, r[i][2]);
            r[i][3] = fmaf(a, b4.w, r[i][3]);
        }
    }
    __syncthreads();
    #pragma unroll
    for (int i = 0; i < 4; ++i) {
        int e = (((ty << 2) + i) << 6) + (tx << 2);
        float4 v = make_float4(sm * r[i][0], sm * r[i][1], sm * r[i][2], sm * r[i][3]);
        if (S) {
            v.x = fmaf(sa, S[e], v.x);     v.y = fmaf(sa, S[e + 1], v.y);
            v.z = fmaf(sa, S[e + 2], v.z); v.w = fmaf(sa, S[e + 3], v.w);
        }
        *(float4*)&C[e] = v;
    }
    __syncthreads();
}

__device__ __forceinline__ void mm64gt(float* __restrict__ C, const float* __restrict__ Ag,
    const float* __restrict__ Bm, int tid)
{
    const int ty = tid >> 4, tx = tid & 15;
    float r[4][4] = {};
    __syncthreads();
    #pragma unroll 4
    for (int k = 0; k < 64; ++k) {
        float4 b4 = *(const float4*)&Bm[(k << 6) + (tx << 2)];
        #pragma unroll
        for (int i = 0; i < 4; ++i) {
            float a = Ag[(((ty << 2) + i) << 6) + k];
            r[i][0] = fmaf(a, b4.x, r[i][0]);
            r[i][1] = fmaf(a, b4.y, r[i][1]);
            r[i][2] = fmaf(a, b4.z, r[i][2]);
            r[i][3] = fmaf(a, b4.w, r[i][3]);
        }
    }
    __syncthreads();
    #pragma unroll
    for (int i = 0; i < 4; ++i) {
        int e = (((ty << 2) + i) << 6) + (tx << 2);
        *(float4*)&C[e] = make_float4(r[i][0], r[i][1], r[i][2], r[i][3]);
    }
    __syncthreads();
}

__global__ __launch_bounds__(256) void k_pinv(const float* __restrict__ attn2,
    const float* __restrict__ mx, const float* __restrict__ t3g, float* __restrict__ t2g)
{
    __shared__ float Zs[4096], Ab[4096], Db[4096];
    const int tid = threadIdx.x;
    const int bh = blockIdx.x;
    const float inv = 1.0f / (mx[0] * mx[1]);
    const float* a2 = attn2 + (size_t)bh * 4096;
    for (int e = tid; e < 4096; e += 256) {
        int i = e >> 6, j = e & 63;
        Zs[e] = a2[(j << 6) + i] * inv;
    }
    for (int it = 0; it < 6; ++it) {
        mm64gt(Ab, a2, Zs, tid);
        mm64t(Db, Ab, Ab, Ab, 7.f, -1.f, tid);
        for (int e = tid; e < 4096; e += 256) {
            int i = e >> 6, j = e & 63;
            Db[e] = ((i == j) ? 15.f : 0.f) - Db[e];
        }
        mm64t(Ab, Zs, Ab, nullptr, 0.f, 1.f, tid);
        mm64t(Zs, Ab, Db, Zs, 3.25f, -0.25f, tid);
    }
    for (int e = tid; e < 4096; e += 256) Ab[e] = t3g[(size_t)bh * 4096 + e];
    mm64t(Db, Zs, Ab, nullptr, 0.f, 1.f, tid);
    for (int e = tid; e < 4096; e += 256) t2g[(size_t)bh * 4096 + e] = Db[e];
}

// ---------------- K7: out1 = softmax(mq@k_l^T) @ t2 + depthwise conv(v), MFMA ----------
// grid (32 bh, 8 groups of 512 rows), 256 thr. Per 64-row tile: q-split staged into qps,
// A-frags preloaded to regs, then qps reused as S/P scratch (u32 [64][68]).
// kl-split and t2^T-split staged once; their B-frags live in registers for all 8 tiles.
__global__ __launch_bounds__(256) void k_attn1(const float* __restrict__ mq,
    const float* __restrict__ klg, const float* __restrict__ t2g,
    const float* __restrict__ vb, const float* __restrict__ cwg,
    float* __restrict__ opre)
{
    __shared__ __align__(16) _Float16 klh[4096], kll[4096];
    __shared__ __align__(16) _Float16 t2h[4096], t2l[4096];
    __shared__ __align__(16) unsigned int qps[64 * 68];
    __shared__ float cw[33];
    const int bh = blockIdx.x;
    const int b = bh >> 3, h = bh & 7;
    const int rgb = blockIdx.y;
    const int tid = threadIdx.x;
    const int wv = tid >> 6, lane = tid & 63;
    const int lg = lane >> 4, ll = lane & 15;

    _Float16* qh_ = (_Float16*)qps;       // h-plane: halves [0,4096)
    _Float16* ql_ = qh_ + 4096;           // l-plane: halves [4096,8192)

    // stage kl split [col][k]
    #pragma unroll
    for (int it = 0; it < 4; ++it) {
        int e = tid + 256 * it;
        int r = e >> 4, c0 = (e & 15) << 2;
        float4 kx = *(const float4*)(klg + (size_t)bh * 4096 + r * 64 + c0);
        f16x4 hh, lo;
        float vals[4] = {kx.x, kx.y, kx.z, kx.w};
        #pragma unroll
        for (int i = 0; i < 4; ++i) {
            _Float16 hv = (_Float16)vals[i];
            hh[i] = hv; lo[i] = (_Float16)(vals[i] - (float)hv);
        }
        int off = r * 64 + (((c0 >> 3) ^ (r & 7)) << 3) + (c0 & 7);
        *(f16x4*)&klh[off] = hh;
        *(f16x4*)&kll[off] = lo;
    }
    // stage t2 transposed split [dh][k]
    {
        const int r0 = (tid & 31) * 2, cb = (tid >> 5) * 4;
        #pragma unroll
        for (int ci = 0; ci < 2; ++ci) {
            int c0 = cb + 32 * ci;
            float4 v0 = *(const float4*)(t2g + (size_t)bh * 4096 + (size_t)r0 * 64 + c0);
            float4 v1 = *(const float4*)(t2g + (size_t)bh * 4096 + (size_t)(r0 + 1) * 64 + c0);
            float a0[4] = {v0.x, v0.y, v0.z, v0.w};
            float a1[4] = {v1.x, v1.y, v1.z, v1.w};
            #pragma unroll
            for (int i = 0; i < 4; ++i) {
                int c = c0 + i;
                _Float16 h0 = (_Float16)a0[i], h1 = (_Float16)a1[i];
                _Float16 e0 = (_Float16)(a0[i] - (float)h0), e1 = (_Float16)(a1[i] - (float)h1);
                int off = c * 64 + (((r0 >> 3) ^ (c & 7)) << 3) + (r0 & 7);
                *(unsigned int*)&t2h[off] = (unsigned int)hbits(h0) | ((unsigned int)hbits(h1) << 16);
                *(unsigned int*)&t2l[off] = (unsigned int)hbits(e0) | ((unsigned int)hbits(e1) << 16);
            }
        }
    }
    if (tid < 33) cw[tid] = cwg[h * 33 + tid];

    const float* mqb = mq + (size_t)bh * NP * DH;
    const float* vbase = vb + (size_t)bh * NTOT * DH;

    f16x8 bkh[2], bkl2[2], bth[2], btl2[2];

    for (int t = 0; t < 8; ++t) {
        const int row0 = (rgb << 9) + (t << 6);
        // stage q tile split (qps as h/l half-planes)
        #pragma unroll
        for (int it = 0; it < 4; ++it) {
            int e = tid + 256 * it;
            int r = e >> 4, c0 = (e & 15) << 2;
            float4 qv = *(const float4*)(mqb + (size_t)(row0 + r) * DH + c0);
            f16x4 hh, lo;
            float vals[4] = {qv.x, qv.y, qv.z, qv.w};
            #pragma unroll
            for (int i = 0; i < 4; ++i) {
                _Float16 hv = (_Float16)vals[i];
                hh[i] = hv; lo[i] = (_Float16)(vals[i] - (float)hv);
            }
            int off = r * 64 + (((c0 >> 3) ^ (r & 7)) << 3) + (c0 & 7);
            *(f16x4*)&qh_[off] = hh;
            *(f16x4*)&ql_[off] = lo;
        }
        __syncthreads();   // A: q visible (and kl/t2t on t==0)
        if (t == 0) {
            #pragma unroll
            for (int ks = 0; ks < 2; ++ks) {
                int k0 = 32 * ks + (lg << 3);
                int br = 16 * wv + ll;
                int boff = br * 64 + (((k0 >> 3) ^ (br & 7)) << 3);
                bkh[ks]  = *(const f16x8*)&klh[boff];
                bkl2[ks] = *(const f16x8*)&kll[boff];
                bth[ks]  = *(const f16x8*)&t2h[boff];
                btl2[ks] = *(const f16x8*)&t2l[boff];
            }
        }
        // preload all A-frags (q) to regs — qps gets overwritten by S after barrier B
        f16x8 ah[2][4], al[2][4];
        #pragma unroll
        for (int ks = 0; ks < 2; ++ks) {
            int k0 = 32 * ks + (lg << 3);
            #pragma unroll
            for (int m = 0; m < 4; ++m) {
                int arw = 16 * m + ll;
                int aoff = arw * 64 + (((k0 >> 3) ^ (arw & 7)) << 3);
                ah[ks][m] = *(const f16x8*)&qh_[aoff];
                al[ks][m] = *(const f16x8*)&ql_[aoff];
            }
        }
        __syncthreads();   // B: all q reads done; qps reusable
        // S = q @ kl^T
        f32x4 accs[4] = {};
        #pragma unroll
        for (int ks = 0; ks < 2; ++ks)
            #pragma unroll
            for (int m = 0; m < 4; ++m) {
                accs[m] = __builtin_amdgcn_mfma_f32_16x16x32_f16(ah[ks][m], bkh[ks], accs[m], 0, 0, 0);
                accs[m] = __builtin_amdgcn_mfma_f32_16x16x32_f16(ah[ks][m], bkl2[ks], accs[m], 0, 0, 0);
                accs[m] = __builtin_amdgcn_mfma_f32_16x16x32_f16(al[ks][m], bkh[ks], accs[m], 0, 0, 0);
            }
        #pragma unroll
        for (int m = 0; m < 4; ++m)
            #pragma unroll
            for (int rgi = 0; rgi < 4; ++rgi)
                qps[(16 * m + lg * 4 + rgi) * 68 + 16 * wv + ll] = __float_as_uint(accs[m][rgi]);
        __syncthreads();   // C: S complete
        // full-row softmax -> P packed h/l planes
        {
            const int r = tid >> 2, q4 = tid & 3;
            float s[16];
            #pragma unroll
            for (int j = 0; j < 16; ++j) s[j] = __uint_as_float(qps[r * 68 + q4 * 16 + j]);
            float rmax = s[0];
            #pragma unroll
            for (int j = 1; j < 16; ++j) rmax = fmaxf(rmax, s[j]);
            rmax = fmaxf(rmax, __shfl_xor(rmax, 1));
            rmax = fmaxf(rmax, __shfl_xor(rmax, 2));
            float p[16], rsum = 0.f;
            #pragma unroll
            for (int j = 0; j < 16; ++j) { p[j] = expf(s[j] - rmax); rsum += p[j]; }
            rsum += __shfl_xor(rsum, 1);
            rsum += __shfl_xor(rsum, 2);
            float rinv = 1.f / rsum;
            #pragma unroll
            for (int j = 0; j < 16; ++j) p[j] *= rinv;
            #pragma unroll
            for (int i2 = 0; i2 < 8; ++i2) {
                float p0 = p[2 * i2], p1 = p[2 * i2 + 1];
                _Float16 h0 = (_Float16)p0, h1 = (_Float16)p1;
                _Float16 e0 = (_Float16)(p0 - (float)h0), e1 = (_Float16)(p1 - (float)h1);
                qps[r * 68 + q4 * 8 + i2]      = (unsigned int)hbits(h0) | ((unsigned int)hbits(h1) << 16);
                qps[r * 68 + 32 + q4 * 8 + i2] = (unsigned int)hbits(e0) | ((unsigned int)hbits(e1) << 16);
            }
        }
        __syncthreads();   // D: P ready
        // O = P @ t2
        f32x4 acco[4] = {};
        #pragma unroll
        for (int ks = 0; ks < 2; ++ks)
            #pragma unroll
            for (int m = 0; m < 4; ++m) {
                int prow = 16 * m + ll;
                union { uint4 u; f16x8 f; } ph, pe;
                ph.u = *(const uint4*)&qps[prow * 68 + 16 * ks + lg * 4];
                pe.u = *(const uint4*)&qps[prow * 68 + 32 + 16 * ks + lg * 4];
                acco[m] = __builtin_amdgcn_mfma_f32_16x16x32_f16(ph.f, bth[ks], acco[m], 0, 0, 0);
                acco[m] = __builtin_amdgcn_mfma_f32_16x16x32_f16(ph.f, btl2[ks], acco[m], 0, 0, 0);
                acco[m] = __builtin_amdgcn_mfma_f32_16x16x32_f16(pe.f, bth[ks], acco[m], 0, 0, 0);
            }
        // conv in MFMA mapping (col fixed per thread) + fused store
        {
            int col = 16 * wv + ll;
            const float* vp = vbase + col;
            #pragma unroll
            for (int m = 0; m < 4; ++m) {
                float cacc[4] = {};
                int rb = row0 + 16 * m + lg * 4;
                #pragma unroll
                for (int kk = 0; kk < 36; ++kk) {
                    int rr = rb - 16 + kk;
                    if (rr >= 0) {
                        float vx = vp[(size_t)rr * DH];
                        #pragma unroll
                        for (int rgi = 0; rgi < 4; ++rgi) {
                            int k = kk - rgi;
                            if (k >= 0 && k < 33)
                                cacc[rgi] = fmaf(cw[k], vx, cacc[rgi]);
                        }
                    }
                }
                #pragma unroll
                for (int rgi = 0; rgi < 4; ++rgi) {
                    int row = rb + rgi;
                    opre[((size_t)b * NP + row) * DIM + h * DH + col] = acco[m][rgi] + cacc[rgi];
                }
            }
        }
        __syncthreads();   // E: PV's qps reads done before next q stage
    }
}

extern "C" void kernel_launch(void* const* d_in, const int* in_sizes, int n_in,
                              void* d_out, int out_size, void* d_ws, size_t ws_size,
                              hipStream_t stream)
{
    const float* x   = (const float*)d_in[0];
    const float* ps  = (const float*)d_in[1];
    const float* wq  = (const float*)d_in[2];
    const float* wo  = (const float*)d_in[3];
    const float* cwg = (const float*)d_in[4];
    float* out = (float*)d_out;
    float* ws  = (float*)d_ws;

    float* mq   = out;               // d_out doubles as mq scratch; k_gemm<1> overwrites last
    float* kb   = ws + OFF_K;
    float* vb   = ws + OFF_V;
    float* ql   = ws + OFF_QL;
    float* kl   = ws + OFF_KL;
    float* a2   = ws + OFF_A2;
    float* t3   = ws + OFF_T3;
    float* t2   = ws + OFF_T2;
    float* mx   = ws + OFF_MAX;
    float* opre = ws + OFF_OPRE;
    float* pacc = opre;
    float* pm   = opre + 3145728ull;
    float* pl   = pm + 49152ull;
    _Float16* BTqh = (_Float16*)(ws + OFF_QL);
    _Float16* BTql = BTqh + 1536 * 512;
    _Float16* BToh = (_Float16*)(ws + OFF_K);
    _Float16* BTol = BToh + 512 * 512;

    k_cvtw        <<<dim3(24, 8), 256, 0, stream>>>(wq, BTqh, BTql, 512, 1536);
    k_gemm_split<0><<<4608, 256, 0, stream>>>(x, ps, BTqh, BTql, mq, kb, vb);
    k_land        <<<4096, 256, 0, stream>>>(mq, kb, ql, kl);
    k_sim2        <<<32, 256, 0, stream>>>(ql, kl, a2, mx);
    k_maxes       <<<32, 64, 0, stream>>>(a2, mx);
    k_sim3part    <<<dim3(32, NCH), 256, 0, stream>>>(ql, kb, vb, pacc, pm, pl);
    k_sim3comb    <<<32, 256, 0, stream>>>(pacc, pm, pl, t3);
    k_cvtw        <<<dim3(8, 8), 256, 0, stream>>>(wo, BToh, BTol, 512, 512);
    k_pinv        <<<32, 256, 0, stream>>>(a2, mx, t3, t2);
    k_attn1       <<<dim3(32, 8), 256, 0, stream>>>(mq, kl, t2, vb, cwg, opre);
    k_gemm_split<1><<<512, 256, 0, stream>>>(opre, nullptr, BToh, BTol, out, nullptr, nullptr);
}

// Round 10
// 620.546 us; speedup vs baseline: 4.4196x; 1.2021x over previous
//
#include <hip/hip_runtime.h>
#include <math.h>

#define Bb 4
#define Hh 8
#define NP 4096
#define PTOT 8192
#define NTOT 12288
#define DIM 512
#define DH 64
#define SCALE 0.125f
#define NCH 24
#define CHUNK 512

typedef __attribute__((ext_vector_type(8))) _Float16 f16x8;
typedef __attribute__((ext_vector_type(4))) _Float16 f16x4;
typedef __attribute__((ext_vector_type(4))) float f32x4;

// ---------------- workspace layout (float offsets) ----------------
#define SZ_K    (4ull*8*12288*64)      // 25,165,824
#define SZ_L    (32ull*64*64)          // 131,072
#define OFF_K    0ull
#define OFF_V    (OFF_K + SZ_K)
#define OFF_QL   (OFF_V + SZ_K)
#define OFF_KL   (OFF_QL + SZ_L)
#define OFF_A2   (OFF_KL + SZ_L)
#define OFF_T3   (OFF_A2 + SZ_L)
#define OFF_T2   (OFF_T3 + SZ_L)
#define OFF_MAX  (OFF_T2 + SZ_L)
#define OFF_OPRE (OFF_MAX + 16ull)
// total = 59,375,648 floats (237.5 MB) — proven fit.
// BTq aliases [OFF_QL...), BTo aliases kb (dead after k_sim3part).

__device__ __forceinline__ unsigned short hbits(_Float16 x) {
    union { _Float16 f; unsigned short u; } c; c.f = x; return c.u;
}

// ---------------- transpose + fp16-split weights -> frag-major BT [N/16][K/8][16][8] ------
__global__ __launch_bounds__(256) void k_cvtw(const float* __restrict__ w,
    _Float16* __restrict__ bh, _Float16* __restrict__ bl, int K, int N)
{
    __shared__ float t[64][65];
    const int n0 = blockIdx.x * 64, k0 = blockIdx.y * 64;
    const int tid = threadIdx.x;
    #pragma unroll
    for (int i = 0; i < 4; ++i) {
        int r = (tid >> 4) + i * 16;
        int c = (tid & 15) * 4;
        float4 v = *(const float4*)(w + (size_t)(k0 + r) * N + n0 + c);
        t[r][c] = v.x; t[r][c+1] = v.y; t[r][c+2] = v.z; t[r][c+3] = v.w;
    }
    __syncthreads();
    const int n = n0 + (tid >> 2), kq = k0 + (tid & 3) * 16;
    f16x8 h8[2], l8[2];
    #pragma unroll
    for (int j = 0; j < 16; ++j) {
        float a = t[(kq - k0) + j][n - n0];
        _Float16 hh = (_Float16)a;
        _Float16 ll = (_Float16)(a - (float)hh);
        h8[j >> 3][j & 7] = hh;
        l8[j >> 3][j & 7] = ll;
    }
    // frag-major: idx(n,k8) = ((n>>4)*(K>>3) + k8)*128 + (n&15)*8
    size_t o = ((size_t)(n >> 4) * (K >> 3) + (kq >> 3)) * 128 + (size_t)(n & 15) * 8;
    *(f16x8*)(bh + o) = h8[0]; *(f16x8*)(bh + o + 128) = h8[1];
    *(f16x8*)(bl + o) = l8[0]; *(f16x8*)(bl + o + 128) = l8[1];
}

// ---------------- fp16-split MFMA GEMM: A via LDS dbuf, B frag-direct from global --------
__device__ __forceinline__ int hoff(int r, int slot) {
    return r * 32 + (((slot ^ (r >> 1)) & 3) << 3);
}

template<int MODE>
__global__ __launch_bounds__(256) void k_gemm_split(
    const float* __restrict__ Asrc0, const float* __restrict__ Asrc1,
    const _Float16* __restrict__ BTh, const _Float16* __restrict__ BTl,
    float* __restrict__ out0, float* __restrict__ out1, float* __restrict__ out2)
{
    __shared__ __align__(16) _Float16 Ah[2][128 * 32], Al[2][128 * 32];
    const int NB = (MODE == 0) ? 12 : 4;
    const int id = blockIdx.x;
    const int w8 = id % (NB * 8);
    const int n0 = (w8 >> 3) * 128;
    const int m0 = ((id / (NB * 8)) * 8 + (w8 & 7)) * 128;
    const int tid = threadIdx.x;
    const int wv = tid >> 6, lane = tid & 63;
    const int wr = wv >> 1, wc = wv & 1;
    const int kslot = lane >> 4, ll = lane & 15;
    const int nb_base = (n0 >> 4) + wc * 4;

    int ar[2], asl[2];
    const float* aptr[2];
    #pragma unroll
    for (int i = 0; i < 2; ++i) {
        int id2 = tid + 256 * i;
        ar[i] = id2 >> 2; asl[i] = id2 & 3;
        int grow = m0 + ar[i];
        if (MODE == 0) {
            int bi = grow / NTOT;
            int pos = grow - bi * NTOT;
            aptr[i] = (pos < NP) ? (Asrc0 + ((size_t)bi * NP + pos) * DIM)
                                 : (Asrc1 + ((size_t)bi * PTOT + (pos - NP)) * DIM);
        } else {
            aptr[i] = Asrc0 + (size_t)grow * DIM;
        }
    }

    float4 a0[2], a1[2];
    auto LOADT = [&](int k0) {
        #pragma unroll
        for (int i = 0; i < 2; ++i) {
            a0[i] = *(const float4*)(aptr[i] + k0 + asl[i] * 8);
            a1[i] = *(const float4*)(aptr[i] + k0 + asl[i] * 8 + 4);
        }
    };
    auto WRITET = [&](int buf) {
        #pragma unroll
        for (int i = 0; i < 2; ++i) {
            f16x8 h, l;
            float vals[8] = {a0[i].x, a0[i].y, a0[i].z, a0[i].w,
                             a1[i].x, a1[i].y, a1[i].z, a1[i].w};
            #pragma unroll
            for (int j = 0; j < 8; ++j) {
                _Float16 hh = (_Float16)vals[j];
                h[j] = hh;
                l[j] = (_Float16)(vals[j] - (float)hh);
            }
            int o = hoff(ar[i], asl[i]);
            *(f16x8*)&Ah[buf][o] = h;
            *(f16x8*)&Al[buf][o] = l;
        }
    };

    LOADT(0);
    WRITET(0);
    LOADT(32);
    int cur = 0;

    f32x4 acc[4][4] = {};
    for (int t = 0; t < 16; ++t) {
        __syncthreads();
        f16x8 afh[4], afl[4];
        #pragma unroll
        for (int m = 0; m < 4; ++m) {
            int o = hoff(wr * 64 + m * 16 + ll, kslot);
            afh[m] = *(const f16x8*)&Ah[cur][o];
            afl[m] = *(const f16x8*)&Al[cur][o];
        }
        // B frags direct from global (frag-major, 256B-coalesced per 16-lane group)
        f16x8 bfh[4], bfl[4];
        {
            int k8 = t * 4 + kslot;
            #pragma unroll
            for (int n = 0; n < 4; ++n) {
                size_t bo = ((size_t)(nb_base + n) * (DIM >> 3) + k8) * 128 + (size_t)ll * 8;
                bfh[n] = *(const f16x8*)(BTh + bo);
                bfl[n] = *(const f16x8*)(BTl + bo);
            }
        }
        if (t < 15) WRITET(cur ^ 1);
        if (t < 14) LOADT((t + 2) * 32);
        #pragma unroll
        for (int n = 0; n < 4; ++n)
            #pragma unroll
            for (int m = 0; m < 4; ++m) {
                acc[m][n] = __builtin_amdgcn_mfma_f32_16x16x32_f16(afh[m], bfh[n], acc[m][n], 0, 0, 0);
                acc[m][n] = __builtin_amdgcn_mfma_f32_16x16x32_f16(afh[m], bfl[n], acc[m][n], 0, 0, 0);
                acc[m][n] = __builtin_amdgcn_mfma_f32_16x16x32_f16(afl[m], bfh[n], acc[m][n], 0, 0, 0);
            }
        cur ^= 1;
    }
    #pragma unroll
    for (int m = 0; m < 4; ++m) {
        #pragma unroll
        for (int n = 0; n < 4; ++n) {
            int gcol = n0 + wc * 64 + n * 16 + ll;
            int rbase = m0 + wr * 64 + m * 16 + (lane >> 4) * 4;
            if (MODE == 1) {
                #pragma unroll
                for (int r = 0; r < 4; ++r)
                    out0[(size_t)(rbase + r) * DIM + gcol] = acc[m][n][r];
            } else {
                int which = gcol >> 9, h = (gcol >> 6) & 7, d = gcol & 63;
                #pragma unroll
                for (int r = 0; r < 4; ++r) {
                    int row = rbase + r;
                    int bi = row / NTOT;
                    int p = row - bi * NTOT;
                    float v = acc[m][n][r];
                    if (which == 0) {
                        if (p < NP) out0[(((size_t)bi * Hh + h) * NP + p) * DH + d] = v * SCALE;
                    } else if (which == 1) {
                        out1[(((size_t)bi * Hh + h) * NTOT + p) * DH + d] = v;
                    } else {
                        out2[(((size_t)bi * Hh + h) * NTOT + p) * DH + d] = v;
                    }
                }
            }
        }
    }
}

// ---------------- K2: landmark means (vectorized) ----------------
__global__ __launch_bounds__(256) void k_land(const float* __restrict__ mq,
    const float* __restrict__ kb, float* __restrict__ ql, float* __restrict__ kl)
{
    __shared__ float part[16][64];
    int idx = blockIdx.x;
    const int tid = threadIdx.x;
    const int rg = tid >> 4, c4 = (tid & 15) << 2;
    const float* src;
    float* dst;
    int R; float sc;
    if (idx < 2048) {
        int bh = idx >> 6, i = idx & 63;
        src = mq + ((size_t)bh * NP + i * 64) * DH;
        dst = ql + ((size_t)bh * 64 + i) * 64;
        R = 64; sc = 1.f / 64.f;
    } else {
        idx -= 2048;
        int bh = idx >> 6, i = idx & 63;
        src = kb + ((size_t)bh * NTOT + i * 192) * DH;
        dst = kl + ((size_t)bh * 64 + i) * 64;
        R = 192; sc = 1.f / 192.f;
    }
    float4 a = make_float4(0.f, 0.f, 0.f, 0.f);
    for (int r = rg; r < R; r += 16) {
        float4 v = *(const float4*)(src + (size_t)r * DH + c4);
        a.x += v.x; a.y += v.y; a.z += v.z; a.w += v.w;
    }
    *(float4*)&part[rg][c4] = a;
    __syncthreads();
    if (tid < 64) {
        float s = 0.f;
        #pragma unroll
        for (int g = 0; g < 16; ++g) s += part[g][tid];
        dst[tid] = s * sc;
    }
}

// ---------------- K3: attn2 = softmax(q_l @ k_l^T); also zero-inits mx ----------------
__global__ __launch_bounds__(256) void k_sim2(const float* __restrict__ ql,
    const float* __restrict__ kl, float* __restrict__ a2, float* __restrict__ mx)
{
    __shared__ float qs[64][64];
    __shared__ float ks[64][65];
    __shared__ float S[64][65];
    const int tid = threadIdx.x;
    const int bh = blockIdx.x;
    if (bh == 0 && tid < 2) mx[tid] = 0.f;
    for (int e = tid; e < 4096; e += 256) {
        qs[e >> 6][e & 63] = ql[(size_t)bh * 4096 + e];
        ks[e >> 6][e & 63] = kl[(size_t)bh * 4096 + e];
    }
    __syncthreads();
    for (int sI = 0; sI < 16; ++sI) {
        int e = (sI << 8) + tid;
        int i = e >> 6, j = e & 63;
        float acc = 0.f;
        #pragma unroll 16
        for (int d = 0; d < 64; ++d) acc = fmaf(qs[i][d], ks[j][d], acc);
        S[i][j] = acc;
    }
    __syncthreads();
    const int wv = tid >> 6, lane = tid & 63;
    for (int i = wv; i < 64; i += 4) {
        float v = S[i][lane];
        float mxv = v;
        #pragma unroll
        for (int off = 32; off; off >>= 1) mxv = fmaxf(mxv, __shfl_xor(mxv, off));
        float p = expf(v - mxv);
        float sm = p;
        #pragma unroll
        for (int off = 32; off; off >>= 1) sm += __shfl_xor(sm, off);
        a2[((size_t)bh * 64 + i) * 64 + lane] = p / sm;
    }
}

// ---------------- K4: global max of row/col abs-sums of attn2 ----------------
__global__ __launch_bounds__(64) void k_maxes(const float* __restrict__ a2,
    float* __restrict__ mx)
{
    const int bh = blockIdx.x;
    const int i = threadIdx.x;
    const float* base = a2 + (size_t)bh * 4096;
    float cs = 0.f, rs = 0.f;
    for (int j = 0; j < 64; ++j) {
        cs += fabsf(base[i * 64 + j]);
        rs += fabsf(base[j * 64 + i]);
    }
    #pragma unroll
    for (int off = 32; off; off >>= 1) {
        cs = fmaxf(cs, __shfl_xor(cs, off));
        rs = fmaxf(rs, __shfl_xor(rs, off));
    }
    if (i == 0) {
        atomicMax((unsigned int*)&mx[0], __float_as_uint(cs));
        atomicMax((unsigned int*)&mx[1], __float_as_uint(rs));
    }
}

// ---------------- K5a: sim3 partials — fp16-split MFMA flash over a 512-row chunk ----------
__global__ __launch_bounds__(256) void k_sim3part(const float* __restrict__ qlg,
    const float* __restrict__ kb, const float* __restrict__ vb,
    float* __restrict__ pacc, float* __restrict__ pm, float* __restrict__ pl)
{
    __shared__ __align__(16) _Float16 qsh[4096], qsl[4096];
    __shared__ __align__(16) _Float16 kvh[4096], kvl[4096];
    __shared__ __align__(16) unsigned int pss[64][68];
    __shared__ float corr_s[64];
    const int bh = blockIdx.x, ch = blockIdx.y;
    const int tid = threadIdx.x;
    const int wv = tid >> 6, lane = tid & 63;
    const int lg = lane >> 4, ll = lane & 15;

    #pragma unroll
    for (int it = 0; it < 4; ++it) {
        int e = tid + 256 * it;
        int r = e >> 4, c0 = (e & 15) << 2;
        float4 qv = *(const float4*)(qlg + (size_t)bh * 4096 + r * 64 + c0);
        f16x4 h, l;
        float vals[4] = {qv.x, qv.y, qv.z, qv.w};
        #pragma unroll
        for (int i = 0; i < 4; ++i) {
            _Float16 hh = (_Float16)vals[i];
            h[i] = hh; l[i] = (_Float16)(vals[i] - (float)hh);
        }
        int off = r * 64 + (((c0 >> 3) ^ (r & 7)) << 3) + (c0 & 7);
        *(f16x4*)&qsh[off] = h;
        *(f16x4*)&qsl[off] = l;
    }

    const float* kc = kb + ((size_t)bh * NTOT + ch * CHUNK) * DH;
    const float* vc = vb + ((size_t)bh * NTOT + ch * CHUNK) * DH;

    float m_run = -INFINITY, l_run = 0.f;
    f32x4 acc_o[4] = {};

    for (int t = 0; t < CHUNK / 64; ++t) {
        __syncthreads();
        #pragma unroll
        for (int it = 0; it < 4; ++it) {
            int e = tid + 256 * it;
            int r = e >> 4, c0 = (e & 15) << 2;
            float4 kx = *(const float4*)(kc + (size_t)(t * 64 + r) * DH + c0);
            f16x4 h, l;
            float vals[4] = {kx.x, kx.y, kx.z, kx.w};
            #pragma unroll
            for (int i = 0; i < 4; ++i) {
                _Float16 hh = (_Float16)vals[i];
                h[i] = hh; l[i] = (_Float16)(vals[i] - (float)hh);
            }
            int off = r * 64 + (((c0 >> 3) ^ (r & 7)) << 3) + (c0 & 7);
            *(f16x4*)&kvh[off] = h;
            *(f16x4*)&kvl[off] = l;
        }
        __syncthreads();
        f32x4 accs[4] = {};
        #pragma unroll
        for (int ks = 0; ks < 2; ++ks) {
            int k0 = 32 * ks + (lg << 3);
            int brow = 16 * wv + ll;
            int boff = brow * 64 + (((k0 >> 3) ^ (brow & 7)) << 3);
            f16x8 bh8 = *(const f16x8*)&kvh[boff];
            f16x8 bl8 = *(const f16x8*)&kvl[boff];
            #pragma unroll
            for (int m = 0; m < 4; ++m) {
                int arow = 16 * m + ll;
                int aoff = arow * 64 + (((k0 >> 3) ^ (arow & 7)) << 3);
                f16x8 ah8 = *(const f16x8*)&qsh[aoff];
                f16x8 al8 = *(const f16x8*)&qsl[aoff];
                accs[m] = __builtin_amdgcn_mfma_f32_16x16x32_f16(ah8, bh8, accs[m], 0, 0, 0);
                accs[m] = __builtin_amdgcn_mfma_f32_16x16x32_f16(ah8, bl8, accs[m], 0, 0, 0);
                accs[m] = __builtin_amdgcn_mfma_f32_16x16x32_f16(al8, bh8, accs[m], 0, 0, 0);
            }
        }
        #pragma unroll
        for (int m = 0; m < 4; ++m)
            #pragma unroll
            for (int rg = 0; rg < 4; ++rg)
                pss[16 * m + lg * 4 + rg][16 * wv + ll] = __float_as_uint(accs[m][rg]);
        __syncthreads();
        {
            const int r = tid >> 2, q = tid & 3;
            float s[16];
            uint4 u0 = *(const uint4*)&pss[r][q * 16];
            uint4 u1 = *(const uint4*)&pss[r][q * 16 + 4];
            uint4 u2 = *(const uint4*)&pss[r][q * 16 + 8];
            uint4 u3 = *(const uint4*)&pss[r][q * 16 + 12];
            s[0]=__uint_as_float(u0.x); s[1]=__uint_as_float(u0.y); s[2]=__uint_as_float(u0.z); s[3]=__uint_as_float(u0.w);
            s[4]=__uint_as_float(u1.x); s[5]=__uint_as_float(u1.y); s[6]=__uint_as_float(u1.z); s[7]=__uint_as_float(u1.w);
            s[8]=__uint_as_float(u2.x); s[9]=__uint_as_float(u2.y); s[10]=__uint_as_float(u2.z); s[11]=__uint_as_float(u2.w);
            s[12]=__uint_as_float(u3.x); s[13]=__uint_as_float(u3.y); s[14]=__uint_as_float(u3.z); s[15]=__uint_as_float(u3.w);
            float lmax = s[0];
            #pragma unroll
            for (int i = 1; i < 16; ++i) lmax = fmaxf(lmax, s[i]);
            lmax = fmaxf(lmax, __shfl_xor(lmax, 1));
            lmax = fmaxf(lmax, __shfl_xor(lmax, 2));
            float mnew = fmaxf(m_run, lmax);
            float corr = expf(m_run - mnew);
            float p[16], rsum = 0.f;
            #pragma unroll
            for (int i = 0; i < 16; ++i) { p[i] = expf(s[i] - mnew); rsum += p[i]; }
            rsum += __shfl_xor(rsum, 1);
            rsum += __shfl_xor(rsum, 2);
            l_run = l_run * corr + rsum;
            m_run = mnew;
            if (q == 0) corr_s[r] = corr;
            #pragma unroll
            for (int i2 = 0; i2 < 8; ++i2) {
                float p0 = p[2 * i2], p1 = p[2 * i2 + 1];
                _Float16 h0 = (_Float16)p0, h1 = (_Float16)p1;
                _Float16 e0 = (_Float16)(p0 - (float)h0), e1 = (_Float16)(p1 - (float)h1);
                pss[r][q * 8 + i2]      = (unsigned int)hbits(h0) | ((unsigned int)hbits(h1) << 16);
                pss[r][32 + q * 8 + i2] = (unsigned int)hbits(e0) | ((unsigned int)hbits(e1) << 16);
            }
        }
        {
            const int r0 = (tid & 31) * 2, cb = (tid >> 5) * 4;
            #pragma unroll
            for (int ci = 0; ci < 2; ++ci) {
                int c0 = cb + 32 * ci;
                float4 v0 = *(const float4*)(vc + (size_t)(t * 64 + r0) * DH + c0);
                float4 v1 = *(const float4*)(vc + (size_t)(t * 64 + r0 + 1) * DH + c0);
                float a0[4] = {v0.x, v0.y, v0.z, v0.w};
                float a1[4] = {v1.x, v1.y, v1.z, v1.w};
                #pragma unroll
                for (int i = 0; i < 4; ++i) {
                    int c = c0 + i;
                    _Float16 h0 = (_Float16)a0[i], h1 = (_Float16)a1[i];
                    _Float16 e0 = (_Float16)(a0[i] - (float)h0), e1 = (_Float16)(a1[i] - (float)h1);
                    int off = c * 64 + (((r0 >> 3) ^ (c & 7)) << 3) + (r0 & 7);
                    *(unsigned int*)&kvh[off] = (unsigned int)hbits(h0) | ((unsigned int)hbits(h1) << 16);
                    *(unsigned int*)&kvl[off] = (unsigned int)hbits(e0) | ((unsigned int)hbits(e1) << 16);
                }
            }
        }
        __syncthreads();
        #pragma unroll
        for (int m = 0; m < 4; ++m)
            #pragma unroll
            for (int rg = 0; rg < 4; ++rg)
                acc_o[m][rg] *= corr_s[16 * m + lg * 4 + rg];
        #pragma unroll
        for (int ks = 0; ks < 2; ++ks) {
            int k0 = 32 * ks + (lg << 3);
            int dh = 16 * wv + ll;
            int boff = dh * 64 + (((k0 >> 3) ^ (dh & 7)) << 3);
            f16x8 vh8 = *(const f16x8*)&kvh[boff];
            f16x8 vl8 = *(const f16x8*)&kvl[boff];
            #pragma unroll
            for (int m = 0; m < 4; ++m) {
                int prow = 16 * m + ll;
                union { uint4 u; f16x8 f; } ph, pe;
                ph.u = *(const uint4*)&pss[prow][16 * ks + lg * 4];
                pe.u = *(const uint4*)&pss[prow][32 + 16 * ks + lg * 4];
                acc_o[m] = __builtin_amdgcn_mfma_f32_16x16x32_f16(ph.f, vh8, acc_o[m], 0, 0, 0);
                acc_o[m] = __builtin_amdgcn_mfma_f32_16x16x32_f16(ph.f, vl8, acc_o[m], 0, 0, 0);
                acc_o[m] = __builtin_amdgcn_mfma_f32_16x16x32_f16(pe.f, vh8, acc_o[m], 0, 0, 0);
            }
        }
    }
    const size_t base = ((size_t)bh * NCH + ch) * 64;
    #pragma unroll
    for (int m = 0; m < 4; ++m)
        #pragma unroll
        for (int rg = 0; rg < 4; ++rg) {
            int row = 16 * m + lg * 4 + rg;
            pacc[(base + row) * 64 + 16 * wv + ll] = acc_o[m][rg];
        }
    if ((tid & 3) == 0) {
        int r = tid >> 2;
        pm[base + r] = m_run;
        pl[base + r] = l_run;
    }
}

// ---------------- K5b: combine sim3 partials -> t3 ----------------
__global__ __launch_bounds__(256) void k_sim3comb(const float* __restrict__ pacc,
    const float* __restrict__ pm, const float* __restrict__ pl, float* __restrict__ t3)
{
    __shared__ float w[NCH][64];
    __shared__ float Linv[64];
    const int bh = blockIdx.x;
    const int tid = threadIdx.x;
    if (tid < 64) {
        float M = -INFINITY;
        for (int c = 0; c < NCH; ++c)
            M = fmaxf(M, pm[((size_t)bh * NCH + c) * 64 + tid]);
        float L = 0.f;
        for (int c = 0; c < NCH; ++c) {
            float e = expf(pm[((size_t)bh * NCH + c) * 64 + tid] - M);
            w[c][tid] = e;
            L = fmaf(e, pl[((size_t)bh * NCH + c) * 64 + tid], L);
        }
        Linv[tid] = 1.f / L;
    }
    __syncthreads();
    const int wv = tid >> 6, lane = tid & 63;
    for (int p = 0; p < 16; ++p) {
        int i = (p << 2) + wv;
        float o = 0.f;
        for (int c = 0; c < NCH; ++c)
            o = fmaf(w[c][i], pacc[(((size_t)bh * NCH + c) * 64 + i) * 64 + lane], o);
        t3[((size_t)bh * 64 + i) * 64 + lane] = o * Linv[i];
    }
}

// ---------------- K6: pinv (LDS-resident, 256 thr, 4x4 register tiles) + t2 = z @ t3 -----
__device__ __forceinline__ void mm64t(float* __restrict__ C, const float* A,
    const float* Bm, const float* S, float sa, float sm, int tid)
{
    const int ty = tid >> 4, tx = tid & 15;
    float r[4][4] = {};
    __syncthreads();
    #pragma unroll 4
    for (int k = 0; k < 64; ++k) {
        float4 b4 = *(const float4*)&Bm[(k << 6) + (tx << 2)];
        #pragma unroll
        for (int i = 0; i < 4; ++i) {
            float a = A[(((ty << 2) + i) << 6) + k];
            r[i][0] = fmaf(a, b4.x, r[i][0]);
            r[i][1] = fmaf(a, b4.y, r[i][1]);
            r[i][2] = fmaf(a, b4.z, r[i][2]);
            r[i][3] = fmaf(a, b4.w, r[i][3]);
        }
    }
    __syncthreads();
    #pragma unroll
    for (int i = 0; i < 4; ++i) {
        int e = (((ty << 2) + i) << 6) + (tx << 2);
        float4 v = make_float4(sm * r[i][0], sm * r[i][1], sm * r[i][2], sm * r[i][3]);
        if (S) {
            v.x = fmaf(sa, S[e], v.x);     v.y = fmaf(sa, S[e + 1], v.y);
            v.z = fmaf(sa, S[e + 2], v.z); v.w = fmaf(sa, S[e + 3], v.w);
        }
        *(float4*)&C[e] = v;
    }
    __syncthreads();
}

__device__ __forceinline__ void mm64gt(float* __restrict__ C, const float* __restrict__ Ag,
    const float* __restrict__ Bm, int tid)
{
    const int ty = tid >> 4, tx = tid & 15;
    float r[4][4] = {};
    __syncthreads();
    #pragma unroll 4
    for (int k = 0; k < 64; ++k) {
        float4 b4 = *(const float4*)&Bm[(k << 6) + (tx << 2)];
        #pragma unroll
        for (int i = 0; i < 4; ++i) {
            float a = Ag[(((ty << 2) + i) << 6) + k];
            r[i][0] = fmaf(a, b4.x, r[i][0]);
            r[i][1] = fmaf(a, b4.y, r[i][1]);
            r[i][2] = fmaf(a, b4.z, r[i][2]);
            r[i][3] = fmaf(a, b4.w, r[i][3]);
        }
    }
    __syncthreads();
    #pragma unroll
    for (int i = 0; i < 4; ++i) {
        int e = (((ty << 2) + i) << 6) + (tx << 2);
        *(float4*)&C[e] = make_float4(r[i][0], r[i][1], r[i][2], r[i][3]);
    }
    __syncthreads();
}

__global__ __launch_bounds__(256) void k_pinv(const float* __restrict__ attn2,
    const float* __restrict__ mx, const float* __restrict__ t3g, float* __restrict__ t2g)
{
    __shared__ float Zs[4096], Ab[4096], Db[4096];
    const int tid = threadIdx.x;
    const int bh = blockIdx.x;
    const float inv = 1.0f / (mx[0] * mx[1]);
    const float* a2 = attn2 + (size_t)bh * 4096;
    for (int e = tid; e < 4096; e += 256) {
        int i = e >> 6, j = e & 63;
        Zs[e] = a2[(j << 6) + i] * inv;
    }
    for (int it = 0; it < 6; ++it) {
        mm64gt(Ab, a2, Zs, tid);
        mm64t(Db, Ab, Ab, Ab, 7.f, -1.f, tid);
        for (int e = tid; e < 4096; e += 256) {
            int i = e >> 6, j = e & 63;
            Db[e] = ((i == j) ? 15.f : 0.f) - Db[e];
        }
        mm64t(Ab, Zs, Ab, nullptr, 0.f, 1.f, tid);
        mm64t(Zs, Ab, Db, Zs, 3.25f, -0.25f, tid);
    }
    for (int e = tid; e < 4096; e += 256) Ab[e] = t3g[(size_t)bh * 4096 + e];
    mm64t(Db, Zs, Ab, nullptr, 0.f, 1.f, tid);
    for (int e = tid; e < 4096; e += 256) t2g[(size_t)bh * 4096 + e] = Db[e];
}

// ---------------- K7: out1 = softmax(mq@k_l^T) @ t2  (MFMA, conv moved to k_conv) --------
__global__ __launch_bounds__(256) void k_attn1(const float* __restrict__ mq,
    const float* __restrict__ klg, const float* __restrict__ t2g,
    float* __restrict__ opre)
{
    __shared__ __align__(16) _Float16 klh[4096], kll[4096];
    __shared__ __align__(16) _Float16 t2h[4096], t2l[4096];
    __shared__ __align__(16) unsigned int qps[64 * 68];
    const int bh = blockIdx.x;
    const int b = bh >> 3, h = bh & 7;
    const int rgb = blockIdx.y;
    const int tid = threadIdx.x;
    const int wv = tid >> 6, lane = tid & 63;
    const int lg = lane >> 4, ll = lane & 15;

    _Float16* qh_ = (_Float16*)qps;
    _Float16* ql_ = qh_ + 4096;

    #pragma unroll
    for (int it = 0; it < 4; ++it) {
        int e = tid + 256 * it;
        int r = e >> 4, c0 = (e & 15) << 2;
        float4 kx = *(const float4*)(klg + (size_t)bh * 4096 + r * 64 + c0);
        f16x4 hh, lo;
        float vals[4] = {kx.x, kx.y, kx.z, kx.w};
        #pragma unroll
        for (int i = 0; i < 4; ++i) {
            _Float16 hv = (_Float16)vals[i];
            hh[i] = hv; lo[i] = (_Float16)(vals[i] - (float)hv);
        }
        int off = r * 64 + (((c0 >> 3) ^ (r & 7)) << 3) + (c0 & 7);
        *(f16x4*)&klh[off] = hh;
        *(f16x4*)&kll[off] = lo;
    }
    {
        const int r0 = (tid & 31) * 2, cb = (tid >> 5) * 4;
        #pragma unroll
        for (int ci = 0; ci < 2; ++ci) {
            int c0 = cb + 32 * ci;
            float4 v0 = *(const float4*)(t2g + (size_t)bh * 4096 + (size_t)r0 * 64 + c0);
            float4 v1 = *(const float4*)(t2g + (size_t)bh * 4096 + (size_t)(r0 + 1) * 64 + c0);
            float a0[4] = {v0.x, v0.y, v0.z, v0.w};
            float a1[4] = {v1.x, v1.y, v1.z, v1.w};
            #pragma unroll
            for (int i = 0; i < 4; ++i) {
                int c = c0 + i;
                _Float16 h0 = (_Float16)a0[i], h1 = (_Float16)a1[i];
                _Float16 e0 = (_Float16)(a0[i] - (float)h0), e1 = (_Float16)(a1[i] - (float)h1);
                int off = c * 64 + (((r0 >> 3) ^ (c & 7)) << 3) + (r0 & 7);
                *(unsigned int*)&t2h[off] = (unsigned int)hbits(h0) | ((unsigned int)hbits(h1) << 16);
                *(unsigned int*)&t2l[off] = (unsigned int)hbits(e0) | ((unsigned int)hbits(e1) << 16);
            }
        }
    }

    const float* mqb = mq + (size_t)bh * NP * DH;
    f16x8 bkh[2], bkl2[2], bth[2], btl2[2];

    for (int t = 0; t < 8; ++t) {
        const int row0 = (rgb << 9) + (t << 6);
        #pragma unroll
        for (int it = 0; it < 4; ++it) {
            int e = tid + 256 * it;
            int r = e >> 4, c0 = (e & 15) << 2;
            float4 qv = *(const float4*)(mqb + (size_t)(row0 + r) * DH + c0);
            f16x4 hh, lo;
            float vals[4] = {qv.x, qv.y, qv.z, qv.w};
            #pragma unroll
            for (int i = 0; i < 4; ++i) {
                _Float16 hv = (_Float16)vals[i];
                hh[i] = hv; lo[i] = (_Float16)(vals[i] - (float)hv);
            }
            int off = r * 64 + (((c0 >> 3) ^ (r & 7)) << 3) + (c0 & 7);
            *(f16x4*)&qh_[off] = hh;
            *(f16x4*)&ql_[off] = lo;
        }
        __syncthreads();
        if (t == 0) {
            #pragma unroll
            for (int ks = 0; ks < 2; ++ks) {
                int k0 = 32 * ks + (lg << 3);
                int br = 16 * wv + ll;
                int boff = br * 64 + (((k0 >> 3) ^ (br & 7)) << 3);
                bkh[ks]  = *(const f16x8*)&klh[boff];
                bkl2[ks] = *(const f16x8*)&kll[boff];
                bth[ks]  = *(const f16x8*)&t2h[boff];
                btl2[ks] = *(const f16x8*)&t2l[boff];
            }
        }
        f16x8 ah[2][4], al[2][4];
        #pragma unroll
        for (int ks = 0; ks < 2; ++ks) {
            int k0 = 32 * ks + (lg << 3);
            #pragma unroll
            for (int m = 0; m < 4; ++m) {
                int arw = 16 * m + ll;
                int aoff = arw * 64 + (((k0 >> 3) ^ (arw & 7)) << 3);
                ah[ks][m] = *(const f16x8*)&qh_[aoff];
                al[ks][m] = *(const f16x8*)&ql_[aoff];
            }
        }
        __syncthreads();
        f32x4 accs[4] = {};
        #pragma unroll
        for (int ks = 0; ks < 2; ++ks)
            #pragma unroll
            for (int m = 0; m < 4; ++m) {
                accs[m] = __builtin_amdgcn_mfma_f32_16x16x32_f16(ah[ks][m], bkh[ks], accs[m], 0, 0, 0);
                accs[m] = __builtin_amdgcn_mfma_f32_16x16x32_f16(ah[ks][m], bkl2[ks], accs[m], 0, 0, 0);
                accs[m] = __builtin_amdgcn_mfma_f32_16x16x32_f16(al[ks][m], bkh[ks], accs[m], 0, 0, 0);
            }
        #pragma unroll
        for (int m = 0; m < 4; ++m)
            #pragma unroll
            for (int rgi = 0; rgi < 4; ++rgi)
                qps[(16 * m + lg * 4 + rgi) * 68 + 16 * wv + ll] = __float_as_uint(accs[m][rgi]);
        __syncthreads();
        {
            const int r = tid >> 2, q4 = tid & 3;
            float s[16];
            #pragma unroll
            for (int j = 0; j < 16; ++j) s[j] = __uint_as_float(qps[r * 68 + q4 * 16 + j]);
            float rmax = s[0];
            #pragma unroll
            for (int j = 1; j < 16; ++j) rmax = fmaxf(rmax, s[j]);
            rmax = fmaxf(rmax, __shfl_xor(rmax, 1));
            rmax = fmaxf(rmax, __shfl_xor(rmax, 2));
            float p[16], rsum = 0.f;
            #pragma unroll
            for (int j = 0; j < 16; ++j) { p[j] = expf(s[j] - rmax); rsum += p[j]; }
            rsum += __shfl_xor(rsum, 1);
            rsum += __shfl_xor(rsum, 2);
            float rinv = 1.f / rsum;
            #pragma unroll
            for (int j = 0; j < 16; ++j) p[j] *= rinv;
            #pragma unroll
            for (int i2 = 0; i2 < 8; ++i2) {
                float p0 = p[2 * i2], p1 = p[2 * i2 + 1];
                _Float16 h0 = (_Float16)p0, h1 = (_Float16)p1;
                _Float16 e0 = (_Float16)(p0 - (float)h0), e1 = (_Float16)(p1 - (float)h1);
                qps[r * 68 + q4 * 8 + i2]      = (unsigned int)hbits(h0) | ((unsigned int)hbits(h1) << 16);
                qps[r * 68 + 32 + q4 * 8 + i2] = (unsigned int)hbits(e0) | ((unsigned int)hbits(e1) << 16);
            }
        }
        __syncthreads();
        f32x4 acco[4] = {};
        #pragma unroll
        for (int ks = 0; ks < 2; ++ks)
            #pragma unroll
            for (int m = 0; m < 4; ++m) {
                int prow = 16 * m + ll;
                union { uint4 u; f16x8 f; } ph, pe;
                ph.u = *(const uint4*)&qps[prow * 68 + 16 * ks + lg * 4];
                pe.u = *(const uint4*)&qps[prow * 68 + 32 + 16 * ks + lg * 4];
                acco[m] = __builtin_amdgcn_mfma_f32_16x16x32_f16(ph.f, bth[ks], acco[m], 0, 0, 0);
                acco[m] = __builtin_amdgcn_mfma_f32_16x16x32_f16(ph.f, btl2[ks], acco[m], 0, 0, 0);
                acco[m] = __builtin_amdgcn_mfma_f32_16x16x32_f16(pe.f, bth[ks], acco[m], 0, 0, 0);
            }
        {
            int col = 16 * wv + ll;
            #pragma unroll
            for (int m = 0; m < 4; ++m) {
                int rb = row0 + 16 * m + lg * 4;
                #pragma unroll
                for (int rgi = 0; rgi < 4; ++rgi)
                    opre[((size_t)b * NP + rb + rgi) * DIM + h * DH + col] = acco[m][rgi];
            }
        }
        __syncthreads();
    }
}

// ---------------- K7b: opre += depthwise conv(v)  (LDS-staged sliding window) ------------
__global__ __launch_bounds__(256) void k_conv(const float* __restrict__ vb,
    const float* __restrict__ cwg, float* __restrict__ opre)
{
    __shared__ float vs[96][68];
    __shared__ float cw[33];
    const int bh = blockIdx.x;
    const int b = bh >> 3, h = bh & 7;
    const int row0 = blockIdx.y << 6;
    const int tid = threadIdx.x;
    const float* vbase = vb + (size_t)bh * NTOT * DH;
    #pragma unroll
    for (int it = 0; it < 6; ++it) {
        int e = tid + 256 * it;          // 1536 float4 slots = 96 rows x 16
        int r = e >> 4, c4 = (e & 15) << 2;
        int gr = row0 - 16 + r;
        float4 v = (gr >= 0) ? *(const float4*)(vbase + (size_t)gr * DH + c4)
                             : make_float4(0.f, 0.f, 0.f, 0.f);
        *(float4*)&vs[r][c4] = v;
    }
    if (tid < 33) cw[tid] = cwg[h * 33 + tid];
    __syncthreads();
    const int ty = tid >> 4, c4 = (tid & 15) << 2;
    #pragma unroll
    for (int i = 0; i < 4; ++i) {
        int lr = ty * 4 + i;
        float4 a = make_float4(0.f, 0.f, 0.f, 0.f);
        #pragma unroll 33
        for (int k = 0; k < 33; ++k) {
            float w = cw[k];
            const float* p = &vs[lr + k][c4];
            a.x = fmaf(w, p[0], a.x); a.y = fmaf(w, p[1], a.y);
            a.z = fmaf(w, p[2], a.z); a.w = fmaf(w, p[3], a.w);
        }
        float* op = opre + ((size_t)b * NP + row0 + lr) * DIM + h * DH + c4;
        float4 o = *(const float4*)op;
        o.x += a.x; o.y += a.y; o.z += a.z; o.w += a.w;
        *(float4*)op = o;
    }
}

extern "C" void kernel_launch(void* const* d_in, const int* in_sizes, int n_in,
                              void* d_out, int out_size, void* d_ws, size_t ws_size,
                              hipStream_t stream)
{
    const float* x   = (const float*)d_in[0];
    const float* ps  = (const float*)d_in[1];
    const float* wq  = (const float*)d_in[2];
    const float* wo  = (const float*)d_in[3];
    const float* cwg = (const float*)d_in[4];
    float* out = (float*)d_out;
    float* ws  = (float*)d_ws;

    float* mq   = out;               // d_out doubles as mq scratch; k_gemm<1> overwrites last
    float* kb   = ws + OFF_K;
    float* vb   = ws + OFF_V;
    float* ql   = ws + OFF_QL;
    float* kl   = ws + OFF_KL;
    float* a2   = ws + OFF_A2;
    float* t3   = ws + OFF_T3;
    float* t2   = ws + OFF_T2;
    float* mx   = ws + OFF_MAX;
    float* opre = ws + OFF_OPRE;
    float* pacc = opre;
    float* pm   = opre + 3145728ull;
    float* pl   = pm + 49152ull;
    _Float16* BTqh = (_Float16*)(ws + OFF_QL);
    _Float16* BTql = BTqh + 1536 * 512;
    _Float16* BToh = (_Float16*)(ws + OFF_K);
    _Float16* BTol = BToh + 512 * 512;

    k_cvtw        <<<dim3(24, 8), 256, 0, stream>>>(wq, BTqh, BTql, 512, 1536);
    k_gemm_split<0><<<4608, 256, 0, stream>>>(x, ps, BTqh, BTql, mq, kb, vb);
    k_land        <<<4096, 256, 0, stream>>>(mq, kb, ql, kl);
    k_sim2        <<<32, 256, 0, stream>>>(ql, kl, a2, mx);
    k_maxes       <<<32, 64, 0, stream>>>(a2, mx);
    k_sim3part    <<<dim3(32, NCH), 256, 0, stream>>>(ql, kb, vb, pacc, pm, pl);
    k_sim3comb    <<<32, 256, 0, stream>>>(pacc, pm, pl, t3);
    k_cvtw        <<<dim3(8, 8), 256, 0, stream>>>(wo, BToh, BTol, 512, 512);
    k_pinv        <<<32, 256, 0, stream>>>(a2, mx, t3, t2);
    k_attn1       <<<dim3(32, 8), 256, 0, stream>>>(mq, kl, t2, opre);
    k_conv        <<<dim3(32, 64), 256, 0, stream>>>(vb, cwg, opre);
    k_gemm_split<1><<<512, 256, 0, stream>>>(opre, nullptr, BToh, BTol, out, nullptr, nullptr);
}